// Round 7
// baseline (1195.806 us; speedup 1.0000x reference)
//
#include <hip/hip_runtime.h>
#include <hip/hip_fp16.h>

#define N_NODES 100000
#define N_EDGES 3200000
#define N_GRAPHS 2048
#define DIM 32
#define HDIM 16
#define FEAT 78
#define OUT_DIM 128
#define BN_EPS 1e-5f

#define BSHIFT 9
#define BSIZE 512
#define NB ((N_NODES + BSIZE - 1) / BSIZE)
#define CHUNK 8192

#define NTILES (N_NODES / 16)          // 6250
#define AGG_BLOCKS ((NTILES + 3) / 4)  // 1563

typedef _Float16 f16x8 __attribute__((ext_vector_type(8)));
typedef float f32x4 __attribute__((ext_vector_type(4)));

// ---------------- K1: coarse bucket histogram ----------------
__global__ __launch_bounds__(256) void bucket_hist_kernel(const int* __restrict__ dst,
                                                          int* __restrict__ bcnt) {
    __shared__ int lh[256];
    int tid = threadIdx.x;
    lh[tid] = 0;
    __syncthreads();
    int i = blockIdx.x * blockDim.x + tid;
    int stride = gridDim.x * blockDim.x;
    for (; i < N_EDGES; i += stride)
        atomicAdd(&lh[dst[i] >> BSHIFT], 1);
    __syncthreads();
    if (tid < NB && lh[tid])
        atomicAdd(&bcnt[tid], lh[tid]);
}

// ---------------- K2: scan over buckets ----------------
__global__ __launch_bounds__(256) void bucket_scan_kernel(const int* __restrict__ bcnt,
                                                          int* __restrict__ bstart,
                                                          int* __restrict__ bcursor,
                                                          int* __restrict__ rowst) {
    __shared__ int sc[256];
    int tid = threadIdx.x;
    int v = (tid < NB) ? bcnt[tid] : 0;
    sc[tid] = v;
    __syncthreads();
    for (int off = 1; off < 256; off <<= 1) {
        int nv = (tid >= off) ? sc[tid - off] : 0;
        __syncthreads();
        sc[tid] += nv;
        __syncthreads();
    }
    if (tid < NB) {
        int ex = sc[tid] - v;
        bstart[tid] = ex;
        bcursor[tid] = ex;
    }
    if (tid == 0) {
        bstart[NB] = N_EDGES;
        rowst[N_NODES] = N_EDGES;
    }
}

// ---------------- K3: multisplit scatter into bucket segments ----------------
__global__ __launch_bounds__(256) void bucket_scatter_kernel(const int* __restrict__ src,
                                                             const int* __restrict__ dst,
                                                             int* __restrict__ bcursor,
                                                             int* __restrict__ bsrc,
                                                             unsigned short* __restrict__ blow) {
    __shared__ int lsrc[CHUNK];
    __shared__ int ldst[CHUNK];
    __shared__ int lhist[256];
    __shared__ int sc[256];
    __shared__ int lpre[256];
    __shared__ int gbase[256];
    __shared__ int lcur[256];
    int tid = threadIdx.x;
    int base = blockIdx.x * CHUNK;
    int n = N_EDGES - base; if (n > CHUNK) n = CHUNK;

    lhist[tid] = 0;
    __syncthreads();
    for (int i = tid; i < n; i += 256)
        atomicAdd(&lhist[dst[base + i] >> BSHIFT], 1);
    __syncthreads();
    int v = lhist[tid];
    sc[tid] = v;
    __syncthreads();
    for (int off = 1; off < 256; off <<= 1) {
        int nv = (tid >= off) ? sc[tid - off] : 0;
        __syncthreads();
        sc[tid] += nv;
        __syncthreads();
    }
    int ex = sc[tid] - v;
    lpre[tid] = ex;
    lcur[tid] = ex;
    if (tid < NB && v)
        gbase[tid] = atomicAdd(&bcursor[tid], v);
    __syncthreads();
    for (int i = tid; i < n; i += 256) {
        int d = dst[base + i];
        int s = src[base + i];
        int b = d >> BSHIFT;
        int pos = atomicAdd(&lcur[b], 1);
        lsrc[pos] = s;
        ldst[pos] = d;
    }
    __syncthreads();
    for (int i = tid; i < n; i += 256) {
        int d = ldst[i];
        int b = d >> BSHIFT;
        int gpos = gbase[b] + (i - lpre[b]);
        bsrc[gpos] = lsrc[i];
        blow[gpos] = (unsigned short)(d & (BSIZE - 1));
    }
}

// ---------------- K4: per-bucket counting sort -> csr + rowst ----------------
__global__ __launch_bounds__(256) void node_sort_kernel(const int* __restrict__ bstart,
                                                        const int* __restrict__ bsrc,
                                                        const unsigned short* __restrict__ blow,
                                                        int* __restrict__ csr,
                                                        int* __restrict__ rowst) {
    __shared__ int lcnt[BSIZE];
    __shared__ int sc[256];
    __shared__ int lpre[BSIZE];
    __shared__ int lcur[BSIZE];
    int tid = threadIdx.x;
    int b = blockIdx.x;
    int ss = bstart[b], se = bstart[b + 1];
    lcnt[tid] = 0; lcnt[tid + 256] = 0;
    __syncthreads();
    for (int i = ss + tid; i < se; i += 256)
        atomicAdd(&lcnt[blow[i]], 1);
    __syncthreads();
    int a0 = lcnt[2 * tid], a1 = lcnt[2 * tid + 1];
    int s = a0 + a1;
    sc[tid] = s;
    __syncthreads();
    for (int off = 1; off < 256; off <<= 1) {
        int nv = (tid >= off) ? sc[tid - off] : 0;
        __syncthreads();
        sc[tid] += nv;
        __syncthreads();
    }
    int ex = sc[tid] - s;
    lpre[2 * tid] = ex;
    lpre[2 * tid + 1] = ex + a0;
    lcur[2 * tid] = ex;
    lcur[2 * tid + 1] = ex + a0;
    __syncthreads();
    int node_base = b << BSHIFT;
    for (int j = tid; j < BSIZE; j += 256) {
        int node = node_base + j;
        if (node < N_NODES) rowst[node] = ss + lpre[j];
    }
    for (int i = ss + tid; i < se; i += 256) {
        int nloc = blow[i];
        int pos = atomicAdd(&lcur[nloc], 1);
        csr[ss + pos] = bsrc[i];
    }
}

// ---------------- transform1: split tables T0/T1 = fp16(x @ W1a) ----------------
__global__ __launch_bounds__(256) void transform1_kernel(const float* __restrict__ x,
                                                         const float* __restrict__ W,
                                                         __half* __restrict__ T0,
                                                         __half* __restrict__ T1) {
    __shared__ float Wl[FEAT * DIM];
    for (int i = threadIdx.x; i < FEAT * DIM; i += blockDim.x) Wl[i] = W[i];
    __syncthreads();
    int lane = threadIdx.x & 31;
    int group = threadIdx.x >> 5;
    int gpb = blockDim.x >> 5;
    for (int node = blockIdx.x * gpb + group; node < N_NODES; node += gridDim.x * gpb) {
        const float* xr = x + (size_t)node * FEAT;
        float r0 = xr[lane];
        float r1 = xr[32 + lane];
        float r2 = (lane < FEAT - 64) ? xr[64 + lane] : 0.f;
        float acc = 0.f;
        #pragma unroll
        for (int k = 0; k < 32; ++k)
            acc += __shfl(r0, k, 32) * Wl[k * DIM + lane];
        #pragma unroll
        for (int k = 0; k < 32; ++k)
            acc += __shfl(r1, k, 32) * Wl[(32 + k) * DIM + lane];
        #pragma unroll
        for (int k = 0; k < FEAT - 64; ++k)
            acc += __shfl(r2, k, 32) * Wl[(64 + k) * DIM + lane];
        __half h = __float2half(acc);
        if (lane < HDIM) T0[(size_t)node * HDIM + lane] = h;
        else             T1[(size_t)node * HDIM + lane - HDIM] = h;
    }
}

// ---------------- prep: fold BN into next layer's Wa ----------------
__global__ __launch_bounds__(1024) void prep_kernel(const float* __restrict__ stats,
                                                    const float* __restrict__ gamma,
                                                    const float* __restrict__ beta,
                                                    const float* __restrict__ Wa,
                                                    float* __restrict__ Wp) {
    __shared__ float a[DIM], c[DIM];
    int tid = threadIdx.x;
    if (tid < DIM) {
        float mu = stats[tid] * (1.f / N_NODES);
        float var = stats[DIM + tid] * (1.f / N_NODES) - mu * mu;
        float av = gamma[tid] * rsqrtf(var + BN_EPS);
        a[tid] = av;
        c[tid] = beta[tid] - mu * av;
    }
    __syncthreads();
    int k = tid >> 5;
    Wp[tid] = a[k] * Wa[tid];
    if (tid < DIM) {
        float s = 0.f;
        for (int kk = 0; kk < DIM; ++kk)
            s += c[kk] * Wa[kk * DIM + tid];
        Wp[DIM * DIM + tid] = s;
    }
}

__global__ __launch_bounds__(1024) void prep_id_kernel(float* __restrict__ Wp) {
    int tid = threadIdx.x;
    Wp[tid] = ((tid >> 5) == (tid & 31)) ? 1.f : 0.f;
    if (tid < DIM) Wp[DIM * DIM + tid] = 0.f;
}

#define ACC8(v) do { const __half2* hp_ = (const __half2*)&(v); float2 f_; \
  f_ = __half22float2(hp_[0]); a0 += f_.x; a1 += f_.y; \
  f_ = __half22float2(hp_[1]); a2 += f_.x; a3 += f_.y; \
  f_ = __half22float2(hp_[2]); a4 += f_.x; a5 += f_.y; \
  f_ = __half22float2(hp_[3]); a6 += f_.x; a7 += f_.y; } while (0)

// Gather body: lane handles edge slots p+2j+e, chunk q (16B of 32B row).
#define GATHER_HALF(T) \
    int p = rs; \
    for (; p + 8 <= re; p += 8) { \
        int idx[4]; \
        _Pragma("unroll") \
        for (int j = 0; j < 4; ++j) idx[j] = csr[p + 2 * j + e]; \
        uint4 v[4]; \
        _Pragma("unroll") \
        for (int j = 0; j < 4; ++j) \
            v[j] = *(const uint4*)((T) + (size_t)idx[j] * HDIM + (q << 3)); \
        _Pragma("unroll") \
        for (int j = 0; j < 4; ++j) ACC8(v[j]); \
    } \
    if (p < re) { \
        _Pragma("unroll") \
        for (int j = 0; j < 4; ++j) { \
            int ei = p + 2 * j + e; \
            uint4 vv = {0, 0, 0, 0}; \
            if (ei < re) vv = *(const uint4*)((T) + (size_t)csr[ei] * HDIM + (q << 3)); \
            ACC8(vv); \
        } \
    } \
    a0 += __shfl_xor(a0, 2); a1 += __shfl_xor(a1, 2); \
    a2 += __shfl_xor(a2, 2); a3 += __shfl_xor(a3, 2); \
    a4 += __shfl_xor(a4, 2); a5 += __shfl_xor(a5, 2); \
    a6 += __shfl_xor(a6, 2); a7 += __shfl_xor(a7, 2);

// ---------------- pass A: aggregate half-table T0 -> A0 (fp32) ----------------
// lane l: node g=l>>2, edge slot e=(l>>1)&1, 16B chunk q=l&1. 3.2MB table: L2-resident.
__global__ __launch_bounds__(256) void agg_half_kernel(const __half* __restrict__ T,
                                                       const int* __restrict__ rowst,
                                                       const int* __restrict__ csr,
                                                       float* __restrict__ aggout) {
    int tid = threadIdx.x;
    int wave = tid >> 6;
    int l = tid & 63;
    int g = l >> 2, e = (l >> 1) & 1, q = l & 1;
    int tile = blockIdx.x * 4 + wave;
    if (tile >= NTILES) return;
    int node = tile * 16 + g;
    int rs = rowst[node], re = rowst[node + 1];
    float a0 = 0.f, a1 = 0.f, a2 = 0.f, a3 = 0.f,
          a4 = 0.f, a5 = 0.f, a6 = 0.f, a7 = 0.f;
    GATHER_HALF(T)
    if (e == 0) {
        uint4 vs = *(const uint4*)(T + (size_t)node * HDIM + (q << 3));
        ACC8(vs);
        float* op = aggout + (size_t)node * HDIM + (q << 3);
        float4 w0 = {a0, a1, a2, a3};
        float4 w1 = {a4, a5, a6, a7};
        *(float4*)op = w0;
        *(float4*)(op + 4) = w1;
    }
}

// ---------------- pass B: aggregate T1 + combine A0 + MFMA MLP + stats ----------------
__global__ __launch_bounds__(256) void agg_mlp_kernel(const __half* __restrict__ T1,
                                                      const float* __restrict__ agg0,
                                                      const int* __restrict__ rowst,
                                                      const int* __restrict__ csr,
                                                      const float* __restrict__ Wp,
                                                      const float* __restrict__ bias_a,
                                                      const float* __restrict__ Wb,
                                                      const float* __restrict__ bias_b,
                                                      __half* __restrict__ out0,
                                                      __half* __restrict__ out1,
                                                      float* __restrict__ stats) {
    __shared__ __align__(16) _Float16 Hl[4][512];
    __shared__ __align__(16) _Float16 H2[4][512];
    __shared__ __align__(16) _Float16 Fl[4][512];
    __shared__ __align__(16) float dg[4][16];
    int tid = threadIdx.x;
    int wave = tid >> 6;
    int l = tid & 63;
    int g = l >> 2, e = (l >> 1) & 1, q = l & 1;
    int d0 = l & 15, kg = l >> 4;
    int tile = blockIdx.x * 4 + wave;
    if (tile >= NTILES) return;
    int node = tile * 16 + g;
    int rs = rowst[node], re = rowst[node + 1];

    {
        float a0 = 0.f, a1 = 0.f, a2 = 0.f, a3 = 0.f,
              a4 = 0.f, a5 = 0.f, a6 = 0.f, a7 = 0.f;
        GATHER_HALF(T1)
        if (e == 0) {
            uint4 vs = *(const uint4*)(T1 + (size_t)node * HDIM + (q << 3));
            ACC8(vs);
            f16x8 hv;
            hv[0] = (_Float16)a0; hv[1] = (_Float16)a1;
            hv[2] = (_Float16)a2; hv[3] = (_Float16)a3;
            hv[4] = (_Float16)a4; hv[5] = (_Float16)a5;
            hv[6] = (_Float16)a6; hv[7] = (_Float16)a7;
            *(f16x8*)&Hl[wave][g * 32 + 16 + q * 8] = hv;
            if (q == 0) dg[wave][g] = (float)(re - rs + 1);
        } else {
            const float* ap = agg0 + (size_t)node * HDIM + (q << 3);
            float4 va0 = *(const float4*)ap;
            float4 va1 = *(const float4*)(ap + 4);
            f16x8 hv;
            hv[0] = (_Float16)va0.x; hv[1] = (_Float16)va0.y;
            hv[2] = (_Float16)va0.z; hv[3] = (_Float16)va0.w;
            hv[4] = (_Float16)va1.x; hv[5] = (_Float16)va1.y;
            hv[6] = (_Float16)va1.z; hv[7] = (_Float16)va1.w;
            *(f16x8*)&Hl[wave][g * 32 + q * 8] = hv;
        }
    }
    asm volatile("s_waitcnt lgkmcnt(0)" ::: "memory");
    __builtin_amdgcn_sched_barrier(0);

    // B fragments
    f16x8 bA0, bA1, bB0, bB1;
    #pragma unroll
    for (int ee = 0; ee < 8; ++ee) {
        int k = kg * 8 + ee;
        bA0[ee] = (_Float16)Wp[k * 32 + d0];
        bA1[ee] = (_Float16)Wp[k * 32 + d0 + 16];
        bB0[ee] = (_Float16)Wb[k * 32 + d0];
        bB1[ee] = (_Float16)Wb[k * 32 + d0 + 16];
    }
    float cw0 = Wp[DIM * DIM + d0], cw1 = Wp[DIM * DIM + d0 + 16];
    float ba0 = bias_a[d0], ba1 = bias_a[d0 + 16];
    float bb0 = bias_b[d0], bb1 = bias_b[d0 + 16];

    // MLP layer A
    {
        f16x8 af = *(f16x8*)&Hl[wave][d0 * 32 + kg * 8];
        f32x4 c0 = {ba0, ba0, ba0, ba0};
        f32x4 c1 = {ba1, ba1, ba1, ba1};
        c0 = __builtin_amdgcn_mfma_f32_16x16x32_f16(af, bA0, c0, 0, 0, 0);
        c1 = __builtin_amdgcn_mfma_f32_16x16x32_f16(af, bA1, c1, 0, 0, 0);
        f32x4 degv = *(f32x4*)&dg[wave][kg * 4];
        #pragma unroll
        for (int rr = 0; rr < 4; ++rr) {
            float v0 = fmaxf(c0[rr] + degv[rr] * cw0, 0.f);
            float v1 = fmaxf(c1[rr] + degv[rr] * cw1, 0.f);
            int row = kg * 4 + rr;
            H2[wave][row * 32 + d0] = (_Float16)v0;
            H2[wave][row * 32 + d0 + 16] = (_Float16)v1;
        }
    }
    asm volatile("s_waitcnt lgkmcnt(0)" ::: "memory");
    __builtin_amdgcn_sched_barrier(0);

    // MLP layer B + BN stats
    float s0 = 0.f, ss0 = 0.f, s1 = 0.f, ss1 = 0.f;
    {
        f16x8 a2f = *(f16x8*)&H2[wave][d0 * 32 + kg * 8];
        f32x4 c0 = {bb0, bb0, bb0, bb0};
        f32x4 c1 = {bb1, bb1, bb1, bb1};
        c0 = __builtin_amdgcn_mfma_f32_16x16x32_f16(a2f, bB0, c0, 0, 0, 0);
        c1 = __builtin_amdgcn_mfma_f32_16x16x32_f16(a2f, bB1, c1, 0, 0, 0);
        #pragma unroll
        for (int rr = 0; rr < 4; ++rr) {
            float y0 = fmaxf(c0[rr], 0.f);
            float y1 = fmaxf(c1[rr], 0.f);
            s0 += y0; ss0 += y0 * y0;
            s1 += y1; ss1 += y1 * y1;
            int row = kg * 4 + rr;
            Fl[wave][row * 32 + d0] = (_Float16)y0;
            Fl[wave][row * 32 + d0 + 16] = (_Float16)y1;
        }
    }
    asm volatile("s_waitcnt lgkmcnt(0)" ::: "memory");
    __builtin_amdgcn_sched_barrier(0);

    // store split halves + stats
    {
        uint4 v = *(uint4*)&Fl[wave][g * 32 + (e << 4) + q * 8];
        __half* op = e ? out1 : out0;
        *(uint4*)(op + (size_t)node * HDIM + (q << 3)) = v;

        s0 += __shfl_xor(s0, 16); s0 += __shfl_xor(s0, 32);
        ss0 += __shfl_xor(ss0, 16); ss0 += __shfl_xor(ss0, 32);
        s1 += __shfl_xor(s1, 16); s1 += __shfl_xor(s1, 32);
        ss1 += __shfl_xor(ss1, 16); ss1 += __shfl_xor(ss1, 32);
        if (kg == 0) {
            atomicAdd(&stats[d0], s0);
            atomicAdd(&stats[DIM + d0], ss0);
            atomicAdd(&stats[d0 + 16], s1);
            atomicAdd(&stats[DIM + d0 + 16], ss1);
        }
    }
}

// ---------------- final BN + global_add_pool (run-length, batch sorted) ----------------
#define POOL_BLOCKS 512
__global__ __launch_bounds__(256) void bn_pool_kernel(const __half* __restrict__ h0,
                                                      const __half* __restrict__ h1,
                                                      const float* __restrict__ stats,
                                                      const float* __restrict__ gamma,
                                                      const float* __restrict__ beta,
                                                      const int* __restrict__ batch,
                                                      float* __restrict__ pooled) {
    int lane = threadIdx.x & 31;
    int group = threadIdx.x >> 5;
    float mu = stats[lane] * (1.f / N_NODES);
    float var = stats[DIM + lane] * (1.f / N_NODES) - mu * mu;
    float inv = rsqrtf(var + BN_EPS);
    float a = gamma[lane] * inv;
    float c = beta[lane] - mu * a;
    const __half* hp = (lane < HDIM) ? h0 : h1;
    int loff = lane & (HDIM - 1);
    const int ngroups = POOL_BLOCKS * 8;
    const int chunk = (N_NODES + ngroups - 1) / ngroups;
    int g = blockIdx.x * 8 + group;
    int start = g * chunk;
    if (start >= N_NODES) return;
    int end = start + chunk; if (end > N_NODES) end = N_NODES;
    int cur = batch[start];
    float s = 0.f;
    for (int node = start; node < end; ++node) {
        float v = __half2float(hp[(size_t)node * HDIM + loff]) * a + c;
        int bg = batch[node];
        if (bg != cur) {
            atomicAdd(&pooled[cur * DIM + lane], s);
            s = 0.f;
            cur = bg;
        }
        s += v;
    }
    atomicAdd(&pooled[cur * DIM + lane], s);
}

// ---------------- out = relu(pooled @ Wfc + bfc) ----------------
__global__ __launch_bounds__(256) void fc_kernel(const float* __restrict__ pooled,
                                                 const float* __restrict__ Wfc,
                                                 const float* __restrict__ bfc,
                                                 float* __restrict__ out) {
    __shared__ float Wl[DIM * OUT_DIM];
    for (int i = threadIdx.x; i < DIM * OUT_DIM; i += blockDim.x) Wl[i] = Wfc[i];
    __syncthreads();
    int idx = blockIdx.x * blockDim.x + threadIdx.x;
    int stride = gridDim.x * blockDim.x;
    for (; idx < N_GRAPHS * OUT_DIM; idx += stride) {
        int g = idx >> 7;
        int o = idx & 127;
        float acc = bfc[o];
        #pragma unroll
        for (int k = 0; k < DIM; ++k)
            acc += pooled[g * DIM + k] * Wl[k * OUT_DIM + o];
        out[idx] = fmaxf(acc, 0.f);
    }
}

extern "C" void kernel_launch(void* const* d_in, const int* in_sizes, int n_in,
                              void* d_out, int out_size, void* d_ws, size_t ws_size,
                              hipStream_t stream) {
    const float* x   = (const float*)d_in[0];
    const int* eidx  = (const int*)d_in[1];
    const int* src   = eidx;
    const int* dst   = eidx + N_EDGES;
    const int* batch = (const int*)d_in[2];
    const float* W1a = (const float*)d_in[3];
    const float* b1a = (const float*)d_in[4];
    const float* W1b = (const float*)d_in[5];
    const float* b1b = (const float*)d_in[6];
    const float* Wa  = (const float*)d_in[7];
    const float* ba  = (const float*)d_in[8];
    const float* Wb  = (const float*)d_in[9];
    const float* bb  = (const float*)d_in[10];
    const float* gamma = (const float*)d_in[11];
    const float* beta  = (const float*)d_in[12];
    const float* Wfc = (const float*)d_in[13];
    const float* bfc = (const float*)d_in[14];
    float* out = (float*)d_out;

    const size_t TSZ = (size_t)N_NODES * HDIM;             // 1.6M elems
    __half* TA0 = (__half*)d_ws;
    __half* TA1 = TA0 + TSZ;
    __half* TB0 = TA1 + TSZ;
    __half* TB1 = TB0 + TSZ;                               // tables: 12.8 MB
    float* A0     = (float*)(TB1 + TSZ);                   // 6.4 MB
    float* stats  = A0 + TSZ;                              // 5*64
    float* pooled = stats + 5 * 64;                        // 65536
    float* Wp     = pooled + N_GRAPHS * DIM;               // 5*1056
    int* csr      = (int*)(Wp + 5 * 1056);                 // 3.2M
    int* rowst    = csr + N_EDGES;                         // N_NODES+1
    int* bcnt     = rowst + N_NODES + 1;                   // 256
    int* bstart   = bcnt + 256;                            // NB+1
    int* bcursor  = bstart + NB + 1;                       // 256
    unsigned short* blow = (unsigned short*)(bcursor + 256); // 6.4 MB

    int* bsrc = (int*)TA0;   // CSR-build scratch: 12.8 MB = the 4 tables (dead until transform1)

    hipMemsetAsync(bcnt, 0, 256 * sizeof(int), stream);
    hipMemsetAsync(stats, 0, 5 * 64 * sizeof(float), stream);
    hipMemsetAsync(pooled, 0, N_GRAPHS * DIM * sizeof(float), stream);

    bucket_hist_kernel<<<1024, 256, 0, stream>>>(dst, bcnt);
    bucket_scan_kernel<<<1, 256, 0, stream>>>(bcnt, bstart, bcursor, rowst);
    bucket_scatter_kernel<<<(N_EDGES + CHUNK - 1) / CHUNK, 256, 0, stream>>>(src, dst, bcursor, bsrc, blow);
    node_sort_kernel<<<NB, 256, 0, stream>>>(bstart, bsrc, blow, csr, rowst);

    transform1_kernel<<<2048, 256, 0, stream>>>(x, W1a, TA0, TA1);

    const __half *in0 = TA0, *in1 = TA1;
    __half *o0 = TB0, *o1 = TB1;

    prep_id_kernel<<<1, 1024, 0, stream>>>(Wp);
    agg_half_kernel<<<AGG_BLOCKS, 256, 0, stream>>>(in0, rowst, csr, A0);
    agg_mlp_kernel<<<AGG_BLOCKS, 256, 0, stream>>>(in1, A0, rowst, csr, Wp, b1a, W1b, b1b,
                                                   o0, o1, stats + 0);
    { const __half* t0 = in0; in0 = o0; o0 = (__half*)t0;
      const __half* t1 = in1; in1 = o1; o1 = (__half*)t1; }

    for (int i = 0; i < 4; ++i) {
        float* Wpi = Wp + (i + 1) * 1056;
        prep_kernel<<<1, 1024, 0, stream>>>(stats + i * 64, gamma + i * DIM, beta + i * DIM,
                                            Wa + i * DIM * DIM, Wpi);
        agg_half_kernel<<<AGG_BLOCKS, 256, 0, stream>>>(in0, rowst, csr, A0);
        agg_mlp_kernel<<<AGG_BLOCKS, 256, 0, stream>>>(in1, A0, rowst, csr, Wpi,
                                                       ba + i * DIM, Wb + i * DIM * DIM, bb + i * DIM,
                                                       o0, o1, stats + (i + 1) * 64);
        { const __half* t0 = in0; in0 = o0; o0 = (__half*)t0;
          const __half* t1 = in1; in1 = o1; o1 = (__half*)t1; }
    }

    bn_pool_kernel<<<POOL_BLOCKS, 256, 0, stream>>>(in0, in1, stats + 4 * 64,
                                                    gamma + 4 * DIM, beta + 4 * DIM, batch, pooled);
    fc_kernel<<<1024, 256, 0, stream>>>(pooled, Wfc, bfc, out);
}

// Round 8
// 898.527 us; speedup vs baseline: 1.3309x; 1.3309x over previous
//
#include <hip/hip_runtime.h>
#include <hip/hip_fp16.h>

#define N_NODES 100000
#define N_EDGES 3200000
#define N_GRAPHS 2048
#define DIM 32
#define HDIM 16
#define FEAT 78
#define OUT_DIM 128
#define BN_EPS 1e-5f

#define BSHIFT 9
#define BSIZE 512
#define NB ((N_NODES + BSIZE - 1) / BSIZE)
#define CHUNK 8192

#define NTILES (N_NODES / 16)          // 6250
#define AGG_BLOCKS ((NTILES + 3) / 4)  // 1563

typedef _Float16 f16x8 __attribute__((ext_vector_type(8)));
typedef float f32x4 __attribute__((ext_vector_type(4)));

// ---------------- K1: coarse bucket histogram ----------------
__global__ __launch_bounds__(256) void bucket_hist_kernel(const int* __restrict__ dst,
                                                          int* __restrict__ bcnt) {
    __shared__ int lh[256];
    int tid = threadIdx.x;
    lh[tid] = 0;
    __syncthreads();
    int i = blockIdx.x * blockDim.x + tid;
    int stride = gridDim.x * blockDim.x;
    for (; i < N_EDGES; i += stride)
        atomicAdd(&lh[dst[i] >> BSHIFT], 1);
    __syncthreads();
    if (tid < NB && lh[tid])
        atomicAdd(&bcnt[tid], lh[tid]);
}

// ---------------- K2: scan over buckets ----------------
__global__ __launch_bounds__(256) void bucket_scan_kernel(const int* __restrict__ bcnt,
                                                          int* __restrict__ bstart,
                                                          int* __restrict__ bcursor,
                                                          int* __restrict__ rowst) {
    __shared__ int sc[256];
    int tid = threadIdx.x;
    int v = (tid < NB) ? bcnt[tid] : 0;
    sc[tid] = v;
    __syncthreads();
    for (int off = 1; off < 256; off <<= 1) {
        int nv = (tid >= off) ? sc[tid - off] : 0;
        __syncthreads();
        sc[tid] += nv;
        __syncthreads();
    }
    if (tid < NB) {
        int ex = sc[tid] - v;
        bstart[tid] = ex;
        bcursor[tid] = ex;
    }
    if (tid == 0) {
        bstart[NB] = N_EDGES;
        rowst[N_NODES] = N_EDGES;
    }
}

// ---------------- K3: multisplit scatter into bucket segments ----------------
__global__ __launch_bounds__(256) void bucket_scatter_kernel(const int* __restrict__ src,
                                                             const int* __restrict__ dst,
                                                             int* __restrict__ bcursor,
                                                             int* __restrict__ bsrc,
                                                             unsigned short* __restrict__ blow) {
    __shared__ int lsrc[CHUNK];
    __shared__ int ldst[CHUNK];
    __shared__ int lhist[256];
    __shared__ int sc[256];
    __shared__ int lpre[256];
    __shared__ int gbase[256];
    __shared__ int lcur[256];
    int tid = threadIdx.x;
    int base = blockIdx.x * CHUNK;
    int n = N_EDGES - base; if (n > CHUNK) n = CHUNK;

    lhist[tid] = 0;
    __syncthreads();
    for (int i = tid; i < n; i += 256)
        atomicAdd(&lhist[dst[base + i] >> BSHIFT], 1);
    __syncthreads();
    int v = lhist[tid];
    sc[tid] = v;
    __syncthreads();
    for (int off = 1; off < 256; off <<= 1) {
        int nv = (tid >= off) ? sc[tid - off] : 0;
        __syncthreads();
        sc[tid] += nv;
        __syncthreads();
    }
    int ex = sc[tid] - v;
    lpre[tid] = ex;
    lcur[tid] = ex;
    if (tid < NB && v)
        gbase[tid] = atomicAdd(&bcursor[tid], v);
    __syncthreads();
    for (int i = tid; i < n; i += 256) {
        int d = dst[base + i];
        int s = src[base + i];
        int b = d >> BSHIFT;
        int pos = atomicAdd(&lcur[b], 1);
        lsrc[pos] = s;
        ldst[pos] = d;
    }
    __syncthreads();
    for (int i = tid; i < n; i += 256) {
        int d = ldst[i];
        int b = d >> BSHIFT;
        int gpos = gbase[b] + (i - lpre[b]);
        bsrc[gpos] = lsrc[i];
        blow[gpos] = (unsigned short)(d & (BSIZE - 1));
    }
}

// ---------------- K4: per-bucket counting sort -> csr + rowst ----------------
__global__ __launch_bounds__(256) void node_sort_kernel(const int* __restrict__ bstart,
                                                        const int* __restrict__ bsrc,
                                                        const unsigned short* __restrict__ blow,
                                                        int* __restrict__ csr,
                                                        int* __restrict__ rowst) {
    __shared__ int lcnt[BSIZE];
    __shared__ int sc[256];
    __shared__ int lpre[BSIZE];
    __shared__ int lcur[BSIZE];
    int tid = threadIdx.x;
    int b = blockIdx.x;
    int ss = bstart[b], se = bstart[b + 1];
    lcnt[tid] = 0; lcnt[tid + 256] = 0;
    __syncthreads();
    for (int i = ss + tid; i < se; i += 256)
        atomicAdd(&lcnt[blow[i]], 1);
    __syncthreads();
    int a0 = lcnt[2 * tid], a1 = lcnt[2 * tid + 1];
    int s = a0 + a1;
    sc[tid] = s;
    __syncthreads();
    for (int off = 1; off < 256; off <<= 1) {
        int nv = (tid >= off) ? sc[tid - off] : 0;
        __syncthreads();
        sc[tid] += nv;
        __syncthreads();
    }
    int ex = sc[tid] - s;
    lpre[2 * tid] = ex;
    lpre[2 * tid + 1] = ex + a0;
    lcur[2 * tid] = ex;
    lcur[2 * tid + 1] = ex + a0;
    __syncthreads();
    int node_base = b << BSHIFT;
    for (int j = tid; j < BSIZE; j += 256) {
        int node = node_base + j;
        if (node < N_NODES) rowst[node] = ss + lpre[j];
    }
    for (int i = ss + tid; i < se; i += 256) {
        int nloc = blow[i];
        int pos = atomicAdd(&lcur[nloc], 1);
        csr[ss + pos] = bsrc[i];
    }
}

// ---------------- deg+1 as float ----------------
__global__ __launch_bounds__(256) void deg_kernel(const int* __restrict__ rowst,
                                                  float* __restrict__ degf) {
    int i = blockIdx.x * blockDim.x + threadIdx.x;
    if (i < N_NODES)
        degf[i] = (float)(rowst[i + 1] - rowst[i] + 1);
}

// ---------------- transform1: split tables T0/T1 = fp16(x @ W1a) ----------------
__global__ __launch_bounds__(256) void transform1_kernel(const float* __restrict__ x,
                                                         const float* __restrict__ W,
                                                         __half* __restrict__ T0,
                                                         __half* __restrict__ T1) {
    __shared__ float Wl[FEAT * DIM];
    for (int i = threadIdx.x; i < FEAT * DIM; i += blockDim.x) Wl[i] = W[i];
    __syncthreads();
    int lane = threadIdx.x & 31;
    int group = threadIdx.x >> 5;
    int gpb = blockDim.x >> 5;
    for (int node = blockIdx.x * gpb + group; node < N_NODES; node += gridDim.x * gpb) {
        const float* xr = x + (size_t)node * FEAT;
        float r0 = xr[lane];
        float r1 = xr[32 + lane];
        float r2 = (lane < FEAT - 64) ? xr[64 + lane] : 0.f;
        float acc = 0.f;
        #pragma unroll
        for (int k = 0; k < 32; ++k)
            acc += __shfl(r0, k, 32) * Wl[k * DIM + lane];
        #pragma unroll
        for (int k = 0; k < 32; ++k)
            acc += __shfl(r1, k, 32) * Wl[(32 + k) * DIM + lane];
        #pragma unroll
        for (int k = 0; k < FEAT - 64; ++k)
            acc += __shfl(r2, k, 32) * Wl[(64 + k) * DIM + lane];
        __half h = __float2half(acc);
        if (lane < HDIM) T0[(size_t)node * HDIM + lane] = h;
        else             T1[(size_t)node * HDIM + lane - HDIM] = h;
    }
}

// ---------------- prep: BN-fold, weights transposed to fragment layout (f16) ----------------
// blob[d*32+k]       = f16( a[k] * Wa[k][d] )      (WpT)
// blob[1024+d*32+k]  = f16( Wb[k][d] )             (WbT)
// cwf[d]             = sum_k c[k] * Wa[k][d]
__global__ __launch_bounds__(1024) void prep_kernel(const float* __restrict__ stats,
                                                    const float* __restrict__ gamma,
                                                    const float* __restrict__ beta,
                                                    const float* __restrict__ Wa,
                                                    const float* __restrict__ Wb,
                                                    __half* __restrict__ blob,
                                                    float* __restrict__ cwf) {
    __shared__ float a[DIM], c[DIM];
    int tid = threadIdx.x;
    if (tid < DIM) {
        float mu = stats[tid] * (1.f / N_NODES);
        float var = stats[DIM + tid] * (1.f / N_NODES) - mu * mu;
        float av = gamma[tid] * rsqrtf(var + BN_EPS);
        a[tid] = av;
        c[tid] = beta[tid] - mu * av;
    }
    __syncthreads();
    int d = tid >> 5, k = tid & 31;
    blob[d * 32 + k] = __float2half(a[k] * Wa[k * 32 + d]);
    blob[1024 + d * 32 + k] = __float2half(Wb[k * 32 + d]);
    if (tid < DIM) {
        float s = 0.f;
        for (int kk = 0; kk < DIM; ++kk)
            s += c[kk] * Wa[kk * 32 + tid];
        cwf[tid] = s;
    }
}

__global__ __launch_bounds__(1024) void prep_id_kernel(const float* __restrict__ W1b,
                                                       __half* __restrict__ blob,
                                                       float* __restrict__ cwf) {
    int tid = threadIdx.x;
    int d = tid >> 5, k = tid & 31;
    blob[d * 32 + k] = __float2half((d == k) ? 1.f : 0.f);
    blob[1024 + d * 32 + k] = __float2half(W1b[k * 32 + d]);
    if (tid < DIM) cwf[tid] = 0.f;
}

#define ACC8(v) do { const __half2* hp_ = (const __half2*)&(v); float2 f_; \
  f_ = __half22float2(hp_[0]); a0 += f_.x; a1 += f_.y; \
  f_ = __half22float2(hp_[1]); a2 += f_.x; a3 += f_.y; \
  f_ = __half22float2(hp_[2]); a4 += f_.x; a5 += f_.y; \
  f_ = __half22float2(hp_[3]); a6 += f_.x; a7 += f_.y; } while (0)

// ---------------- agg_half: gather one half-table (L2-resident) -> A16 (combined, f16) ----
// lane l: node g=l>>2, edge-slot group e=(l>>1)&1 (4 consecutive edges), 16B chunk q=l&1.
__global__ __launch_bounds__(256) void agg_half_kernel(const __half* __restrict__ T,
                                                       const int* __restrict__ rowst,
                                                       const int* __restrict__ csr,
                                                       __half* __restrict__ outA) {
    int tid = threadIdx.x;
    int wave = tid >> 6;
    int l = tid & 63;
    int g = l >> 2, e = (l >> 1) & 1, q = l & 1;
    int tile = blockIdx.x * 4 + wave;
    if (tile >= NTILES) return;
    int node = tile * 16 + g;
    int rs = rowst[node], re = rowst[node + 1];
    float a0 = 0.f, a1 = 0.f, a2 = 0.f, a3 = 0.f,
          a4 = 0.f, a5 = 0.f, a6 = 0.f, a7 = 0.f;
    int p = rs;
    for (; p + 8 <= re; p += 8) {
        int base = p + 4 * e;
        int i0 = csr[base], i1 = csr[base + 1], i2 = csr[base + 2], i3 = csr[base + 3];
        uint4 v0 = *(const uint4*)(T + (size_t)i0 * HDIM + (q << 3));
        uint4 v1 = *(const uint4*)(T + (size_t)i1 * HDIM + (q << 3));
        uint4 v2 = *(const uint4*)(T + (size_t)i2 * HDIM + (q << 3));
        uint4 v3 = *(const uint4*)(T + (size_t)i3 * HDIM + (q << 3));
        ACC8(v0); ACC8(v1); ACC8(v2); ACC8(v3);
    }
    if (p < re) {
        #pragma unroll
        for (int j = 0; j < 4; ++j) {
            int ei = p + 4 * e + j;
            uint4 vv = {0, 0, 0, 0};
            if (ei < re) vv = *(const uint4*)(T + (size_t)csr[ei] * HDIM + (q << 3));
            ACC8(vv);
        }
    }
    // reduce over e (lane bit 1)
    a0 += __shfl_xor(a0, 2); a1 += __shfl_xor(a1, 2);
    a2 += __shfl_xor(a2, 2); a3 += __shfl_xor(a3, 2);
    a4 += __shfl_xor(a4, 2); a5 += __shfl_xor(a5, 2);
    a6 += __shfl_xor(a6, 2); a7 += __shfl_xor(a7, 2);
    if (e == 0) {
        uint4 vs = *(const uint4*)(T + (size_t)node * HDIM + (q << 3));
        ACC8(vs);
        f16x8 hv;
        hv[0] = (_Float16)a0; hv[1] = (_Float16)a1;
        hv[2] = (_Float16)a2; hv[3] = (_Float16)a3;
        hv[4] = (_Float16)a4; hv[5] = (_Float16)a5;
        hv[6] = (_Float16)a6; hv[7] = (_Float16)a7;
        *(f16x8*)(outA + (size_t)node * DIM + (q << 3)) = hv;
    }
}

// ---------------- mlp: streaming MFMA over nodes (no gather) ----------------
// One wave per 16-node tile. A-frag loaded directly from A16 in fragment layout.
__global__ __launch_bounds__(256) void mlp_kernel(const __half* __restrict__ A16,
                                                  const float* __restrict__ degf,
                                                  const __half* __restrict__ blob,
                                                  const float* __restrict__ cwf,
                                                  const float* __restrict__ bias_a,
                                                  const float* __restrict__ bias_b,
                                                  __half* __restrict__ out0,
                                                  __half* __restrict__ out1,
                                                  float* __restrict__ stats) {
    __shared__ __align__(16) _Float16 X[4][512];
    int tid = threadIdx.x;
    int wave = tid >> 6;
    int l = tid & 63;
    int d0 = l & 15, kg = l >> 4;
    int tile = blockIdx.x * 4 + wave;
    if (tile >= NTILES) return;
    int tb = tile * 16;

    f16x8 af = *(const f16x8*)(A16 + (size_t)(tb + d0) * DIM + kg * 8);
    f16x8 bA0 = *(const f16x8*)(blob + d0 * 32 + kg * 8);
    f16x8 bA1 = *(const f16x8*)(blob + (d0 + 16) * 32 + kg * 8);
    f16x8 bB0 = *(const f16x8*)(blob + 1024 + d0 * 32 + kg * 8);
    f16x8 bB1 = *(const f16x8*)(blob + 1024 + (d0 + 16) * 32 + kg * 8);
    f32x4 degv = *(const f32x4*)(degf + tb + kg * 4);
    float cw0 = cwf[d0], cw1 = cwf[d0 + 16];
    float ba0 = bias_a[d0], ba1 = bias_a[d0 + 16];
    float bb0 = bias_b[d0], bb1 = bias_b[d0 + 16];

    // layer A
    f32x4 c0 = {ba0, ba0, ba0, ba0};
    f32x4 c1 = {ba1, ba1, ba1, ba1};
    c0 = __builtin_amdgcn_mfma_f32_16x16x32_f16(af, bA0, c0, 0, 0, 0);
    c1 = __builtin_amdgcn_mfma_f32_16x16x32_f16(af, bA1, c1, 0, 0, 0);
    #pragma unroll
    for (int rr = 0; rr < 4; ++rr) {
        float v0 = fmaxf(c0[rr] + degv[rr] * cw0, 0.f);
        float v1 = fmaxf(c1[rr] + degv[rr] * cw1, 0.f);
        int row = kg * 4 + rr;
        X[wave][row * 32 + d0] = (_Float16)v0;
        X[wave][row * 32 + d0 + 16] = (_Float16)v1;
    }
    __builtin_amdgcn_wave_barrier();
    f16x8 af2 = *(f16x8*)&X[wave][d0 * 32 + kg * 8];
    __builtin_amdgcn_wave_barrier();

    // layer B
    f32x4 e0 = {bb0, bb0, bb0, bb0};
    f32x4 e1 = {bb1, bb1, bb1, bb1};
    e0 = __builtin_amdgcn_mfma_f32_16x16x32_f16(af2, bB0, e0, 0, 0, 0);
    e1 = __builtin_amdgcn_mfma_f32_16x16x32_f16(af2, bB1, e1, 0, 0, 0);
    float s0 = 0.f, ss0 = 0.f, s1 = 0.f, ss1 = 0.f;
    #pragma unroll
    for (int rr = 0; rr < 4; ++rr) {
        float y0 = fmaxf(e0[rr], 0.f);
        float y1 = fmaxf(e1[rr], 0.f);
        s0 += y0; ss0 += y0 * y0;
        s1 += y1; ss1 += y1 * y1;
        int row = kg * 4 + rr;
        X[wave][row * 32 + d0] = (_Float16)y0;
        X[wave][row * 32 + d0 + 16] = (_Float16)y1;
    }
    __builtin_amdgcn_wave_barrier();
    // node-major readback -> split coalesced store
    {
        int gg = l >> 2, c = l & 3;
        uint4 vv = *(uint4*)&X[wave][gg * 32 + c * 8];
        __half* op = (c & 2) ? out1 : out0;
        *(uint4*)(op + (size_t)(tb + gg) * HDIM + (c & 1) * 8) = vv;
    }
    // BN stats
    s0 += __shfl_xor(s0, 16); s0 += __shfl_xor(s0, 32);
    ss0 += __shfl_xor(ss0, 16); ss0 += __shfl_xor(ss0, 32);
    s1 += __shfl_xor(s1, 16); s1 += __shfl_xor(s1, 32);
    ss1 += __shfl_xor(ss1, 16); ss1 += __shfl_xor(ss1, 32);
    if (kg == 0) {
        atomicAdd(&stats[d0], s0);
        atomicAdd(&stats[DIM + d0], ss0);
        atomicAdd(&stats[d0 + 16], s1);
        atomicAdd(&stats[DIM + d0 + 16], ss1);
    }
}

// ---------------- final BN + global_add_pool (run-length, batch sorted) ----------------
#define POOL_BLOCKS 512
__global__ __launch_bounds__(256) void bn_pool_kernel(const __half* __restrict__ h0,
                                                      const __half* __restrict__ h1,
                                                      const float* __restrict__ stats,
                                                      const float* __restrict__ gamma,
                                                      const float* __restrict__ beta,
                                                      const int* __restrict__ batch,
                                                      float* __restrict__ pooled) {
    int lane = threadIdx.x & 31;
    int group = threadIdx.x >> 5;
    float mu = stats[lane] * (1.f / N_NODES);
    float var = stats[DIM + lane] * (1.f / N_NODES) - mu * mu;
    float inv = rsqrtf(var + BN_EPS);
    float a = gamma[lane] * inv;
    float c = beta[lane] - mu * a;
    const __half* hp = (lane < HDIM) ? h0 : h1;
    int loff = lane & (HDIM - 1);
    const int ngroups = POOL_BLOCKS * 8;
    const int chunk = (N_NODES + ngroups - 1) / ngroups;
    int g = blockIdx.x * 8 + group;
    int start = g * chunk;
    if (start >= N_NODES) return;
    int end = start + chunk; if (end > N_NODES) end = N_NODES;
    int cur = batch[start];
    float s = 0.f;
    for (int node = start; node < end; ++node) {
        float v = __half2float(hp[(size_t)node * HDIM + loff]) * a + c;
        int bg = batch[node];
        if (bg != cur) {
            atomicAdd(&pooled[cur * DIM + lane], s);
            s = 0.f;
            cur = bg;
        }
        s += v;
    }
    atomicAdd(&pooled[cur * DIM + lane], s);
}

// ---------------- out = relu(pooled @ Wfc + bfc) ----------------
__global__ __launch_bounds__(256) void fc_kernel(const float* __restrict__ pooled,
                                                 const float* __restrict__ Wfc,
                                                 const float* __restrict__ bfc,
                                                 float* __restrict__ out) {
    __shared__ float Wl[DIM * OUT_DIM];
    for (int i = threadIdx.x; i < DIM * OUT_DIM; i += blockDim.x) Wl[i] = Wfc[i];
    __syncthreads();
    int idx = blockIdx.x * blockDim.x + threadIdx.x;
    int stride = gridDim.x * blockDim.x;
    for (; idx < N_GRAPHS * OUT_DIM; idx += stride) {
        int g = idx >> 7;
        int o = idx & 127;
        float acc = bfc[o];
        #pragma unroll
        for (int k = 0; k < DIM; ++k)
            acc += pooled[g * DIM + k] * Wl[k * OUT_DIM + o];
        out[idx] = fmaxf(acc, 0.f);
    }
}

extern "C" void kernel_launch(void* const* d_in, const int* in_sizes, int n_in,
                              void* d_out, int out_size, void* d_ws, size_t ws_size,
                              hipStream_t stream) {
    const float* x   = (const float*)d_in[0];
    const int* eidx  = (const int*)d_in[1];
    const int* src   = eidx;
    const int* dst   = eidx + N_EDGES;
    const int* batch = (const int*)d_in[2];
    const float* W1a = (const float*)d_in[3];
    const float* b1a = (const float*)d_in[4];
    const float* W1b = (const float*)d_in[5];
    const float* b1b = (const float*)d_in[6];
    const float* Wa  = (const float*)d_in[7];
    const float* ba  = (const float*)d_in[8];
    const float* Wb  = (const float*)d_in[9];
    const float* bb  = (const float*)d_in[10];
    const float* gamma = (const float*)d_in[11];
    const float* beta  = (const float*)d_in[12];
    const float* Wfc = (const float*)d_in[13];
    const float* bfc = (const float*)d_in[14];
    float* out = (float*)d_out;

    const size_t TSZ = (size_t)N_NODES * HDIM;               // 1.6M halfs
    __half* TA0 = (__half*)d_ws;
    __half* TA1 = TA0 + TSZ;
    __half* TB0 = TA1 + TSZ;
    __half* TB1 = TB0 + TSZ;                                 // 12.8 MB
    __half* A16 = TB1 + TSZ;                                 // 3.2M halfs = 6.4 MB
    float* degf   = (float*)(A16 + (size_t)N_NODES * DIM);   // 400 KB
    float* stats  = degf + N_NODES;                          // 5*64
    float* pooled = stats + 5 * 64;                          // 256 KB
    float* cwf    = pooled + N_GRAPHS * DIM;                 // 5*32
    __half* blobs = (__half*)(cwf + 5 * 32);                 // 5*2048 halfs
    int* csr      = (int*)(blobs + 5 * 2048);                // 12.8 MB
    int* rowst    = csr + N_EDGES;                           // N_NODES+1
    int* bcnt     = rowst + N_NODES + 1;
    int* bstart   = bcnt + 256;
    int* bcursor  = bstart + NB + 1;

    // CSR-build scratch aliases (dead before first use of their hosts)
    int* bsrc            = (int*)TA0;   // 12.8 MB over the 4 T tables
    unsigned short* blow = (unsigned short*)A16;  // 6.4 MB over A16

    hipMemsetAsync(bcnt, 0, 256 * sizeof(int), stream);
    hipMemsetAsync(stats, 0, 5 * 64 * sizeof(float), stream);
    hipMemsetAsync(pooled, 0, N_GRAPHS * DIM * sizeof(float), stream);

    bucket_hist_kernel<<<1024, 256, 0, stream>>>(dst, bcnt);
    bucket_scan_kernel<<<1, 256, 0, stream>>>(bcnt, bstart, bcursor, rowst);
    bucket_scatter_kernel<<<(N_EDGES + CHUNK - 1) / CHUNK, 256, 0, stream>>>(src, dst, bcursor, bsrc, blow);
    node_sort_kernel<<<NB, 256, 0, stream>>>(bstart, bsrc, blow, csr, rowst);

    deg_kernel<<<(N_NODES + 255) / 256, 256, 0, stream>>>(rowst, degf);
    transform1_kernel<<<2048, 256, 0, stream>>>(x, W1a, TA0, TA1);

    prep_id_kernel<<<1, 1024, 0, stream>>>(W1b, blobs, cwf);

    const __half *in0 = TA0, *in1 = TA1;
    __half *o0 = TB0, *o1 = TB1;

    // layer 1
    agg_half_kernel<<<AGG_BLOCKS, 256, 0, stream>>>(in0, rowst, csr, A16);
    agg_half_kernel<<<AGG_BLOCKS, 256, 0, stream>>>(in1, rowst, csr, A16 + HDIM);
    mlp_kernel<<<AGG_BLOCKS, 256, 0, stream>>>(A16, degf, blobs, cwf, b1a, b1b, o0, o1, stats + 0);
    { const __half* t0 = in0; in0 = o0; o0 = (__half*)t0;
      const __half* t1 = in1; in1 = o1; o1 = (__half*)t1; }

    for (int i = 0; i < 4; ++i) {
        __half* blob_i = blobs + (i + 1) * 2048;
        float* cwf_i = cwf + (i + 1) * 32;
        prep_kernel<<<1, 1024, 0, stream>>>(stats + i * 64, gamma + i * DIM, beta + i * DIM,
                                            Wa + i * DIM * DIM, Wb + i * DIM * DIM, blob_i, cwf_i);
        agg_half_kernel<<<AGG_BLOCKS, 256, 0, stream>>>(in0, rowst, csr, A16);
        agg_half_kernel<<<AGG_BLOCKS, 256, 0, stream>>>(in1, rowst, csr, A16 + HDIM);
        mlp_kernel<<<AGG_BLOCKS, 256, 0, stream>>>(A16, degf, blob_i, cwf_i,
                                                   ba + i * DIM, bb + i * DIM, o0, o1,
                                                   stats + (i + 1) * 64);
        { const __half* t0 = in0; in0 = o0; o0 = (__half*)t0;
          const __half* t1 = in1; in1 = o1; o1 = (__half*)t1; }
    }

    bn_pool_kernel<<<POOL_BLOCKS, 256, 0, stream>>>(in0, in1, stats + 4 * 64,
                                                    gamma + 4 * DIM, beta + 4 * DIM, batch, pooled);
    fc_kernel<<<1024, 256, 0, stream>>>(pooled, Wfc, bfc, out);
}

// Round 9
// 516.203 us; speedup vs baseline: 2.3165x; 1.7406x over previous
//
#include <hip/hip_runtime.h>
#include <hip/hip_fp16.h>

#define N_NODES 100000
#define N_EDGES 3200000
#define N_GRAPHS 2048
#define DIM 32
#define HDIM 16
#define FEAT 78
#define OUT_DIM 128
#define BN_EPS 1e-5f

#define BSHIFT 9
#define BSIZE 512
#define NB ((N_NODES + BSIZE - 1) / BSIZE)
#define CHUNK 8192

#define NTILES (N_NODES / 16)          // 6250
#define AGG_BLOCKS ((NTILES + 3) / 4)  // 1563
#define SBINS 64                        // stats bins (contention spreading)

typedef _Float16 f16x8 __attribute__((ext_vector_type(8)));
typedef float f32x4 __attribute__((ext_vector_type(4)));

// ---------------- K1: coarse bucket histogram ----------------
__global__ __launch_bounds__(256) void bucket_hist_kernel(const int* __restrict__ dst,
                                                          int* __restrict__ bcnt) {
    __shared__ int lh[256];
    int tid = threadIdx.x;
    lh[tid] = 0;
    __syncthreads();
    int i = blockIdx.x * blockDim.x + tid;
    int stride = gridDim.x * blockDim.x;
    for (; i < N_EDGES; i += stride)
        atomicAdd(&lh[dst[i] >> BSHIFT], 1);
    __syncthreads();
    if (tid < NB && lh[tid])
        atomicAdd(&bcnt[tid], lh[tid]);
}

// ---------------- K2: scan over buckets ----------------
__global__ __launch_bounds__(256) void bucket_scan_kernel(const int* __restrict__ bcnt,
                                                          int* __restrict__ bstart,
                                                          int* __restrict__ bcursor,
                                                          int* __restrict__ rowst) {
    __shared__ int sc[256];
    int tid = threadIdx.x;
    int v = (tid < NB) ? bcnt[tid] : 0;
    sc[tid] = v;
    __syncthreads();
    for (int off = 1; off < 256; off <<= 1) {
        int nv = (tid >= off) ? sc[tid - off] : 0;
        __syncthreads();
        sc[tid] += nv;
        __syncthreads();
    }
    if (tid < NB) {
        int ex = sc[tid] - v;
        bstart[tid] = ex;
        bcursor[tid] = ex;
    }
    if (tid == 0) {
        bstart[NB] = N_EDGES;
        rowst[N_NODES] = N_EDGES;
    }
}

// ---------------- K3: multisplit scatter into bucket segments ----------------
__global__ __launch_bounds__(256) void bucket_scatter_kernel(const int* __restrict__ src,
                                                             const int* __restrict__ dst,
                                                             int* __restrict__ bcursor,
                                                             int* __restrict__ bsrc,
                                                             unsigned short* __restrict__ blow) {
    __shared__ int lsrc[CHUNK];
    __shared__ int ldst[CHUNK];
    __shared__ int lhist[256];
    __shared__ int sc[256];
    __shared__ int lpre[256];
    __shared__ int gbase[256];
    __shared__ int lcur[256];
    int tid = threadIdx.x;
    int base = blockIdx.x * CHUNK;
    int n = N_EDGES - base; if (n > CHUNK) n = CHUNK;

    lhist[tid] = 0;
    __syncthreads();
    for (int i = tid; i < n; i += 256)
        atomicAdd(&lhist[dst[base + i] >> BSHIFT], 1);
    __syncthreads();
    int v = lhist[tid];
    sc[tid] = v;
    __syncthreads();
    for (int off = 1; off < 256; off <<= 1) {
        int nv = (tid >= off) ? sc[tid - off] : 0;
        __syncthreads();
        sc[tid] += nv;
        __syncthreads();
    }
    int ex = sc[tid] - v;
    lpre[tid] = ex;
    lcur[tid] = ex;
    if (tid < NB && v)
        gbase[tid] = atomicAdd(&bcursor[tid], v);
    __syncthreads();
    for (int i = tid; i < n; i += 256) {
        int d = dst[base + i];
        int s = src[base + i];
        int b = d >> BSHIFT;
        int pos = atomicAdd(&lcur[b], 1);
        lsrc[pos] = s;
        ldst[pos] = d;
    }
    __syncthreads();
    for (int i = tid; i < n; i += 256) {
        int d = ldst[i];
        int b = d >> BSHIFT;
        int gpos = gbase[b] + (i - lpre[b]);
        bsrc[gpos] = lsrc[i];
        blow[gpos] = (unsigned short)(d & (BSIZE - 1));
    }
}

// ---------------- K4: per-bucket counting sort -> csr + rowst ----------------
__global__ __launch_bounds__(256) void node_sort_kernel(const int* __restrict__ bstart,
                                                        const int* __restrict__ bsrc,
                                                        const unsigned short* __restrict__ blow,
                                                        int* __restrict__ csr,
                                                        int* __restrict__ rowst) {
    __shared__ int lcnt[BSIZE];
    __shared__ int sc[256];
    __shared__ int lpre[BSIZE];
    __shared__ int lcur[BSIZE];
    int tid = threadIdx.x;
    int b = blockIdx.x;
    int ss = bstart[b], se = bstart[b + 1];
    lcnt[tid] = 0; lcnt[tid + 256] = 0;
    __syncthreads();
    for (int i = ss + tid; i < se; i += 256)
        atomicAdd(&lcnt[blow[i]], 1);
    __syncthreads();
    int a0 = lcnt[2 * tid], a1 = lcnt[2 * tid + 1];
    int s = a0 + a1;
    sc[tid] = s;
    __syncthreads();
    for (int off = 1; off < 256; off <<= 1) {
        int nv = (tid >= off) ? sc[tid - off] : 0;
        __syncthreads();
        sc[tid] += nv;
        __syncthreads();
    }
    int ex = sc[tid] - s;
    lpre[2 * tid] = ex;
    lpre[2 * tid + 1] = ex + a0;
    lcur[2 * tid] = ex;
    lcur[2 * tid + 1] = ex + a0;
    __syncthreads();
    int node_base = b << BSHIFT;
    for (int j = tid; j < BSIZE; j += 256) {
        int node = node_base + j;
        if (node < N_NODES) rowst[node] = ss + lpre[j];
    }
    for (int i = ss + tid; i < se; i += 256) {
        int nloc = blow[i];
        int pos = atomicAdd(&lcur[nloc], 1);
        csr[ss + pos] = bsrc[i];
    }
}

// ---------------- deg+1 as float ----------------
__global__ __launch_bounds__(256) void deg_kernel(const int* __restrict__ rowst,
                                                  float* __restrict__ degf) {
    int i = blockIdx.x * blockDim.x + threadIdx.x;
    if (i < N_NODES)
        degf[i] = (float)(rowst[i + 1] - rowst[i] + 1);
}

// ---------------- transform1: split tables T0/T1 = fp16(x @ W1a) ----------------
__global__ __launch_bounds__(256) void transform1_kernel(const float* __restrict__ x,
                                                         const float* __restrict__ W,
                                                         __half* __restrict__ T0,
                                                         __half* __restrict__ T1) {
    __shared__ float Wl[FEAT * DIM];
    for (int i = threadIdx.x; i < FEAT * DIM; i += blockDim.x) Wl[i] = W[i];
    __syncthreads();
    int lane = threadIdx.x & 31;
    int group = threadIdx.x >> 5;
    int gpb = blockDim.x >> 5;
    for (int node = blockIdx.x * gpb + group; node < N_NODES; node += gridDim.x * gpb) {
        const float* xr = x + (size_t)node * FEAT;
        float r0 = xr[lane];
        float r1 = xr[32 + lane];
        float r2 = (lane < FEAT - 64) ? xr[64 + lane] : 0.f;
        float acc = 0.f;
        #pragma unroll
        for (int k = 0; k < 32; ++k)
            acc += __shfl(r0, k, 32) * Wl[k * DIM + lane];
        #pragma unroll
        for (int k = 0; k < 32; ++k)
            acc += __shfl(r1, k, 32) * Wl[(32 + k) * DIM + lane];
        #pragma unroll
        for (int k = 0; k < FEAT - 64; ++k)
            acc += __shfl(r2, k, 32) * Wl[(64 + k) * DIM + lane];
        __half h = __float2half(acc);
        if (lane < HDIM) T0[(size_t)node * HDIM + lane] = h;
        else             T1[(size_t)node * HDIM + lane - HDIM] = h;
    }
}

// ---------------- prep: reduce stat bins + BN-fold, weights in fragment layout ----------------
__global__ __launch_bounds__(1024) void prep_kernel(const float* __restrict__ sbins,
                                                    const float* __restrict__ gamma,
                                                    const float* __restrict__ beta,
                                                    const float* __restrict__ Wa,
                                                    const float* __restrict__ Wb,
                                                    __half* __restrict__ blob,
                                                    float* __restrict__ cwf) {
    __shared__ float st[64];
    __shared__ float a[DIM], c[DIM];
    int tid = threadIdx.x;
    if (tid < 64) {
        float s = 0.f;
        for (int b = 0; b < SBINS; ++b) s += sbins[b * 64 + tid];
        st[tid] = s;
    }
    __syncthreads();
    if (tid < DIM) {
        float mu = st[tid] * (1.f / N_NODES);
        float var = st[DIM + tid] * (1.f / N_NODES) - mu * mu;
        float av = gamma[tid] * rsqrtf(var + BN_EPS);
        a[tid] = av;
        c[tid] = beta[tid] - mu * av;
    }
    __syncthreads();
    int d = tid >> 5, k = tid & 31;
    blob[d * 32 + k] = __float2half(a[k] * Wa[k * 32 + d]);
    blob[1024 + d * 32 + k] = __float2half(Wb[k * 32 + d]);
    if (tid < DIM) {
        float s = 0.f;
        for (int kk = 0; kk < DIM; ++kk)
            s += c[kk] * Wa[kk * 32 + tid];
        cwf[tid] = s;
    }
}

__global__ __launch_bounds__(1024) void prep_id_kernel(const float* __restrict__ W1b,
                                                       __half* __restrict__ blob,
                                                       float* __restrict__ cwf) {
    int tid = threadIdx.x;
    int d = tid >> 5, k = tid & 31;
    blob[d * 32 + k] = __float2half((d == k) ? 1.f : 0.f);
    blob[1024 + d * 32 + k] = __float2half(W1b[k * 32 + d]);
    if (tid < DIM) cwf[tid] = 0.f;
}

#define ACC8(v) do { const __half2* hp_ = (const __half2*)&(v); float2 f_; \
  f_ = __half22float2(hp_[0]); a0 += f_.x; a1 += f_.y; \
  f_ = __half22float2(hp_[1]); a2 += f_.x; a3 += f_.y; \
  f_ = __half22float2(hp_[2]); a4 += f_.x; a5 += f_.y; \
  f_ = __half22float2(hp_[3]); a6 += f_.x; a7 += f_.y; } while (0)

// ---------------- agg_half: gather one half-table (L2-resident) -> A16 (combined, f16) ----
// lane l: node g=l>>2, edge-slot group e=(l>>1)&1 (8 consecutive edges), 16B chunk q=l&1.
// 16-edge rounds: 8 chunk-gathers in flight per lane.
__global__ __launch_bounds__(256) void agg_half_kernel(const __half* __restrict__ T,
                                                       const int* __restrict__ rowst,
                                                       const int* __restrict__ csr,
                                                       __half* __restrict__ outA) {
    int tid = threadIdx.x;
    int wave = tid >> 6;
    int l = tid & 63;
    int g = l >> 2, e = (l >> 1) & 1, q = l & 1;
    int tile = blockIdx.x * 4 + wave;
    if (tile >= NTILES) return;
    int node = tile * 16 + g;
    int rs = rowst[node], re = rowst[node + 1];
    float a0 = 0.f, a1 = 0.f, a2 = 0.f, a3 = 0.f,
          a4 = 0.f, a5 = 0.f, a6 = 0.f, a7 = 0.f;
    int p = rs;
    for (; p + 16 <= re; p += 16) {
        int base = p + 8 * e;
        int idx[8];
        #pragma unroll
        for (int j = 0; j < 8; ++j) idx[j] = csr[base + j];
        uint4 v[8];
        #pragma unroll
        for (int j = 0; j < 8; ++j)
            v[j] = *(const uint4*)(T + (size_t)idx[j] * HDIM + (q << 3));
        #pragma unroll
        for (int j = 0; j < 8; ++j) ACC8(v[j]);
    }
    if (p < re) {
        #pragma unroll
        for (int j = 0; j < 8; ++j) {
            int ei = p + 8 * e + j;
            uint4 vv = {0, 0, 0, 0};
            if (ei < re) vv = *(const uint4*)(T + (size_t)csr[ei] * HDIM + (q << 3));
            ACC8(vv);
        }
    }
    // reduce over e (lane bit 1)
    a0 += __shfl_xor(a0, 2); a1 += __shfl_xor(a1, 2);
    a2 += __shfl_xor(a2, 2); a3 += __shfl_xor(a3, 2);
    a4 += __shfl_xor(a4, 2); a5 += __shfl_xor(a5, 2);
    a6 += __shfl_xor(a6, 2); a7 += __shfl_xor(a7, 2);
    if (e == 0) {
        uint4 vs = *(const uint4*)(T + (size_t)node * HDIM + (q << 3));
        ACC8(vs);
        f16x8 hv;
        hv[0] = (_Float16)a0; hv[1] = (_Float16)a1;
        hv[2] = (_Float16)a2; hv[3] = (_Float16)a3;
        hv[4] = (_Float16)a4; hv[5] = (_Float16)a5;
        hv[6] = (_Float16)a6; hv[7] = (_Float16)a7;
        *(f16x8*)(outA + (size_t)node * DIM + (q << 3)) = hv;
    }
}

// ---------------- mlp: streaming MFMA over nodes; binned BN stats ----------------
__global__ __launch_bounds__(256) void mlp_kernel(const __half* __restrict__ A16,
                                                  const float* __restrict__ degf,
                                                  const __half* __restrict__ blob,
                                                  const float* __restrict__ cwf,
                                                  const float* __restrict__ bias_a,
                                                  const float* __restrict__ bias_b,
                                                  __half* __restrict__ out0,
                                                  __half* __restrict__ out1,
                                                  float* __restrict__ sbins) {
    __shared__ __align__(16) _Float16 X[4][512];
    int tid = threadIdx.x;
    int wave = tid >> 6;
    int l = tid & 63;
    int d0 = l & 15, kg = l >> 4;
    int tile = blockIdx.x * 4 + wave;
    if (tile >= NTILES) return;
    int tb = tile * 16;

    f16x8 af = *(const f16x8*)(A16 + (size_t)(tb + d0) * DIM + kg * 8);
    f16x8 bA0 = *(const f16x8*)(blob + d0 * 32 + kg * 8);
    f16x8 bA1 = *(const f16x8*)(blob + (d0 + 16) * 32 + kg * 8);
    f16x8 bB0 = *(const f16x8*)(blob + 1024 + d0 * 32 + kg * 8);
    f16x8 bB1 = *(const f16x8*)(blob + 1024 + (d0 + 16) * 32 + kg * 8);
    f32x4 degv = *(const f32x4*)(degf + tb + kg * 4);
    float cw0 = cwf[d0], cw1 = cwf[d0 + 16];
    float ba0 = bias_a[d0], ba1 = bias_a[d0 + 16];
    float bb0 = bias_b[d0], bb1 = bias_b[d0 + 16];

    // layer A
    f32x4 c0 = {ba0, ba0, ba0, ba0};
    f32x4 c1 = {ba1, ba1, ba1, ba1};
    c0 = __builtin_amdgcn_mfma_f32_16x16x32_f16(af, bA0, c0, 0, 0, 0);
    c1 = __builtin_amdgcn_mfma_f32_16x16x32_f16(af, bA1, c1, 0, 0, 0);
    #pragma unroll
    for (int rr = 0; rr < 4; ++rr) {
        float v0 = fmaxf(c0[rr] + degv[rr] * cw0, 0.f);
        float v1 = fmaxf(c1[rr] + degv[rr] * cw1, 0.f);
        int row = kg * 4 + rr;
        X[wave][row * 32 + d0] = (_Float16)v0;
        X[wave][row * 32 + d0 + 16] = (_Float16)v1;
    }
    __builtin_amdgcn_wave_barrier();
    f16x8 af2 = *(f16x8*)&X[wave][d0 * 32 + kg * 8];
    __builtin_amdgcn_wave_barrier();

    // layer B
    f32x4 e0 = {bb0, bb0, bb0, bb0};
    f32x4 e1 = {bb1, bb1, bb1, bb1};
    e0 = __builtin_amdgcn_mfma_f32_16x16x32_f16(af2, bB0, e0, 0, 0, 0);
    e1 = __builtin_amdgcn_mfma_f32_16x16x32_f16(af2, bB1, e1, 0, 0, 0);
    float s0 = 0.f, ss0 = 0.f, s1 = 0.f, ss1 = 0.f;
    #pragma unroll
    for (int rr = 0; rr < 4; ++rr) {
        float y0 = fmaxf(e0[rr], 0.f);
        float y1 = fmaxf(e1[rr], 0.f);
        s0 += y0; ss0 += y0 * y0;
        s1 += y1; ss1 += y1 * y1;
        int row = kg * 4 + rr;
        X[wave][row * 32 + d0] = (_Float16)y0;
        X[wave][row * 32 + d0 + 16] = (_Float16)y1;
    }
    __builtin_amdgcn_wave_barrier();
    // node-major readback -> split coalesced store
    {
        int gg = l >> 2, c = l & 3;
        uint4 vv = *(uint4*)&X[wave][gg * 32 + c * 8];
        __half* op = (c & 2) ? out1 : out0;
        *(uint4*)(op + (size_t)(tb + gg) * HDIM + (c & 1) * 8) = vv;
    }
    // BN stats -> binned commit (spread contention over SBINS lines)
    s0 += __shfl_xor(s0, 16); s0 += __shfl_xor(s0, 32);
    ss0 += __shfl_xor(ss0, 16); ss0 += __shfl_xor(ss0, 32);
    s1 += __shfl_xor(s1, 16); s1 += __shfl_xor(s1, 32);
    ss1 += __shfl_xor(ss1, 16); ss1 += __shfl_xor(ss1, 32);
    if (kg == 0) {
        float* sb = sbins + ((blockIdx.x * 4 + wave) & (SBINS - 1)) * 64;
        atomicAdd(&sb[d0], s0);
        atomicAdd(&sb[DIM + d0], ss0);
        atomicAdd(&sb[d0 + 16], s1);
        atomicAdd(&sb[DIM + d0 + 16], ss1);
    }
}

// ---------------- final BN + global_add_pool (run-length, batch sorted) ----------------
#define POOL_BLOCKS 512
__global__ __launch_bounds__(256) void bn_pool_kernel(const __half* __restrict__ h0,
                                                      const __half* __restrict__ h1,
                                                      const float* __restrict__ sbins,
                                                      const float* __restrict__ gamma,
                                                      const float* __restrict__ beta,
                                                      const int* __restrict__ batch,
                                                      float* __restrict__ pooled) {
    __shared__ float st[64];
    int tid = threadIdx.x;
    if (tid < 64) {
        float s = 0.f;
        for (int b = 0; b < SBINS; ++b) s += sbins[b * 64 + tid];
        st[tid] = s;
    }
    __syncthreads();
    int lane = tid & 31;
    int group = tid >> 5;
    float mu = st[lane] * (1.f / N_NODES);
    float var = st[DIM + lane] * (1.f / N_NODES) - mu * mu;
    float inv = rsqrtf(var + BN_EPS);
    float a = gamma[lane] * inv;
    float c = beta[lane] - mu * a;
    const __half* hp = (lane < HDIM) ? h0 : h1;
    int loff = lane & (HDIM - 1);
    const int ngroups = POOL_BLOCKS * 8;
    const int chunk = (N_NODES + ngroups - 1) / ngroups;
    int g = blockIdx.x * 8 + group;
    int start = g * chunk;
    if (start >= N_NODES) return;
    int end = start + chunk; if (end > N_NODES) end = N_NODES;
    int cur = batch[start];
    float s = 0.f;
    for (int node = start; node < end; ++node) {
        float v = __half2float(hp[(size_t)node * HDIM + loff]) * a + c;
        int bg = batch[node];
        if (bg != cur) {
            atomicAdd(&pooled[cur * DIM + lane], s);
            s = 0.f;
            cur = bg;
        }
        s += v;
    }
    atomicAdd(&pooled[cur * DIM + lane], s);
}

// ---------------- out = relu(pooled @ Wfc + bfc) ----------------
__global__ __launch_bounds__(256) void fc_kernel(const float* __restrict__ pooled,
                                                 const float* __restrict__ Wfc,
                                                 const float* __restrict__ bfc,
                                                 float* __restrict__ out) {
    __shared__ float Wl[DIM * OUT_DIM];
    for (int i = threadIdx.x; i < DIM * OUT_DIM; i += blockDim.x) Wl[i] = Wfc[i];
    __syncthreads();
    int idx = blockIdx.x * blockDim.x + threadIdx.x;
    int stride = gridDim.x * blockDim.x;
    for (; idx < N_GRAPHS * OUT_DIM; idx += stride) {
        int g = idx >> 7;
        int o = idx & 127;
        float acc = bfc[o];
        #pragma unroll
        for (int k = 0; k < DIM; ++k)
            acc += pooled[g * DIM + k] * Wl[k * OUT_DIM + o];
        out[idx] = fmaxf(acc, 0.f);
    }
}

extern "C" void kernel_launch(void* const* d_in, const int* in_sizes, int n_in,
                              void* d_out, int out_size, void* d_ws, size_t ws_size,
                              hipStream_t stream) {
    const float* x   = (const float*)d_in[0];
    const int* eidx  = (const int*)d_in[1];
    const int* src   = eidx;
    const int* dst   = eidx + N_EDGES;
    const int* batch = (const int*)d_in[2];
    const float* W1a = (const float*)d_in[3];
    const float* b1a = (const float*)d_in[4];
    const float* W1b = (const float*)d_in[5];
    const float* b1b = (const float*)d_in[6];
    const float* Wa  = (const float*)d_in[7];
    const float* ba  = (const float*)d_in[8];
    const float* Wb  = (const float*)d_in[9];
    const float* bb  = (const float*)d_in[10];
    const float* gamma = (const float*)d_in[11];
    const float* beta  = (const float*)d_in[12];
    const float* Wfc = (const float*)d_in[13];
    const float* bfc = (const float*)d_in[14];
    float* out = (float*)d_out;

    const size_t TSZ = (size_t)N_NODES * HDIM;               // 1.6M halfs
    __half* TA0 = (__half*)d_ws;
    __half* TA1 = TA0 + TSZ;
    __half* TB0 = TA1 + TSZ;
    __half* TB1 = TB0 + TSZ;                                 // 12.8 MB
    __half* A16 = TB1 + TSZ;                                 // 6.4 MB
    float* degf   = (float*)(A16 + (size_t)N_NODES * DIM);   // 400 KB
    float* sbins  = degf + N_NODES;                          // 5 * SBINS * 64 floats
    float* pooled = sbins + 5 * SBINS * 64;                  // 256 KB
    float* cwf    = pooled + N_GRAPHS * DIM;                 // 5*32
    __half* blobs = (__half*)(cwf + 5 * 32);                 // 5*2048 halfs
    int* csr      = (int*)(blobs + 5 * 2048);                // 12.8 MB
    int* rowst    = csr + N_EDGES;                           // N_NODES+1
    int* bcnt     = rowst + N_NODES + 1;
    int* bstart   = bcnt + 256;
    int* bcursor  = bstart + NB + 1;

    // CSR-build scratch aliases (dead before first use of their hosts)
    int* bsrc            = (int*)TA0;             // 12.8 MB over the 4 T tables
    unsigned short* blow = (unsigned short*)A16;  // 6.4 MB over A16

    hipMemsetAsync(bcnt, 0, 256 * sizeof(int), stream);
    hipMemsetAsync(sbins, 0, 5 * SBINS * 64 * sizeof(float), stream);
    hipMemsetAsync(pooled, 0, N_GRAPHS * DIM * sizeof(float), stream);

    bucket_hist_kernel<<<1024, 256, 0, stream>>>(dst, bcnt);
    bucket_scan_kernel<<<1, 256, 0, stream>>>(bcnt, bstart, bcursor, rowst);
    bucket_scatter_kernel<<<(N_EDGES + CHUNK - 1) / CHUNK, 256, 0, stream>>>(src, dst, bcursor, bsrc, blow);
    node_sort_kernel<<<NB, 256, 0, stream>>>(bstart, bsrc, blow, csr, rowst);

    deg_kernel<<<(N_NODES + 255) / 256, 256, 0, stream>>>(rowst, degf);
    transform1_kernel<<<2048, 256, 0, stream>>>(x, W1a, TA0, TA1);

    prep_id_kernel<<<1, 1024, 0, stream>>>(W1b, blobs, cwf);

    const __half *in0 = TA0, *in1 = TA1;
    __half *o0 = TB0, *o1 = TB1;

    // layer 1
    agg_half_kernel<<<AGG_BLOCKS, 256, 0, stream>>>(in0, rowst, csr, A16);
    agg_half_kernel<<<AGG_BLOCKS, 256, 0, stream>>>(in1, rowst, csr, A16 + HDIM);
    mlp_kernel<<<AGG_BLOCKS, 256, 0, stream>>>(A16, degf, blobs, cwf, b1a, b1b, o0, o1, sbins);
    { const __half* t0 = in0; in0 = o0; o0 = (__half*)t0;
      const __half* t1 = in1; in1 = o1; o1 = (__half*)t1; }

    for (int i = 0; i < 4; ++i) {
        __half* blob_i = blobs + (i + 1) * 2048;
        float* cwf_i = cwf + (i + 1) * 32;
        prep_kernel<<<1, 1024, 0, stream>>>(sbins + i * SBINS * 64, gamma + i * DIM, beta + i * DIM,
                                            Wa + i * DIM * DIM, Wb + i * DIM * DIM, blob_i, cwf_i);
        agg_half_kernel<<<AGG_BLOCKS, 256, 0, stream>>>(in0, rowst, csr, A16);
        agg_half_kernel<<<AGG_BLOCKS, 256, 0, stream>>>(in1, rowst, csr, A16 + HDIM);
        mlp_kernel<<<AGG_BLOCKS, 256, 0, stream>>>(A16, degf, blob_i, cwf_i,
                                                   ba + i * DIM, bb + i * DIM, o0, o1,
                                                   sbins + (i + 1) * SBINS * 64);
        { const __half* t0 = in0; in0 = o0; o0 = (__half*)t0;
          const __half* t1 = in1; in1 = o1; o1 = (__half*)t1; }
    }

    bn_pool_kernel<<<POOL_BLOCKS, 256, 0, stream>>>(in0, in1, sbins + 4 * SBINS * 64,
                                                    gamma + 4 * DIM, beta + 4 * DIM, batch, pooled);
    fc_kernel<<<1024, 256, 0, stream>>>(pooled, Wfc, bfc, out);
}

// Round 10
// 468.463 us; speedup vs baseline: 2.5526x; 1.1019x over previous
//
#include <hip/hip_runtime.h>
#include <hip/hip_fp16.h>

#define N_NODES 100000
#define N_EDGES 3200000
#define N_GRAPHS 2048
#define DIM 32
#define HDIM 16
#define FEAT 78
#define OUT_DIM 128
#define BN_EPS 1e-5f

#define BSHIFT 9
#define BSIZE 512
#define NB ((N_NODES + BSIZE - 1) / BSIZE)   // 196
#define CHUNK 8192
#define NSUB 4

#define NTILES (N_NODES / 16)          // 6250
#define SBINS 64

typedef _Float16 f16x8 __attribute__((ext_vector_type(8)));
typedef float f32x4 __attribute__((ext_vector_type(4)));

// ---------------- K1: coarse bucket histogram ----------------
__global__ __launch_bounds__(256) void bucket_hist_kernel(const int* __restrict__ dst,
                                                          int* __restrict__ bcnt) {
    __shared__ int lh[256];
    int tid = threadIdx.x;
    lh[tid] = 0;
    __syncthreads();
    int i = blockIdx.x * blockDim.x + tid;
    int stride = gridDim.x * blockDim.x;
    for (; i < N_EDGES; i += stride)
        atomicAdd(&lh[dst[i] >> BSHIFT], 1);
    __syncthreads();
    if (tid < NB && lh[tid])
        atomicAdd(&bcnt[tid], lh[tid]);
}

// ---------------- K2: scan over buckets ----------------
__global__ __launch_bounds__(256) void bucket_scan_kernel(const int* __restrict__ bcnt,
                                                          int* __restrict__ bstart,
                                                          int* __restrict__ bcursor,
                                                          int* __restrict__ rowst) {
    __shared__ int sc[256];
    int tid = threadIdx.x;
    int v = (tid < NB) ? bcnt[tid] : 0;
    sc[tid] = v;
    __syncthreads();
    for (int off = 1; off < 256; off <<= 1) {
        int nv = (tid >= off) ? sc[tid - off] : 0;
        __syncthreads();
        sc[tid] += nv;
        __syncthreads();
    }
    if (tid < NB) {
        int ex = sc[tid] - v;
        bstart[tid] = ex;
        bcursor[tid] = ex;
    }
    if (tid == 0) {
        bstart[NB] = N_EDGES;
        rowst[N_NODES] = N_EDGES;
    }
}

// ---------------- K3: multisplit scatter into bucket segments ----------------
__global__ __launch_bounds__(256) void bucket_scatter_kernel(const int* __restrict__ src,
                                                             const int* __restrict__ dst,
                                                             int* __restrict__ bcursor,
                                                             int* __restrict__ bsrc,
                                                             unsigned short* __restrict__ blow) {
    __shared__ int lsrc[CHUNK];
    __shared__ int ldst[CHUNK];
    __shared__ int lhist[256];
    __shared__ int sc[256];
    __shared__ int lpre[256];
    __shared__ int gbase[256];
    __shared__ int lcur[256];
    int tid = threadIdx.x;
    int base = blockIdx.x * CHUNK;
    int n = N_EDGES - base; if (n > CHUNK) n = CHUNK;

    lhist[tid] = 0;
    __syncthreads();
    for (int i = tid; i < n; i += 256)
        atomicAdd(&lhist[dst[base + i] >> BSHIFT], 1);
    __syncthreads();
    int v = lhist[tid];
    sc[tid] = v;
    __syncthreads();
    for (int off = 1; off < 256; off <<= 1) {
        int nv = (tid >= off) ? sc[tid - off] : 0;
        __syncthreads();
        sc[tid] += nv;
        __syncthreads();
    }
    int ex = sc[tid] - v;
    lpre[tid] = ex;
    lcur[tid] = ex;
    if (tid < NB && v)
        gbase[tid] = atomicAdd(&bcursor[tid], v);
    __syncthreads();
    for (int i = tid; i < n; i += 256) {
        int d = dst[base + i];
        int s = src[base + i];
        int b = d >> BSHIFT;
        int pos = atomicAdd(&lcur[b], 1);
        lsrc[pos] = s;
        ldst[pos] = d;
    }
    __syncthreads();
    for (int i = tid; i < n; i += 256) {
        int d = ldst[i];
        int b = d >> BSHIFT;
        int gpos = gbase[b] + (i - lpre[b]);
        bsrc[gpos] = lsrc[i];
        blow[gpos] = (unsigned short)(d & (BSIZE - 1));
    }
}

// ---------------- K4a: per-(bucket,quarter) node histogram ----------------
__global__ __launch_bounds__(256) void node_count_kernel(const int* __restrict__ bstart,
                                                         const unsigned short* __restrict__ blow,
                                                         int* __restrict__ qcnt) {
    __shared__ int lcnt[BSIZE];
    int tid = threadIdx.x;
    int b = blockIdx.x / NSUB;
    int qt = blockIdx.x % NSUB;
    int ss = bstart[b], se = bstart[b + 1];
    int len = se - ss;
    int qs = ss + (int)(((long long)len * qt) / NSUB);
    int qe = ss + (int)(((long long)len * (qt + 1)) / NSUB);
    lcnt[tid] = 0; lcnt[tid + 256] = 0;
    __syncthreads();
    for (int i = qs + tid; i < qe; i += 256)
        atomicAdd(&lcnt[blow[i]], 1);
    __syncthreads();
    int* qc = qcnt + (size_t)blockIdx.x * BSIZE;
    qc[tid] = lcnt[tid];
    qc[tid + 256] = lcnt[tid + 256];
}

// ---------------- K4b: per-bucket scan over nodes+quarters -> rowst, qbase ----------------
__global__ __launch_bounds__(256) void node_scan_kernel(const int* __restrict__ bstart,
                                                        const int* __restrict__ qcnt,
                                                        int* __restrict__ qbase,
                                                        int* __restrict__ rowst) {
    __shared__ int sc[256];
    int tid = threadIdx.x;
    int b = blockIdx.x;
    int ss = bstart[b];
    const int* qc = qcnt + (size_t)b * NSUB * BSIZE;
    int j0 = 2 * tid, j1 = 2 * tid + 1;
    int c00 = qc[0 * BSIZE + j0], c01 = qc[1 * BSIZE + j0],
        c02 = qc[2 * BSIZE + j0], c03 = qc[3 * BSIZE + j0];
    int c10 = qc[0 * BSIZE + j1], c11 = qc[1 * BSIZE + j1],
        c12 = qc[2 * BSIZE + j1], c13 = qc[3 * BSIZE + j1];
    int t0 = c00 + c01 + c02 + c03;
    int t1 = c10 + c11 + c12 + c13;
    int s = t0 + t1;
    sc[tid] = s;
    __syncthreads();
    for (int off = 1; off < 256; off <<= 1) {
        int nv = (tid >= off) ? sc[tid - off] : 0;
        __syncthreads();
        sc[tid] += nv;
        __syncthreads();
    }
    int ex = sc[tid] - s;
    int base0 = ss + ex;
    int base1 = base0 + t0;
    int node_base = b << BSHIFT;
    if (node_base + j0 < N_NODES) rowst[node_base + j0] = base0;
    if (node_base + j1 < N_NODES) rowst[node_base + j1] = base1;
    int* qb = qbase + (size_t)b * NSUB * BSIZE;
    qb[0 * BSIZE + j0] = base0;
    qb[1 * BSIZE + j0] = base0 + c00;
    qb[2 * BSIZE + j0] = base0 + c00 + c01;
    qb[3 * BSIZE + j0] = base0 + c00 + c01 + c02;
    qb[0 * BSIZE + j1] = base1;
    qb[1 * BSIZE + j1] = base1 + c10;
    qb[2 * BSIZE + j1] = base1 + c10 + c11;
    qb[3 * BSIZE + j1] = base1 + c10 + c11 + c12;
}

// ---------------- K4c: per-(bucket,quarter) scatter -> csr ----------------
__global__ __launch_bounds__(256) void node_scatter_kernel(const int* __restrict__ bstart,
                                                           const int* __restrict__ bsrc,
                                                           const unsigned short* __restrict__ blow,
                                                           const int* __restrict__ qbase,
                                                           int* __restrict__ csr) {
    __shared__ int lcur[BSIZE];
    int tid = threadIdx.x;
    int b = blockIdx.x / NSUB;
    int qt = blockIdx.x % NSUB;
    int ss = bstart[b], se = bstart[b + 1];
    int len = se - ss;
    int qs = ss + (int)(((long long)len * qt) / NSUB);
    int qe = ss + (int)(((long long)len * (qt + 1)) / NSUB);
    const int* qb = qbase + (size_t)blockIdx.x * BSIZE;
    lcur[tid] = qb[tid];
    lcur[tid + 256] = qb[tid + 256];
    __syncthreads();
    for (int i = qs + tid; i < qe; i += 256) {
        int nloc = blow[i];
        int pos = atomicAdd(&lcur[nloc], 1);
        csr[pos] = bsrc[i];
    }
}

// ---------------- deg+1 as float ----------------
__global__ __launch_bounds__(256) void deg_kernel(const int* __restrict__ rowst,
                                                  float* __restrict__ degf) {
    int i = blockIdx.x * blockDim.x + threadIdx.x;
    if (i < N_NODES)
        degf[i] = (float)(rowst[i + 1] - rowst[i] + 1);
}

// ---------------- transform1: split tables T0/T1 = fp16(x @ W1a) ----------------
__global__ __launch_bounds__(256) void transform1_kernel(const float* __restrict__ x,
                                                         const float* __restrict__ W,
                                                         __half* __restrict__ T0,
                                                         __half* __restrict__ T1) {
    __shared__ float Wl[FEAT * DIM];
    for (int i = threadIdx.x; i < FEAT * DIM; i += blockDim.x) Wl[i] = W[i];
    __syncthreads();
    int lane = threadIdx.x & 31;
    int group = threadIdx.x >> 5;
    int gpb = blockDim.x >> 5;
    for (int node = blockIdx.x * gpb + group; node < N_NODES; node += gridDim.x * gpb) {
        const float* xr = x + (size_t)node * FEAT;
        float r0 = xr[lane];
        float r1 = xr[32 + lane];
        float r2 = (lane < FEAT - 64) ? xr[64 + lane] : 0.f;
        float acc = 0.f;
        #pragma unroll
        for (int k = 0; k < 32; ++k)
            acc += __shfl(r0, k, 32) * Wl[k * DIM + lane];
        #pragma unroll
        for (int k = 0; k < 32; ++k)
            acc += __shfl(r1, k, 32) * Wl[(32 + k) * DIM + lane];
        #pragma unroll
        for (int k = 0; k < FEAT - 64; ++k)
            acc += __shfl(r2, k, 32) * Wl[(64 + k) * DIM + lane];
        __half h = __float2half(acc);
        if (lane < HDIM) T0[(size_t)node * HDIM + lane] = h;
        else             T1[(size_t)node * HDIM + lane - HDIM] = h;
    }
}

// ---------------- prep: reduce stat bins + BN-fold, weights in fragment layout ----------------
__global__ __launch_bounds__(1024) void prep_kernel(const float* __restrict__ sbins,
                                                    const float* __restrict__ gamma,
                                                    const float* __restrict__ beta,
                                                    const float* __restrict__ Wa,
                                                    const float* __restrict__ Wb,
                                                    __half* __restrict__ blob,
                                                    float* __restrict__ cwf) {
    __shared__ float st[64];
    __shared__ float a[DIM], c[DIM];
    int tid = threadIdx.x;
    if (tid < 64) {
        float s = 0.f;
        for (int b = 0; b < SBINS; ++b) s += sbins[b * 64 + tid];
        st[tid] = s;
    }
    __syncthreads();
    if (tid < DIM) {
        float mu = st[tid] * (1.f / N_NODES);
        float var = st[DIM + tid] * (1.f / N_NODES) - mu * mu;
        float av = gamma[tid] * rsqrtf(var + BN_EPS);
        a[tid] = av;
        c[tid] = beta[tid] - mu * av;
    }
    __syncthreads();
    int d = tid >> 5, k = tid & 31;
    blob[d * 32 + k] = __float2half(a[k] * Wa[k * 32 + d]);
    blob[1024 + d * 32 + k] = __float2half(Wb[k * 32 + d]);
    if (tid < DIM) {
        float s = 0.f;
        for (int kk = 0; kk < DIM; ++kk)
            s += c[kk] * Wa[kk * 32 + tid];
        cwf[tid] = s;
    }
}

__global__ __launch_bounds__(1024) void prep_id_kernel(const float* __restrict__ W1b,
                                                       __half* __restrict__ blob,
                                                       float* __restrict__ cwf) {
    int tid = threadIdx.x;
    int d = tid >> 5, k = tid & 31;
    blob[d * 32 + k] = __float2half((d == k) ? 1.f : 0.f);
    blob[1024 + d * 32 + k] = __float2half(W1b[k * 32 + d]);
    if (tid < DIM) cwf[tid] = 0.f;
}

#define ACC8(v) do { const __half2* hp_ = (const __half2*)&(v); float2 f_; \
  f_ = __half22float2(hp_[0]); a0 += f_.x; a1 += f_.y; \
  f_ = __half22float2(hp_[1]); a2 += f_.x; a3 += f_.y; \
  f_ = __half22float2(hp_[2]); a4 += f_.x; a5 += f_.y; \
  f_ = __half22float2(hp_[3]); a6 += f_.x; a7 += f_.y; } while (0)

// ---------------- agg_dual: both halves in one launch, XCD-partitioned ----------------
// XCDs 0-3 gather from T0 (dims 0-15), XCDs 4-7 from T1 (dims 16-31); each XCD's
// gather table is 3.2MB -> L2-resident. Software-pipelined csr prefetch.
// lane l: node g=l>>2, edge-group e=(l>>1)&1 (8 edges), 16B chunk q=l&1.
#define AGG_DUAL_BLOCKS 3128
__global__ __launch_bounds__(256) void agg_dual_kernel(const __half* __restrict__ T0,
                                                       const __half* __restrict__ T1,
                                                       const int* __restrict__ rowst,
                                                       const int* __restrict__ csr,
                                                       __half* __restrict__ outA) {
    int b = blockIdx.x;
    int half = (b >> 2) & 1;
    int idx_in_half = (b >> 3) * 4 + (b & 3);
    int tid = threadIdx.x;
    int wave = tid >> 6;
    int l = tid & 63;
    int g = l >> 2, e = (l >> 1) & 1, q = l & 1;
    int tile = idx_in_half * 4 + wave;
    if (tile >= NTILES) return;
    const __half* T = half ? T1 : T0;
    __half* outp = outA + half * HDIM;
    int node = tile * 16 + g;
    int rs = rowst[node], re = rowst[node + 1];
    float a0 = 0.f, a1 = 0.f, a2 = 0.f, a3 = 0.f,
          a4 = 0.f, a5 = 0.f, a6 = 0.f, a7 = 0.f;
    int p = rs;
    int idx[8];
    bool have = (p + 16 <= re);
    if (have) {
        #pragma unroll
        for (int j = 0; j < 8; ++j) idx[j] = csr[p + 8 * e + j];
    }
    while (have) {
        uint4 v[8];
        #pragma unroll
        for (int j = 0; j < 8; ++j)
            v[j] = *(const uint4*)(T + (size_t)idx[j] * HDIM + (q << 3));
        int np = p + 16;
        bool nhave = (np + 16 <= re);
        int nidx[8];
        if (nhave) {
            #pragma unroll
            for (int j = 0; j < 8; ++j) nidx[j] = csr[np + 8 * e + j];
        }
        #pragma unroll
        for (int j = 0; j < 8; ++j) ACC8(v[j]);
        #pragma unroll
        for (int j = 0; j < 8; ++j) idx[j] = nidx[j];
        p = np;
        have = nhave;
    }
    if (p < re) {
        #pragma unroll
        for (int j = 0; j < 8; ++j) {
            int ei = p + 8 * e + j;
            uint4 vv = {0, 0, 0, 0};
            if (ei < re) vv = *(const uint4*)(T + (size_t)csr[ei] * HDIM + (q << 3));
            ACC8(vv);
        }
    }
    // reduce over e (lane bit 1)
    a0 += __shfl_xor(a0, 2); a1 += __shfl_xor(a1, 2);
    a2 += __shfl_xor(a2, 2); a3 += __shfl_xor(a3, 2);
    a4 += __shfl_xor(a4, 2); a5 += __shfl_xor(a5, 2);
    a6 += __shfl_xor(a6, 2); a7 += __shfl_xor(a7, 2);
    if (e == 0) {
        uint4 vs = *(const uint4*)(T + (size_t)node * HDIM + (q << 3));
        ACC8(vs);
        f16x8 hv;
        hv[0] = (_Float16)a0; hv[1] = (_Float16)a1;
        hv[2] = (_Float16)a2; hv[3] = (_Float16)a3;
        hv[4] = (_Float16)a4; hv[5] = (_Float16)a5;
        hv[6] = (_Float16)a6; hv[7] = (_Float16)a7;
        *(f16x8*)(outp + (size_t)node * DIM + (q << 3)) = hv;
    }
}

// ---------------- mlp: streaming MFMA over nodes; binned BN stats ----------------
__global__ __launch_bounds__(256) void mlp_kernel(const __half* __restrict__ A16,
                                                  const float* __restrict__ degf,
                                                  const __half* __restrict__ blob,
                                                  const float* __restrict__ cwf,
                                                  const float* __restrict__ bias_a,
                                                  const float* __restrict__ bias_b,
                                                  __half* __restrict__ out0,
                                                  __half* __restrict__ out1,
                                                  float* __restrict__ sbins) {
    __shared__ __align__(16) _Float16 X[4][512];
    int tid = threadIdx.x;
    int wave = tid >> 6;
    int l = tid & 63;
    int d0 = l & 15, kg = l >> 4;
    int tile = blockIdx.x * 4 + wave;
    if (tile >= NTILES) return;
    int tb = tile * 16;

    f16x8 af = *(const f16x8*)(A16 + (size_t)(tb + d0) * DIM + kg * 8);
    f16x8 bA0 = *(const f16x8*)(blob + d0 * 32 + kg * 8);
    f16x8 bA1 = *(const f16x8*)(blob + (d0 + 16) * 32 + kg * 8);
    f16x8 bB0 = *(const f16x8*)(blob + 1024 + d0 * 32 + kg * 8);
    f16x8 bB1 = *(const f16x8*)(blob + 1024 + (d0 + 16) * 32 + kg * 8);
    f32x4 degv = *(const f32x4*)(degf + tb + kg * 4);
    float cw0 = cwf[d0], cw1 = cwf[d0 + 16];
    float ba0 = bias_a[d0], ba1 = bias_a[d0 + 16];
    float bb0 = bias_b[d0], bb1 = bias_b[d0 + 16];

    // layer A
    f32x4 c0 = {ba0, ba0, ba0, ba0};
    f32x4 c1 = {ba1, ba1, ba1, ba1};
    c0 = __builtin_amdgcn_mfma_f32_16x16x32_f16(af, bA0, c0, 0, 0, 0);
    c1 = __builtin_amdgcn_mfma_f32_16x16x32_f16(af, bA1, c1, 0, 0, 0);
    #pragma unroll
    for (int rr = 0; rr < 4; ++rr) {
        float v0 = fmaxf(c0[rr] + degv[rr] * cw0, 0.f);
        float v1 = fmaxf(c1[rr] + degv[rr] * cw1, 0.f);
        int row = kg * 4 + rr;
        X[wave][row * 32 + d0] = (_Float16)v0;
        X[wave][row * 32 + d0 + 16] = (_Float16)v1;
    }
    __builtin_amdgcn_wave_barrier();
    f16x8 af2 = *(f16x8*)&X[wave][d0 * 32 + kg * 8];
    __builtin_amdgcn_wave_barrier();

    // layer B
    f32x4 e0 = {bb0, bb0, bb0, bb0};
    f32x4 e1 = {bb1, bb1, bb1, bb1};
    e0 = __builtin_amdgcn_mfma_f32_16x16x32_f16(af2, bB0, e0, 0, 0, 0);
    e1 = __builtin_amdgcn_mfma_f32_16x16x32_f16(af2, bB1, e1, 0, 0, 0);
    float s0 = 0.f, ss0 = 0.f, s1 = 0.f, ss1 = 0.f;
    #pragma unroll
    for (int rr = 0; rr < 4; ++rr) {
        float y0 = fmaxf(e0[rr], 0.f);
        float y1 = fmaxf(e1[rr], 0.f);
        s0 += y0; ss0 += y0 * y0;
        s1 += y1; ss1 += y1 * y1;
        int row = kg * 4 + rr;
        X[wave][row * 32 + d0] = (_Float16)y0;
        X[wave][row * 32 + d0 + 16] = (_Float16)y1;
    }
    __builtin_amdgcn_wave_barrier();
    {
        int gg = l >> 2, c = l & 3;
        uint4 vv = *(uint4*)&X[wave][gg * 32 + c * 8];
        __half* op = (c & 2) ? out1 : out0;
        *(uint4*)(op + (size_t)(tb + gg) * HDIM + (c & 1) * 8) = vv;
    }
    s0 += __shfl_xor(s0, 16); s0 += __shfl_xor(s0, 32);
    ss0 += __shfl_xor(ss0, 16); ss0 += __shfl_xor(ss0, 32);
    s1 += __shfl_xor(s1, 16); s1 += __shfl_xor(s1, 32);
    ss1 += __shfl_xor(ss1, 16); ss1 += __shfl_xor(ss1, 32);
    if (kg == 0) {
        float* sb = sbins + ((blockIdx.x * 4 + wave) & (SBINS - 1)) * 64;
        atomicAdd(&sb[d0], s0);
        atomicAdd(&sb[DIM + d0], ss0);
        atomicAdd(&sb[d0 + 16], s1);
        atomicAdd(&sb[DIM + d0 + 16], ss1);
    }
}

// ---------------- final BN + global_add_pool (run-length, batch sorted) ----------------
#define POOL_BLOCKS 512
__global__ __launch_bounds__(256) void bn_pool_kernel(const __half* __restrict__ h0,
                                                      const __half* __restrict__ h1,
                                                      const float* __restrict__ sbins,
                                                      const float* __restrict__ gamma,
                                                      const float* __restrict__ beta,
                                                      const int* __restrict__ batch,
                                                      float* __restrict__ pooled) {
    __shared__ float st[64];
    int tid = threadIdx.x;
    if (tid < 64) {
        float s = 0.f;
        for (int b = 0; b < SBINS; ++b) s += sbins[b * 64 + tid];
        st[tid] = s;
    }
    __syncthreads();
    int lane = tid & 31;
    int group = tid >> 5;
    float mu = st[lane] * (1.f / N_NODES);
    float var = st[DIM + lane] * (1.f / N_NODES) - mu * mu;
    float inv = rsqrtf(var + BN_EPS);
    float a = gamma[lane] * inv;
    float c = beta[lane] - mu * a;
    const __half* hp = (lane < HDIM) ? h0 : h1;
    int loff = lane & (HDIM - 1);
    const int ngroups = POOL_BLOCKS * 8;
    const int chunk = (N_NODES + ngroups - 1) / ngroups;
    int g = blockIdx.x * 8 + group;
    int start = g * chunk;
    if (start >= N_NODES) return;
    int end = start + chunk; if (end > N_NODES) end = N_NODES;
    int cur = batch[start];
    float s = 0.f;
    for (int node = start; node < end; ++node) {
        float v = __half2float(hp[(size_t)node * HDIM + loff]) * a + c;
        int bg = batch[node];
        if (bg != cur) {
            atomicAdd(&pooled[cur * DIM + lane], s);
            s = 0.f;
            cur = bg;
        }
        s += v;
    }
    atomicAdd(&pooled[cur * DIM + lane], s);
}

// ---------------- out = relu(pooled @ Wfc + bfc) ----------------
__global__ __launch_bounds__(256) void fc_kernel(const float* __restrict__ pooled,
                                                 const float* __restrict__ Wfc,
                                                 const float* __restrict__ bfc,
                                                 float* __restrict__ out) {
    __shared__ float Wl[DIM * OUT_DIM];
    for (int i = threadIdx.x; i < DIM * OUT_DIM; i += blockDim.x) Wl[i] = Wfc[i];
    __syncthreads();
    int idx = blockIdx.x * blockDim.x + threadIdx.x;
    int stride = gridDim.x * blockDim.x;
    for (; idx < N_GRAPHS * OUT_DIM; idx += stride) {
        int g = idx >> 7;
        int o = idx & 127;
        float acc = bfc[o];
        #pragma unroll
        for (int k = 0; k < DIM; ++k)
            acc += pooled[g * DIM + k] * Wl[k * OUT_DIM + o];
        out[idx] = fmaxf(acc, 0.f);
    }
}

extern "C" void kernel_launch(void* const* d_in, const int* in_sizes, int n_in,
                              void* d_out, int out_size, void* d_ws, size_t ws_size,
                              hipStream_t stream) {
    const float* x   = (const float*)d_in[0];
    const int* eidx  = (const int*)d_in[1];
    const int* src   = eidx;
    const int* dst   = eidx + N_EDGES;
    const int* batch = (const int*)d_in[2];
    const float* W1a = (const float*)d_in[3];
    const float* b1a = (const float*)d_in[4];
    const float* W1b = (const float*)d_in[5];
    const float* b1b = (const float*)d_in[6];
    const float* Wa  = (const float*)d_in[7];
    const float* ba  = (const float*)d_in[8];
    const float* Wb  = (const float*)d_in[9];
    const float* bb  = (const float*)d_in[10];
    const float* gamma = (const float*)d_in[11];
    const float* beta  = (const float*)d_in[12];
    const float* Wfc = (const float*)d_in[13];
    const float* bfc = (const float*)d_in[14];
    float* out = (float*)d_out;

    const size_t TSZ = (size_t)N_NODES * HDIM;               // 1.6M halfs
    __half* TA0 = (__half*)d_ws;
    __half* TA1 = TA0 + TSZ;
    __half* TB0 = TA1 + TSZ;
    __half* TB1 = TB0 + TSZ;                                 // 12.8 MB
    __half* A16 = TB1 + TSZ;                                 // 6.4 MB
    float* degf   = (float*)(A16 + (size_t)N_NODES * DIM);   // 400 KB
    float* sbins  = degf + N_NODES;                          // 5 * SBINS * 64
    float* pooled = sbins + 5 * SBINS * 64;                  // 256 KB
    float* cwf    = pooled + N_GRAPHS * DIM;                 // 5*32
    __half* blobs = (__half*)(cwf + 5 * 32);                 // 5*2048 halfs
    int* csr      = (int*)(blobs + 5 * 2048);                // 12.8 MB
    int* rowst    = csr + N_EDGES;                           // N_NODES+1
    int* bcnt     = rowst + N_NODES + 1;
    int* bstart   = bcnt + 256;
    int* bcursor  = bstart + NB + 1;
    int* qcnt     = bcursor + 256;                           // NB*NSUB*BSIZE = 1.6MB
    int* qbase    = qcnt + NB * NSUB * BSIZE;                // 1.6MB

    // CSR-build scratch aliases (dead before first use of their hosts)
    int* bsrc            = (int*)TA0;             // 12.8 MB over the 4 T tables
    unsigned short* blow = (unsigned short*)A16;  // 6.4 MB over A16

    hipMemsetAsync(bcnt, 0, 256 * sizeof(int), stream);
    hipMemsetAsync(sbins, 0, 5 * SBINS * 64 * sizeof(float), stream);
    hipMemsetAsync(pooled, 0, N_GRAPHS * DIM * sizeof(float), stream);

    bucket_hist_kernel<<<1024, 256, 0, stream>>>(dst, bcnt);
    bucket_scan_kernel<<<1, 256, 0, stream>>>(bcnt, bstart, bcursor, rowst);
    bucket_scatter_kernel<<<(N_EDGES + CHUNK - 1) / CHUNK, 256, 0, stream>>>(src, dst, bcursor, bsrc, blow);
    node_count_kernel<<<NB * NSUB, 256, 0, stream>>>(bstart, blow, qcnt);
    node_scan_kernel<<<NB, 256, 0, stream>>>(bstart, qcnt, qbase, rowst);
    node_scatter_kernel<<<NB * NSUB, 256, 0, stream>>>(bstart, bsrc, blow, qbase, csr);

    deg_kernel<<<(N_NODES + 255) / 256, 256, 0, stream>>>(rowst, degf);
    transform1_kernel<<<2048, 256, 0, stream>>>(x, W1a, TA0, TA1);

    prep_id_kernel<<<1, 1024, 0, stream>>>(W1b, blobs, cwf);

    const __half *in0 = TA0, *in1 = TA1;
    __half *o0 = TB0, *o1 = TB1;

    // layer 1
    agg_dual_kernel<<<AGG_DUAL_BLOCKS, 256, 0, stream>>>(in0, in1, rowst, csr, A16);
    mlp_kernel<<<(NTILES + 3) / 4, 256, 0, stream>>>(A16, degf, blobs, cwf, b1a, b1b, o0, o1, sbins);
    { const __half* t0 = in0; in0 = o0; o0 = (__half*)t0;
      const __half* t1 = in1; in1 = o1; o1 = (__half*)t1; }

    for (int i = 0; i < 4; ++i) {
        __half* blob_i = blobs + (i + 1) * 2048;
        float* cwf_i = cwf + (i + 1) * 32;
        prep_kernel<<<1, 1024, 0, stream>>>(sbins + i * SBINS * 64, gamma + i * DIM, beta + i * DIM,
                                            Wa + i * DIM * DIM, Wb + i * DIM * DIM, blob_i, cwf_i);
        agg_dual_kernel<<<AGG_DUAL_BLOCKS, 256, 0, stream>>>(in0, in1, rowst, csr, A16);
        mlp_kernel<<<(NTILES + 3) / 4, 256, 0, stream>>>(A16, degf, blob_i, cwf_i,
                                                         ba + i * DIM, bb + i * DIM, o0, o1,
                                                         sbins + (i + 1) * SBINS * 64);
        { const __half* t0 = in0; in0 = o0; o0 = (__half*)t0;
          const __half* t1 = in1; in1 = o1; o1 = (__half*)t1; }
    }

    bn_pool_kernel<<<POOL_BLOCKS, 256, 0, stream>>>(in0, in1, sbins + 4 * SBINS * 64,
                                                    gamma + 4 * DIM, beta + 4 * DIM, batch, pooled);
    fc_kernel<<<1024, 256, 0, stream>>>(pooled, Wfc, bfc, out);
}

// Round 11
// 432.297 us; speedup vs baseline: 2.7662x; 1.0837x over previous
//
#include <hip/hip_runtime.h>
#include <hip/hip_fp16.h>

#define N_NODES 100000
#define N_EDGES 3200000
#define N_GRAPHS 2048
#define DIM 32
#define HDIM 16
#define FEAT 78
#define OUT_DIM 128
#define BN_EPS 1e-5f

#define BSHIFT 9
#define BSIZE 512
#define NB ((N_NODES + BSIZE - 1) / BSIZE)   // 196
#define CHUNK 8192
#define NSUB 4

#define NTILES (N_NODES / 16)          // 6250
#define SBINS 64

typedef _Float16 f16x8 __attribute__((ext_vector_type(8)));
typedef float f32x4 __attribute__((ext_vector_type(4)));

// ---------------- K1: coarse bucket histogram (int4-vectorized) ----------------
__global__ __launch_bounds__(256) void bucket_hist_kernel(const int* __restrict__ dst,
                                                          int* __restrict__ bcnt) {
    __shared__ int lh[256];
    int tid = threadIdx.x;
    lh[tid] = 0;
    __syncthreads();
    const int4* d4 = (const int4*)dst;
    const int n4 = N_EDGES / 4;
    int i = blockIdx.x * blockDim.x + tid;
    int stride = gridDim.x * blockDim.x;
    for (; i < n4; i += stride) {
        int4 v = d4[i];
        atomicAdd(&lh[v.x >> BSHIFT], 1);
        atomicAdd(&lh[v.y >> BSHIFT], 1);
        atomicAdd(&lh[v.z >> BSHIFT], 1);
        atomicAdd(&lh[v.w >> BSHIFT], 1);
    }
    __syncthreads();
    if (tid < NB && lh[tid])
        atomicAdd(&bcnt[tid], lh[tid]);
}

// ---------------- K2: scan over buckets ----------------
__global__ __launch_bounds__(256) void bucket_scan_kernel(const int* __restrict__ bcnt,
                                                          int* __restrict__ bstart,
                                                          int* __restrict__ bcursor,
                                                          int* __restrict__ rowst) {
    __shared__ int sc[256];
    int tid = threadIdx.x;
    int v = (tid < NB) ? bcnt[tid] : 0;
    sc[tid] = v;
    __syncthreads();
    for (int off = 1; off < 256; off <<= 1) {
        int nv = (tid >= off) ? sc[tid - off] : 0;
        __syncthreads();
        sc[tid] += nv;
        __syncthreads();
    }
    if (tid < NB) {
        int ex = sc[tid] - v;
        bstart[tid] = ex;
        bcursor[tid] = ex;
    }
    if (tid == 0) {
        bstart[NB] = N_EDGES;
        rowst[N_NODES] = N_EDGES;
    }
}

// ---------------- K3: multisplit scatter into bucket segments ----------------
__global__ __launch_bounds__(256) void bucket_scatter_kernel(const int* __restrict__ src,
                                                             const int* __restrict__ dst,
                                                             int* __restrict__ bcursor,
                                                             int* __restrict__ bsrc,
                                                             unsigned short* __restrict__ blow) {
    __shared__ int lsrc[CHUNK];
    __shared__ int ldst[CHUNK];
    __shared__ int lhist[256];
    __shared__ int sc[256];
    __shared__ int lpre[256];
    __shared__ int gbase[256];
    __shared__ int lcur[256];
    int tid = threadIdx.x;
    int base = blockIdx.x * CHUNK;
    int n = N_EDGES - base; if (n > CHUNK) n = CHUNK;

    lhist[tid] = 0;
    __syncthreads();
    for (int i = tid; i < n; i += 256)
        atomicAdd(&lhist[dst[base + i] >> BSHIFT], 1);
    __syncthreads();
    int v = lhist[tid];
    sc[tid] = v;
    __syncthreads();
    for (int off = 1; off < 256; off <<= 1) {
        int nv = (tid >= off) ? sc[tid - off] : 0;
        __syncthreads();
        sc[tid] += nv;
        __syncthreads();
    }
    int ex = sc[tid] - v;
    lpre[tid] = ex;
    lcur[tid] = ex;
    if (tid < NB && v)
        gbase[tid] = atomicAdd(&bcursor[tid], v);
    __syncthreads();
    for (int i = tid; i < n; i += 256) {
        int d = dst[base + i];
        int s = src[base + i];
        int b = d >> BSHIFT;
        int pos = atomicAdd(&lcur[b], 1);
        lsrc[pos] = s;
        ldst[pos] = d;
    }
    __syncthreads();
    for (int i = tid; i < n; i += 256) {
        int d = ldst[i];
        int b = d >> BSHIFT;
        int gpos = gbase[b] + (i - lpre[b]);
        bsrc[gpos] = lsrc[i];
        blow[gpos] = (unsigned short)(d & (BSIZE - 1));
    }
}

// ---------------- K4a: per-(bucket,quarter) node histogram ----------------
__global__ __launch_bounds__(256) void node_count_kernel(const int* __restrict__ bstart,
                                                         const unsigned short* __restrict__ blow,
                                                         int* __restrict__ qcnt) {
    __shared__ int lcnt[BSIZE];
    int tid = threadIdx.x;
    int b = blockIdx.x / NSUB;
    int qt = blockIdx.x % NSUB;
    int ss = bstart[b], se = bstart[b + 1];
    int len = se - ss;
    int qs = ss + (int)(((long long)len * qt) / NSUB);
    int qe = ss + (int)(((long long)len * (qt + 1)) / NSUB);
    lcnt[tid] = 0; lcnt[tid + 256] = 0;
    __syncthreads();
    for (int i = qs + tid; i < qe; i += 256)
        atomicAdd(&lcnt[blow[i]], 1);
    __syncthreads();
    int* qc = qcnt + (size_t)blockIdx.x * BSIZE;
    qc[tid] = lcnt[tid];
    qc[tid + 256] = lcnt[tid + 256];
}

// ---------------- K4b: per-bucket scan over nodes+quarters -> rowst, qbase ----------------
__global__ __launch_bounds__(256) void node_scan_kernel(const int* __restrict__ bstart,
                                                        const int* __restrict__ qcnt,
                                                        int* __restrict__ qbase,
                                                        int* __restrict__ rowst) {
    __shared__ int sc[256];
    int tid = threadIdx.x;
    int b = blockIdx.x;
    int ss = bstart[b];
    const int* qc = qcnt + (size_t)b * NSUB * BSIZE;
    int j0 = 2 * tid, j1 = 2 * tid + 1;
    int c00 = qc[0 * BSIZE + j0], c01 = qc[1 * BSIZE + j0],
        c02 = qc[2 * BSIZE + j0], c03 = qc[3 * BSIZE + j0];
    int c10 = qc[0 * BSIZE + j1], c11 = qc[1 * BSIZE + j1],
        c12 = qc[2 * BSIZE + j1], c13 = qc[3 * BSIZE + j1];
    int t0 = c00 + c01 + c02 + c03;
    int t1 = c10 + c11 + c12 + c13;
    int s = t0 + t1;
    sc[tid] = s;
    __syncthreads();
    for (int off = 1; off < 256; off <<= 1) {
        int nv = (tid >= off) ? sc[tid - off] : 0;
        __syncthreads();
        sc[tid] += nv;
        __syncthreads();
    }
    int ex = sc[tid] - s;
    int base0 = ss + ex;
    int base1 = base0 + t0;
    int node_base = b << BSHIFT;
    if (node_base + j0 < N_NODES) rowst[node_base + j0] = base0;
    if (node_base + j1 < N_NODES) rowst[node_base + j1] = base1;
    int* qb = qbase + (size_t)b * NSUB * BSIZE;
    qb[0 * BSIZE + j0] = base0;
    qb[1 * BSIZE + j0] = base0 + c00;
    qb[2 * BSIZE + j0] = base0 + c00 + c01;
    qb[3 * BSIZE + j0] = base0 + c00 + c01 + c02;
    qb[0 * BSIZE + j1] = base1;
    qb[1 * BSIZE + j1] = base1 + c10;
    qb[2 * BSIZE + j1] = base1 + c10 + c11;
    qb[3 * BSIZE + j1] = base1 + c10 + c11 + c12;
}

// ---------------- K4c: per-(bucket,quarter) scatter -> csr ----------------
__global__ __launch_bounds__(256) void node_scatter_kernel(const int* __restrict__ bstart,
                                                           const int* __restrict__ bsrc,
                                                           const unsigned short* __restrict__ blow,
                                                           const int* __restrict__ qbase,
                                                           int* __restrict__ csr) {
    __shared__ int lcur[BSIZE];
    int tid = threadIdx.x;
    int b = blockIdx.x / NSUB;
    int qt = blockIdx.x % NSUB;
    int ss = bstart[b], se = bstart[b + 1];
    int len = se - ss;
    int qs = ss + (int)(((long long)len * qt) / NSUB);
    int qe = ss + (int)(((long long)len * (qt + 1)) / NSUB);
    const int* qb = qbase + (size_t)blockIdx.x * BSIZE;
    lcur[tid] = qb[tid];
    lcur[tid + 256] = qb[tid + 256];
    __syncthreads();
    for (int i = qs + tid; i < qe; i += 256) {
        int nloc = blow[i];
        int pos = atomicAdd(&lcur[nloc], 1);
        csr[pos] = bsrc[i];
    }
}

// ---------------- deg+1 as float ----------------
__global__ __launch_bounds__(256) void deg_kernel(const int* __restrict__ rowst,
                                                  float* __restrict__ degf) {
    int i = blockIdx.x * blockDim.x + threadIdx.x;
    if (i < N_NODES)
        degf[i] = (float)(rowst[i + 1] - rowst[i] + 1);
}

// ---------------- prep_t1: W1a (78x32, zero-pad K->96) -> 6 B-fragments f16 ----------------
// fragment f = kc*2+ct: elem for (lane l, e): k = kc*32+(l>>4)*8+e, col = ct*16+(l&15)
__global__ __launch_bounds__(1024) void prep_t1_kernel(const float* __restrict__ W1a,
                                                       __half* __restrict__ blob1) {
    int tid = threadIdx.x;
    for (int idx = tid; idx < 6 * 512; idx += 1024) {
        int e = idx & 7;
        int l = (idx >> 3) & 63;
        int f = idx >> 9;
        int kc = f >> 1, ct = f & 1;
        int k = kc * 32 + (l >> 4) * 8 + e;
        int col = ct * 16 + (l & 15);
        float v = (k < FEAT) ? W1a[k * DIM + col] : 0.f;
        blob1[idx] = __float2half(v);
    }
}

// ---------------- transform1: MFMA x @ W1a -> split tables T0/T1 ----------------
// One wave per 16-node tile; A-frags loaded from x (f32->f16), 6 MFMAs (K=96 padded).
__global__ __launch_bounds__(256) void transform1_kernel(const float* __restrict__ x,
                                                         const __half* __restrict__ blob1,
                                                         __half* __restrict__ T0,
                                                         __half* __restrict__ T1) {
    __shared__ __align__(16) _Float16 X[4][512];
    int tid = threadIdx.x;
    int wave = tid >> 6;
    int l = tid & 63;
    int d0 = l & 15, kg = l >> 4;
    int tile = blockIdx.x * 4 + wave;
    if (tile >= NTILES) return;
    int tb = tile * 16;
    const float* xr = x + (size_t)(tb + d0) * FEAT;

    f16x8 af0, af1, af2;
    #pragma unroll
    for (int j = 0; j < 4; ++j) {
        int k0 = kg * 8 + 2 * j;
        float2 v0 = *(const float2*)(xr + k0);           // k<64 always valid
        float2 v1 = *(const float2*)(xr + 32 + k0);
        af0[2 * j] = (_Float16)v0.x; af0[2 * j + 1] = (_Float16)v0.y;
        af1[2 * j] = (_Float16)v1.x; af1[2 * j + 1] = (_Float16)v1.y;
        int k2 = 64 + k0;
        float2 v2 = {0.f, 0.f};
        if (k2 < FEAT) v2 = *(const float2*)(xr + k2);   // k2 even, <=76 loads 76,77
        af2[2 * j] = (_Float16)v2.x; af2[2 * j + 1] = (_Float16)v2.y;
    }
    f16x8 b0 = *(const f16x8*)(blob1 + (0 * 64 + l) * 8);
    f16x8 b1 = *(const f16x8*)(blob1 + (1 * 64 + l) * 8);
    f16x8 b2 = *(const f16x8*)(blob1 + (2 * 64 + l) * 8);
    f16x8 b3 = *(const f16x8*)(blob1 + (3 * 64 + l) * 8);
    f16x8 b4 = *(const f16x8*)(blob1 + (4 * 64 + l) * 8);
    f16x8 b5 = *(const f16x8*)(blob1 + (5 * 64 + l) * 8);

    f32x4 c0 = {0.f, 0.f, 0.f, 0.f};
    f32x4 c1 = {0.f, 0.f, 0.f, 0.f};
    c0 = __builtin_amdgcn_mfma_f32_16x16x32_f16(af0, b0, c0, 0, 0, 0);
    c1 = __builtin_amdgcn_mfma_f32_16x16x32_f16(af0, b1, c1, 0, 0, 0);
    c0 = __builtin_amdgcn_mfma_f32_16x16x32_f16(af1, b2, c0, 0, 0, 0);
    c1 = __builtin_amdgcn_mfma_f32_16x16x32_f16(af1, b3, c1, 0, 0, 0);
    c0 = __builtin_amdgcn_mfma_f32_16x16x32_f16(af2, b4, c0, 0, 0, 0);
    c1 = __builtin_amdgcn_mfma_f32_16x16x32_f16(af2, b5, c1, 0, 0, 0);

    #pragma unroll
    for (int rr = 0; rr < 4; ++rr) {
        int row = kg * 4 + rr;
        X[wave][row * 32 + d0] = (_Float16)c0[rr];
        X[wave][row * 32 + d0 + 16] = (_Float16)c1[rr];
    }
    __builtin_amdgcn_wave_barrier();
    int gg = l >> 2, cq = l & 3;
    uint4 vv = *(uint4*)&X[wave][gg * 32 + cq * 8];
    __half* op = (cq & 2) ? T1 : T0;
    *(uint4*)(op + (size_t)(tb + gg) * HDIM + (cq & 1) * 8) = vv;
}

// ---------------- prep: reduce stat bins + BN-fold, weights in fragment layout ----------------
__global__ __launch_bounds__(1024) void prep_kernel(const float* __restrict__ sbins,
                                                    const float* __restrict__ gamma,
                                                    const float* __restrict__ beta,
                                                    const float* __restrict__ Wa,
                                                    const float* __restrict__ Wb,
                                                    __half* __restrict__ blob,
                                                    float* __restrict__ cwf) {
    __shared__ float st[64];
    __shared__ float a[DIM], c[DIM];
    int tid = threadIdx.x;
    if (tid < 64) {
        float s = 0.f;
        for (int b = 0; b < SBINS; ++b) s += sbins[b * 64 + tid];
        st[tid] = s;
    }
    __syncthreads();
    if (tid < DIM) {
        float mu = st[tid] * (1.f / N_NODES);
        float var = st[DIM + tid] * (1.f / N_NODES) - mu * mu;
        float av = gamma[tid] * rsqrtf(var + BN_EPS);
        a[tid] = av;
        c[tid] = beta[tid] - mu * av;
    }
    __syncthreads();
    int d = tid >> 5, k = tid & 31;
    blob[d * 32 + k] = __float2half(a[k] * Wa[k * 32 + d]);
    blob[1024 + d * 32 + k] = __float2half(Wb[k * 32 + d]);
    if (tid < DIM) {
        float s = 0.f;
        for (int kk = 0; kk < DIM; ++kk)
            s += c[kk] * Wa[kk * 32 + tid];
        cwf[tid] = s;
    }
}

__global__ __launch_bounds__(1024) void prep_id_kernel(const float* __restrict__ W1b,
                                                       __half* __restrict__ blob,
                                                       float* __restrict__ cwf) {
    int tid = threadIdx.x;
    int d = tid >> 5, k = tid & 31;
    blob[d * 32 + k] = __float2half((d == k) ? 1.f : 0.f);
    blob[1024 + d * 32 + k] = __float2half(W1b[k * 32 + d]);
    if (tid < DIM) cwf[tid] = 0.f;
}

#define ACC8(v) do { const __half2* hp_ = (const __half2*)&(v); float2 f_; \
  f_ = __half22float2(hp_[0]); a0 += f_.x; a1 += f_.y; \
  f_ = __half22float2(hp_[1]); a2 += f_.x; a3 += f_.y; \
  f_ = __half22float2(hp_[2]); a4 += f_.x; a5 += f_.y; \
  f_ = __half22float2(hp_[3]); a6 += f_.x; a7 += f_.y; } while (0)

// ---------------- agg_dual: both halves in one launch, XCD-partitioned ----------------
#define AGG_DUAL_BLOCKS 3128
__global__ __launch_bounds__(256) void agg_dual_kernel(const __half* __restrict__ T0,
                                                       const __half* __restrict__ T1,
                                                       const int* __restrict__ rowst,
                                                       const int* __restrict__ csr,
                                                       __half* __restrict__ outA) {
    int b = blockIdx.x;
    int half = (b >> 2) & 1;
    int idx_in_half = (b >> 3) * 4 + (b & 3);
    int tid = threadIdx.x;
    int wave = tid >> 6;
    int l = tid & 63;
    int g = l >> 2, e = (l >> 1) & 1, q = l & 1;
    int tile = idx_in_half * 4 + wave;
    if (tile >= NTILES) return;
    const __half* T = half ? T1 : T0;
    __half* outp = outA + half * HDIM;
    int node = tile * 16 + g;
    int rs = rowst[node], re = rowst[node + 1];
    float a0 = 0.f, a1 = 0.f, a2 = 0.f, a3 = 0.f,
          a4 = 0.f, a5 = 0.f, a6 = 0.f, a7 = 0.f;
    int p = rs;
    int idx[8];
    bool have = (p + 16 <= re);
    if (have) {
        #pragma unroll
        for (int j = 0; j < 8; ++j) idx[j] = csr[p + 8 * e + j];
    }
    while (have) {
        uint4 v[8];
        #pragma unroll
        for (int j = 0; j < 8; ++j)
            v[j] = *(const uint4*)(T + (size_t)idx[j] * HDIM + (q << 3));
        int np = p + 16;
        bool nhave = (np + 16 <= re);
        int nidx[8];
        if (nhave) {
            #pragma unroll
            for (int j = 0; j < 8; ++j) nidx[j] = csr[np + 8 * e + j];
        }
        #pragma unroll
        for (int j = 0; j < 8; ++j) ACC8(v[j]);
        #pragma unroll
        for (int j = 0; j < 8; ++j) idx[j] = nidx[j];
        p = np;
        have = nhave;
    }
    if (p < re) {
        #pragma unroll
        for (int j = 0; j < 8; ++j) {
            int ei = p + 8 * e + j;
            uint4 vv = {0, 0, 0, 0};
            if (ei < re) vv = *(const uint4*)(T + (size_t)csr[ei] * HDIM + (q << 3));
            ACC8(vv);
        }
    }
    a0 += __shfl_xor(a0, 2); a1 += __shfl_xor(a1, 2);
    a2 += __shfl_xor(a2, 2); a3 += __shfl_xor(a3, 2);
    a4 += __shfl_xor(a4, 2); a5 += __shfl_xor(a5, 2);
    a6 += __shfl_xor(a6, 2); a7 += __shfl_xor(a7, 2);
    if (e == 0) {
        uint4 vs = *(const uint4*)(T + (size_t)node * HDIM + (q << 3));
        ACC8(vs);
        f16x8 hv;
        hv[0] = (_Float16)a0; hv[1] = (_Float16)a1;
        hv[2] = (_Float16)a2; hv[3] = (_Float16)a3;
        hv[4] = (_Float16)a4; hv[5] = (_Float16)a5;
        hv[6] = (_Float16)a6; hv[7] = (_Float16)a7;
        *(f16x8*)(outp + (size_t)node * DIM + (q << 3)) = hv;
    }
}

// ---------------- mlp: streaming MFMA over nodes; binned BN stats ----------------
__global__ __launch_bounds__(256) void mlp_kernel(const __half* __restrict__ A16,
                                                  const float* __restrict__ degf,
                                                  const __half* __restrict__ blob,
                                                  const float* __restrict__ cwf,
                                                  const float* __restrict__ bias_a,
                                                  const float* __restrict__ bias_b,
                                                  __half* __restrict__ out0,
                                                  __half* __restrict__ out1,
                                                  float* __restrict__ sbins) {
    __shared__ __align__(16) _Float16 X[4][512];
    int tid = threadIdx.x;
    int wave = tid >> 6;
    int l = tid & 63;
    int d0 = l & 15, kg = l >> 4;
    int tile = blockIdx.x * 4 + wave;
    if (tile >= NTILES) return;
    int tb = tile * 16;

    f16x8 af = *(const f16x8*)(A16 + (size_t)(tb + d0) * DIM + kg * 8);
    f16x8 bA0 = *(const f16x8*)(blob + d0 * 32 + kg * 8);
    f16x8 bA1 = *(const f16x8*)(blob + (d0 + 16) * 32 + kg * 8);
    f16x8 bB0 = *(const f16x8*)(blob + 1024 + d0 * 32 + kg * 8);
    f16x8 bB1 = *(const f16x8*)(blob + 1024 + (d0 + 16) * 32 + kg * 8);
    f32x4 degv = *(const f32x4*)(degf + tb + kg * 4);
    float cw0 = cwf[d0], cw1 = cwf[d0 + 16];
    float ba0 = bias_a[d0], ba1 = bias_a[d0 + 16];
    float bb0 = bias_b[d0], bb1 = bias_b[d0 + 16];

    f32x4 c0 = {ba0, ba0, ba0, ba0};
    f32x4 c1 = {ba1, ba1, ba1, ba1};
    c0 = __builtin_amdgcn_mfma_f32_16x16x32_f16(af, bA0, c0, 0, 0, 0);
    c1 = __builtin_amdgcn_mfma_f32_16x16x32_f16(af, bA1, c1, 0, 0, 0);
    #pragma unroll
    for (int rr = 0; rr < 4; ++rr) {
        float v0 = fmaxf(c0[rr] + degv[rr] * cw0, 0.f);
        float v1 = fmaxf(c1[rr] + degv[rr] * cw1, 0.f);
        int row = kg * 4 + rr;
        X[wave][row * 32 + d0] = (_Float16)v0;
        X[wave][row * 32 + d0 + 16] = (_Float16)v1;
    }
    __builtin_amdgcn_wave_barrier();
    f16x8 af2 = *(f16x8*)&X[wave][d0 * 32 + kg * 8];
    __builtin_amdgcn_wave_barrier();

    f32x4 e0 = {bb0, bb0, bb0, bb0};
    f32x4 e1 = {bb1, bb1, bb1, bb1};
    e0 = __builtin_amdgcn_mfma_f32_16x16x32_f16(af2, bB0, e0, 0, 0, 0);
    e1 = __builtin_amdgcn_mfma_f32_16x16x32_f16(af2, bB1, e1, 0, 0, 0);
    float s0 = 0.f, ss0 = 0.f, s1 = 0.f, ss1 = 0.f;
    #pragma unroll
    for (int rr = 0; rr < 4; ++rr) {
        float y0 = fmaxf(e0[rr], 0.f);
        float y1 = fmaxf(e1[rr], 0.f);
        s0 += y0; ss0 += y0 * y0;
        s1 += y1; ss1 += y1 * y1;
        int row = kg * 4 + rr;
        X[wave][row * 32 + d0] = (_Float16)y0;
        X[wave][row * 32 + d0 + 16] = (_Float16)y1;
    }
    __builtin_amdgcn_wave_barrier();
    {
        int gg = l >> 2, c = l & 3;
        uint4 vv = *(uint4*)&X[wave][gg * 32 + c * 8];
        __half* op = (c & 2) ? out1 : out0;
        *(uint4*)(op + (size_t)(tb + gg) * HDIM + (c & 1) * 8) = vv;
    }
    s0 += __shfl_xor(s0, 16); s0 += __shfl_xor(s0, 32);
    ss0 += __shfl_xor(ss0, 16); ss0 += __shfl_xor(ss0, 32);
    s1 += __shfl_xor(s1, 16); s1 += __shfl_xor(s1, 32);
    ss1 += __shfl_xor(ss1, 16); ss1 += __shfl_xor(ss1, 32);
    if (kg == 0) {
        float* sb = sbins + ((blockIdx.x * 4 + wave) & (SBINS - 1)) * 64;
        atomicAdd(&sb[d0], s0);
        atomicAdd(&sb[DIM + d0], ss0);
        atomicAdd(&sb[d0 + 16], s1);
        atomicAdd(&sb[DIM + d0 + 16], ss1);
    }
}

// ---------------- final BN + global_add_pool (run-length, batch sorted) ----------------
#define POOL_BLOCKS 512
__global__ __launch_bounds__(256) void bn_pool_kernel(const __half* __restrict__ h0,
                                                      const __half* __restrict__ h1,
                                                      const float* __restrict__ sbins,
                                                      const float* __restrict__ gamma,
                                                      const float* __restrict__ beta,
                                                      const int* __restrict__ batch,
                                                      float* __restrict__ pooled) {
    __shared__ float st[64];
    int tid = threadIdx.x;
    if (tid < 64) {
        float s = 0.f;
        for (int b = 0; b < SBINS; ++b) s += sbins[b * 64 + tid];
        st[tid] = s;
    }
    __syncthreads();
    int lane = tid & 31;
    int group = tid >> 5;
    float mu = st[lane] * (1.f / N_NODES);
    float var = st[DIM + lane] * (1.f / N_NODES) - mu * mu;
    float inv = rsqrtf(var + BN_EPS);
    float a = gamma[lane] * inv;
    float c = beta[lane] - mu * a;
    const __half* hp = (lane < HDIM) ? h0 : h1;
    int loff = lane & (HDIM - 1);
    const int ngroups = POOL_BLOCKS * 8;
    const int chunk = (N_NODES + ngroups - 1) / ngroups;
    int g = blockIdx.x * 8 + group;
    int start = g * chunk;
    if (start >= N_NODES) return;
    int end = start + chunk; if (end > N_NODES) end = N_NODES;
    int cur = batch[start];
    float s = 0.f;
    for (int node = start; node < end; ++node) {
        float v = __half2float(hp[(size_t)node * HDIM + loff]) * a + c;
        int bg = batch[node];
        if (bg != cur) {
            atomicAdd(&pooled[cur * DIM + lane], s);
            s = 0.f;
            cur = bg;
        }
        s += v;
    }
    atomicAdd(&pooled[cur * DIM + lane], s);
}

// ---------------- out = relu(pooled @ Wfc + bfc) ----------------
__global__ __launch_bounds__(256) void fc_kernel(const float* __restrict__ pooled,
                                                 const float* __restrict__ Wfc,
                                                 const float* __restrict__ bfc,
                                                 float* __restrict__ out) {
    __shared__ float Wl[DIM * OUT_DIM];
    for (int i = threadIdx.x; i < DIM * OUT_DIM; i += blockDim.x) Wl[i] = Wfc[i];
    __syncthreads();
    int idx = blockIdx.x * blockDim.x + threadIdx.x;
    int stride = gridDim.x * blockDim.x;
    for (; idx < N_GRAPHS * OUT_DIM; idx += stride) {
        int g = idx >> 7;
        int o = idx & 127;
        float acc = bfc[o];
        #pragma unroll
        for (int k = 0; k < DIM; ++k)
            acc += pooled[g * DIM + k] * Wl[k * OUT_DIM + o];
        out[idx] = fmaxf(acc, 0.f);
    }
}

extern "C" void kernel_launch(void* const* d_in, const int* in_sizes, int n_in,
                              void* d_out, int out_size, void* d_ws, size_t ws_size,
                              hipStream_t stream) {
    const float* x   = (const float*)d_in[0];
    const int* eidx  = (const int*)d_in[1];
    const int* src   = eidx;
    const int* dst   = eidx + N_EDGES;
    const int* batch = (const int*)d_in[2];
    const float* W1a = (const float*)d_in[3];
    const float* b1a = (const float*)d_in[4];
    const float* W1b = (const float*)d_in[5];
    const float* b1b = (const float*)d_in[6];
    const float* Wa  = (const float*)d_in[7];
    const float* ba  = (const float*)d_in[8];
    const float* Wb  = (const float*)d_in[9];
    const float* bb  = (const float*)d_in[10];
    const float* gamma = (const float*)d_in[11];
    const float* beta  = (const float*)d_in[12];
    const float* Wfc = (const float*)d_in[13];
    const float* bfc = (const float*)d_in[14];
    float* out = (float*)d_out;

    const size_t TSZ = (size_t)N_NODES * HDIM;               // 1.6M halfs
    __half* TA0 = (__half*)d_ws;
    __half* TA1 = TA0 + TSZ;
    __half* TB0 = TA1 + TSZ;
    __half* TB1 = TB0 + TSZ;                                 // 12.8 MB
    __half* A16 = TB1 + TSZ;                                 // 6.4 MB
    float* degf   = (float*)(A16 + (size_t)N_NODES * DIM);   // 400 KB
    float* sbins  = degf + N_NODES;                          // 5 * SBINS * 64
    float* pooled = sbins + 5 * SBINS * 64;                  // 256 KB
    float* cwf    = pooled + N_GRAPHS * DIM;                 // 5*32
    __half* blobs = (__half*)(cwf + 5 * 32);                 // 5*2048 halfs
    __half* blob1 = blobs + 5 * 2048;                        // 3072 halfs
    int* csr      = (int*)(blob1 + 6 * 512);                 // 12.8 MB
    int* rowst    = csr + N_EDGES;                           // N_NODES+1
    int* bcnt     = rowst + N_NODES + 1;
    int* bstart   = bcnt + 256;
    int* bcursor  = bstart + NB + 1;
    int* qcnt     = bcursor + 256;                           // NB*NSUB*BSIZE
    int* qbase    = qcnt + NB * NSUB * BSIZE;

    // CSR-build scratch aliases (dead before first use of their hosts)
    int* bsrc            = (int*)TA0;             // 12.8 MB over the 4 T tables
    unsigned short* blow = (unsigned short*)A16;  // 6.4 MB over A16

    hipMemsetAsync(bcnt, 0, 256 * sizeof(int), stream);
    hipMemsetAsync(sbins, 0, 5 * SBINS * 64 * sizeof(float), stream);
    hipMemsetAsync(pooled, 0, N_GRAPHS * DIM * sizeof(float), stream);

    bucket_hist_kernel<<<1024, 256, 0, stream>>>(dst, bcnt);
    bucket_scan_kernel<<<1, 256, 0, stream>>>(bcnt, bstart, bcursor, rowst);
    bucket_scatter_kernel<<<(N_EDGES + CHUNK - 1) / CHUNK, 256, 0, stream>>>(src, dst, bcursor, bsrc, blow);
    node_count_kernel<<<NB * NSUB, 256, 0, stream>>>(bstart, blow, qcnt);
    node_scan_kernel<<<NB, 256, 0, stream>>>(bstart, qcnt, qbase, rowst);
    node_scatter_kernel<<<NB * NSUB, 256, 0, stream>>>(bstart, bsrc, blow, qbase, csr);

    deg_kernel<<<(N_NODES + 255) / 256, 256, 0, stream>>>(rowst, degf);
    prep_t1_kernel<<<1, 1024, 0, stream>>>(W1a, blob1);
    transform1_kernel<<<(NTILES + 3) / 4, 256, 0, stream>>>(x, blob1, TA0, TA1);

    prep_id_kernel<<<1, 1024, 0, stream>>>(W1b, blobs, cwf);

    const __half *in0 = TA0, *in1 = TA1;
    __half *o0 = TB0, *o1 = TB1;

    // layer 1
    agg_dual_kernel<<<AGG_DUAL_BLOCKS, 256, 0, stream>>>(in0, in1, rowst, csr, A16);
    mlp_kernel<<<(NTILES + 3) / 4, 256, 0, stream>>>(A16, degf, blobs, cwf, b1a, b1b, o0, o1, sbins);
    { const __half* t0 = in0; in0 = o0; o0 = (__half*)t0;
      const __half* t1 = in1; in1 = o1; o1 = (__half*)t1; }

    for (int i = 0; i < 4; ++i) {
        __half* blob_i = blobs + (i + 1) * 2048;
        float* cwf_i = cwf + (i + 1) * 32;
        prep_kernel<<<1, 1024, 0, stream>>>(sbins + i * SBINS * 64, gamma + i * DIM, beta + i * DIM,
                                            Wa + i * DIM * DIM, Wb + i * DIM * DIM, blob_i, cwf_i);
        agg_dual_kernel<<<AGG_DUAL_BLOCKS, 256, 0, stream>>>(in0, in1, rowst, csr, A16);
        mlp_kernel<<<(NTILES + 3) / 4, 256, 0, stream>>>(A16, degf, blob_i, cwf_i,
                                                         ba + i * DIM, bb + i * DIM, o0, o1,
                                                         sbins + (i + 1) * SBINS * 64);
        { const __half* t0 = in0; in0 = o0; o0 = (__half*)t0;
          const __half* t1 = in1; in1 = o1; o1 = (__half*)t1; }
    }

    bn_pool_kernel<<<POOL_BLOCKS, 256, 0, stream>>>(in0, in1, sbins + 4 * SBINS * 64,
                                                    gamma + 4 * DIM, beta + 4 * DIM, batch, pooled);
    fc_kernel<<<1024, 256, 0, stream>>>(pooled, Wfc, bfc, out);
}

// Round 12
// 369.405 us; speedup vs baseline: 3.2371x; 1.1703x over previous
//
#include <hip/hip_runtime.h>
#include <hip/hip_fp16.h>

#define N_NODES 100000
#define N_GRAPHS 2048
#define N_EDGES 3200000
#define NHALF 50000
#define DIM 32
#define FEAT 78
#define OUT_DIM 128
#define BN_EPS 1e-5f

#define BSHIFT 9
#define BSIZE 512
#define NB ((N_NODES + BSIZE - 1) / BSIZE)   // 196
#define CHUNK 8192
#define NSUB 4

#define NTILES (N_NODES / 16)          // 6250
#define SBINS 64
#define AGG_BLOCKS 3128

typedef _Float16 f16x8 __attribute__((ext_vector_type(8)));
typedef float f32x4 __attribute__((ext_vector_type(4)));

// ---------------- K1: coarse bucket histogram (int4-vectorized) ----------------
__global__ __launch_bounds__(256) void bucket_hist_kernel(const int* __restrict__ dst,
                                                          int* __restrict__ bcnt) {
    __shared__ int lh[256];
    int tid = threadIdx.x;
    lh[tid] = 0;
    __syncthreads();
    const int4* d4 = (const int4*)dst;
    const int n4 = N_EDGES / 4;
    int i = blockIdx.x * blockDim.x + tid;
    int stride = gridDim.x * blockDim.x;
    for (; i < n4; i += stride) {
        int4 v = d4[i];
        atomicAdd(&lh[v.x >> BSHIFT], 1);
        atomicAdd(&lh[v.y >> BSHIFT], 1);
        atomicAdd(&lh[v.z >> BSHIFT], 1);
        atomicAdd(&lh[v.w >> BSHIFT], 1);
    }
    __syncthreads();
    if (tid < NB && lh[tid])
        atomicAdd(&bcnt[tid], lh[tid]);
}

// ---------------- K2: scan over buckets ----------------
__global__ __launch_bounds__(256) void bucket_scan_kernel(const int* __restrict__ bcnt,
                                                          int* __restrict__ bstart,
                                                          int* __restrict__ bcursor,
                                                          int* __restrict__ rowst) {
    __shared__ int sc[256];
    int tid = threadIdx.x;
    int v = (tid < NB) ? bcnt[tid] : 0;
    sc[tid] = v;
    __syncthreads();
    for (int off = 1; off < 256; off <<= 1) {
        int nv = (tid >= off) ? sc[tid - off] : 0;
        __syncthreads();
        sc[tid] += nv;
        __syncthreads();
    }
    if (tid < NB) {
        int ex = sc[tid] - v;
        bstart[tid] = ex;
        bcursor[tid] = ex;
    }
    if (tid == 0) {
        bstart[NB] = N_EDGES;
        rowst[N_NODES] = N_EDGES;
    }
}

// ---------------- K3: multisplit scatter into bucket segments ----------------
__global__ __launch_bounds__(256) void bucket_scatter_kernel(const int* __restrict__ src,
                                                             const int* __restrict__ dst,
                                                             int* __restrict__ bcursor,
                                                             int* __restrict__ bsrc,
                                                             unsigned short* __restrict__ blow) {
    __shared__ int lsrc[CHUNK];
    __shared__ int ldst[CHUNK];
    __shared__ int lhist[256];
    __shared__ int sc[256];
    __shared__ int lpre[256];
    __shared__ int gbase[256];
    __shared__ int lcur[256];
    int tid = threadIdx.x;
    int base = blockIdx.x * CHUNK;
    int n = N_EDGES - base; if (n > CHUNK) n = CHUNK;

    lhist[tid] = 0;
    __syncthreads();
    for (int i = tid; i < n; i += 256)
        atomicAdd(&lhist[dst[base + i] >> BSHIFT], 1);
    __syncthreads();
    int v = lhist[tid];
    sc[tid] = v;
    __syncthreads();
    for (int off = 1; off < 256; off <<= 1) {
        int nv = (tid >= off) ? sc[tid - off] : 0;
        __syncthreads();
        sc[tid] += nv;
        __syncthreads();
    }
    int ex = sc[tid] - v;
    lpre[tid] = ex;
    lcur[tid] = ex;
    if (tid < NB && v)
        gbase[tid] = atomicAdd(&bcursor[tid], v);
    __syncthreads();
    for (int i = tid; i < n; i += 256) {
        int d = dst[base + i];
        int s = src[base + i];
        int b = d >> BSHIFT;
        int pos = atomicAdd(&lcur[b], 1);
        lsrc[pos] = s;
        ldst[pos] = d;
    }
    __syncthreads();
    for (int i = tid; i < n; i += 256) {
        int d = ldst[i];
        int b = d >> BSHIFT;
        int gpos = gbase[b] + (i - lpre[b]);
        bsrc[gpos] = lsrc[i];
        blow[gpos] = (unsigned short)(d & (BSIZE - 1));
    }
}

// ---------------- K4a: per-(bucket,quarter) histogram, packed (tot<<16)|cnt_lo ----------------
__global__ __launch_bounds__(256) void node_count_kernel(const int* __restrict__ bstart,
                                                         const int* __restrict__ bsrc,
                                                         const unsigned short* __restrict__ blow,
                                                         int* __restrict__ qcnt) {
    __shared__ int lcnt[BSIZE];
    int tid = threadIdx.x;
    int b = blockIdx.x / NSUB;
    int qt = blockIdx.x % NSUB;
    int ss = bstart[b], se = bstart[b + 1];
    int len = se - ss;
    int qs = ss + (int)(((long long)len * qt) / NSUB);
    int qe = ss + (int)(((long long)len * (qt + 1)) / NSUB);
    lcnt[tid] = 0; lcnt[tid + 256] = 0;
    __syncthreads();
    for (int i = qs + tid; i < qe; i += 256) {
        int add = 0x10000 | (bsrc[i] < NHALF ? 1 : 0);
        atomicAdd(&lcnt[blow[i]], add);
    }
    __syncthreads();
    int* qc = qcnt + (size_t)blockIdx.x * BSIZE;
    qc[tid] = lcnt[tid];
    qc[tid + 256] = lcnt[tid + 256];
}

// ---------------- K4b: per-bucket scan -> rowst, rowmid, qbase0/1 ----------------
__global__ __launch_bounds__(256) void node_scan_kernel(const int* __restrict__ bstart,
                                                        const int* __restrict__ qcnt,
                                                        int* __restrict__ qbase0,
                                                        int* __restrict__ qbase1,
                                                        int* __restrict__ rowst,
                                                        int* __restrict__ rowmid) {
    __shared__ int sc[256];
    int tid = threadIdx.x;
    int b = blockIdx.x;
    int ss = bstart[b];
    const int* qc = qcnt + (size_t)b * NSUB * BSIZE;
    int j0 = 2 * tid, j1 = 2 * tid + 1;
    int pk0[NSUB], pk1[NSUB];
    int t0 = 0, t1 = 0, m0 = 0, m1 = 0;
    #pragma unroll
    for (int q = 0; q < NSUB; ++q) {
        pk0[q] = qc[q * BSIZE + j0];
        pk1[q] = qc[q * BSIZE + j1];
        t0 += pk0[q] >> 16; m0 += pk0[q] & 0xFFFF;
        t1 += pk1[q] >> 16; m1 += pk1[q] & 0xFFFF;
    }
    int s = t0 + t1;
    sc[tid] = s;
    __syncthreads();
    for (int off = 1; off < 256; off <<= 1) {
        int nv = (tid >= off) ? sc[tid - off] : 0;
        __syncthreads();
        sc[tid] += nv;
        __syncthreads();
    }
    int ex = sc[tid] - s;
    int B0 = ss + ex;
    int B1 = B0 + t0;
    int node_base = b << BSHIFT;
    if (node_base + j0 < N_NODES) { rowst[node_base + j0] = B0; rowmid[node_base + j0] = B0 + m0; }
    if (node_base + j1 < N_NODES) { rowst[node_base + j1] = B1; rowmid[node_base + j1] = B1 + m1; }
    int r0a = B0, r0b = B0 + m0;
    int r1a = B1, r1b = B1 + m1;
    #pragma unroll
    for (int q = 0; q < NSUB; ++q) {
        int c0 = pk0[q] & 0xFFFF, ct = pk0[q] >> 16;
        qbase0[((size_t)b * NSUB + q) * BSIZE + j0] = r0a; r0a += c0;
        qbase1[((size_t)b * NSUB + q) * BSIZE + j0] = r0b; r0b += ct - c0;
        int d0c = pk1[q] & 0xFFFF, dt = pk1[q] >> 16;
        qbase0[((size_t)b * NSUB + q) * BSIZE + j1] = r1a; r1a += d0c;
        qbase1[((size_t)b * NSUB + q) * BSIZE + j1] = r1b; r1b += dt - d0c;
    }
}

// ---------------- K4c: per-(bucket,quarter) scatter (src-range split) -> csr ----------------
__global__ __launch_bounds__(256) void node_scatter_kernel(const int* __restrict__ bstart,
                                                           const int* __restrict__ bsrc,
                                                           const unsigned short* __restrict__ blow,
                                                           const int* __restrict__ qbase0,
                                                           const int* __restrict__ qbase1,
                                                           int* __restrict__ csr) {
    __shared__ int lcur[2 * BSIZE];
    int tid = threadIdx.x;
    int b = blockIdx.x / NSUB;
    int qt = blockIdx.x % NSUB;
    int ss = bstart[b], se = bstart[b + 1];
    int len = se - ss;
    int qs = ss + (int)(((long long)len * qt) / NSUB);
    int qe = ss + (int)(((long long)len * (qt + 1)) / NSUB);
    size_t off = ((size_t)b * NSUB + qt) * BSIZE;
    for (int j = tid; j < BSIZE; j += 256) {
        lcur[j] = qbase0[off + j];
        lcur[BSIZE + j] = qbase1[off + j];
    }
    __syncthreads();
    for (int i = qs + tid; i < qe; i += 256) {
        int s = bsrc[i];
        int nloc = blow[i];
        int r = (s >= NHALF) ? BSIZE : 0;
        int pos = atomicAdd(&lcur[r + nloc], 1);
        csr[pos] = s;
    }
}

// ---------------- deg+1 as float ----------------
__global__ __launch_bounds__(256) void deg_kernel(const int* __restrict__ rowst,
                                                  float* __restrict__ degf) {
    int i = blockIdx.x * blockDim.x + threadIdx.x;
    if (i < N_NODES)
        degf[i] = (float)(rowst[i + 1] - rowst[i] + 1);
}

// ---------------- prep_t1: W1a (78x32, zero-pad K->96) -> 6 B-fragments f16 ----------------
__global__ __launch_bounds__(1024) void prep_t1_kernel(const float* __restrict__ W1a,
                                                       __half* __restrict__ blob1) {
    int tid = threadIdx.x;
    for (int idx = tid; idx < 6 * 512; idx += 1024) {
        int e = idx & 7;
        int l = (idx >> 3) & 63;
        int f = idx >> 9;
        int kc = f >> 1, ct = f & 1;
        int k = kc * 32 + (l >> 4) * 8 + e;
        int col = ct * 16 + (l & 15);
        float v = (k < FEAT) ? W1a[k * DIM + col] : 0.f;
        blob1[idx] = __float2half(v);
    }
}

// ---------------- transform1: MFMA x @ W1a -> table T [node][32] ----------------
__global__ __launch_bounds__(256) void transform1_kernel(const float* __restrict__ x,
                                                         const __half* __restrict__ blob1,
                                                         __half* __restrict__ T) {
    __shared__ __align__(16) _Float16 X[4][512];
    int tid = threadIdx.x;
    int wave = tid >> 6;
    int l = tid & 63;
    int d0 = l & 15, kg = l >> 4;
    int tile = blockIdx.x * 4 + wave;
    if (tile >= NTILES) return;
    int tb = tile * 16;
    const float* xr = x + (size_t)(tb + d0) * FEAT;

    f16x8 af0, af1, af2;
    #pragma unroll
    for (int j = 0; j < 4; ++j) {
        int k0 = kg * 8 + 2 * j;
        float2 v0 = *(const float2*)(xr + k0);
        float2 v1 = *(const float2*)(xr + 32 + k0);
        af0[2 * j] = (_Float16)v0.x; af0[2 * j + 1] = (_Float16)v0.y;
        af1[2 * j] = (_Float16)v1.x; af1[2 * j + 1] = (_Float16)v1.y;
        int k2 = 64 + k0;
        float2 v2 = {0.f, 0.f};
        if (k2 < FEAT) v2 = *(const float2*)(xr + k2);
        af2[2 * j] = (_Float16)v2.x; af2[2 * j + 1] = (_Float16)v2.y;
    }
    f16x8 b0 = *(const f16x8*)(blob1 + (0 * 64 + l) * 8);
    f16x8 b1 = *(const f16x8*)(blob1 + (1 * 64 + l) * 8);
    f16x8 b2 = *(const f16x8*)(blob1 + (2 * 64 + l) * 8);
    f16x8 b3 = *(const f16x8*)(blob1 + (3 * 64 + l) * 8);
    f16x8 b4 = *(const f16x8*)(blob1 + (4 * 64 + l) * 8);
    f16x8 b5 = *(const f16x8*)(blob1 + (5 * 64 + l) * 8);

    f32x4 c0 = {0.f, 0.f, 0.f, 0.f};
    f32x4 c1 = {0.f, 0.f, 0.f, 0.f};
    c0 = __builtin_amdgcn_mfma_f32_16x16x32_f16(af0, b0, c0, 0, 0, 0);
    c1 = __builtin_amdgcn_mfma_f32_16x16x32_f16(af0, b1, c1, 0, 0, 0);
    c0 = __builtin_amdgcn_mfma_f32_16x16x32_f16(af1, b2, c0, 0, 0, 0);
    c1 = __builtin_amdgcn_mfma_f32_16x16x32_f16(af1, b3, c1, 0, 0, 0);
    c0 = __builtin_amdgcn_mfma_f32_16x16x32_f16(af2, b4, c0, 0, 0, 0);
    c1 = __builtin_amdgcn_mfma_f32_16x16x32_f16(af2, b5, c1, 0, 0, 0);

    #pragma unroll
    for (int rr = 0; rr < 4; ++rr) {
        int row = kg * 4 + rr;
        X[wave][row * 32 + d0] = (_Float16)c0[rr];
        X[wave][row * 32 + d0 + 16] = (_Float16)c1[rr];
    }
    __builtin_amdgcn_wave_barrier();
    int gg = l >> 2, cq = l & 3;
    uint4 vv = *(uint4*)&X[wave][gg * 32 + cq * 8];
    *(uint4*)(T + (size_t)(tb + gg) * DIM + cq * 8) = vv;
}

// ---------------- prep: reduce stat bins + BN-fold, weights in fragment layout ----------------
__global__ __launch_bounds__(1024) void prep_kernel(const float* __restrict__ sbins,
                                                    const float* __restrict__ gamma,
                                                    const float* __restrict__ beta,
                                                    const float* __restrict__ Wa,
                                                    const float* __restrict__ Wb,
                                                    __half* __restrict__ blob,
                                                    float* __restrict__ cwf) {
    __shared__ float st[64];
    __shared__ float a[DIM], c[DIM];
    int tid = threadIdx.x;
    if (tid < 64) {
        float s = 0.f;
        for (int b = 0; b < SBINS; ++b) s += sbins[b * 64 + tid];
        st[tid] = s;
    }
    __syncthreads();
    if (tid < DIM) {
        float mu = st[tid] * (1.f / N_NODES);
        float var = st[DIM + tid] * (1.f / N_NODES) - mu * mu;
        float av = gamma[tid] * rsqrtf(var + BN_EPS);
        a[tid] = av;
        c[tid] = beta[tid] - mu * av;
    }
    __syncthreads();
    int d = tid >> 5, k = tid & 31;
    blob[d * 32 + k] = __float2half(a[k] * Wa[k * 32 + d]);
    blob[1024 + d * 32 + k] = __float2half(Wb[k * 32 + d]);
    if (tid < DIM) {
        float s = 0.f;
        for (int kk = 0; kk < DIM; ++kk)
            s += c[kk] * Wa[kk * 32 + tid];
        cwf[tid] = s;
    }
}

__global__ __launch_bounds__(1024) void prep_id_kernel(const float* __restrict__ W1b,
                                                       __half* __restrict__ blob,
                                                       float* __restrict__ cwf) {
    int tid = threadIdx.x;
    int d = tid >> 5, k = tid & 31;
    blob[d * 32 + k] = __float2half((d == k) ? 1.f : 0.f);
    blob[1024 + d * 32 + k] = __float2half(W1b[k * 32 + d]);
    if (tid < DIM) cwf[tid] = 0.f;
}

#define ACC8(v) do { const __half2* hp_ = (const __half2*)&(v); float2 f_; \
  f_ = __half22float2(hp_[0]); a0 += f_.x; a1 += f_.y; \
  f_ = __half22float2(hp_[1]); a2 += f_.x; a3 += f_.y; \
  f_ = __half22float2(hp_[2]); a4 += f_.x; a5 += f_.y; \
  f_ = __half22float2(hp_[3]); a6 += f_.x; a7 += f_.y; } while (0)

// ---------------- agg_pass: src-range-partitioned gather, XCD-split, full 64B rows ----------
// XCDs 0-3 (half 0): edges with src<NHALF (hot rows 0..NHALF = 3.2MB, L2-resident).
// XCDs 4-7 (half 1): src>=NHALF. Lane l: node g=l>>2, 16B chunk q=l&3. No shuffles:
// each lane exclusively owns 8 dims of its node; partials stored f16.
__global__ __launch_bounds__(256) void agg_pass_kernel(const __half* __restrict__ T,
                                                       const int* __restrict__ rowst,
                                                       const int* __restrict__ rowmid,
                                                       const int* __restrict__ csr,
                                                       __half* __restrict__ P0,
                                                       __half* __restrict__ P1) {
    int b = blockIdx.x;
    int half = (b >> 2) & 1;
    int idx_in_half = (b >> 3) * 4 + (b & 3);
    int tid = threadIdx.x;
    int wave = tid >> 6;
    int l = tid & 63;
    int g = l >> 2, q = l & 3;
    int tile = idx_in_half * 4 + wave;
    if (tile >= NTILES) return;
    int node = tile * 16 + g;
    int ps, pe;
    if (half == 0) { ps = rowst[node]; pe = rowmid[node]; }
    else           { ps = rowmid[node]; pe = rowst[node + 1]; }
    float a0 = 0.f, a1 = 0.f, a2 = 0.f, a3 = 0.f,
          a4 = 0.f, a5 = 0.f, a6 = 0.f, a7 = 0.f;
    int p = ps;
    int idx[8];
    bool have = (p + 8 <= pe);
    if (have) {
        #pragma unroll
        for (int j = 0; j < 8; ++j) idx[j] = csr[p + j];
    }
    while (have) {
        uint4 v[8];
        #pragma unroll
        for (int j = 0; j < 8; ++j)
            v[j] = *(const uint4*)(T + (size_t)idx[j] * DIM + (q << 3));
        int np = p + 8;
        bool nhave = (np + 8 <= pe);
        int nidx[8];
        if (nhave) {
            #pragma unroll
            for (int j = 0; j < 8; ++j) nidx[j] = csr[np + j];
        }
        #pragma unroll
        for (int j = 0; j < 8; ++j) ACC8(v[j]);
        #pragma unroll
        for (int j = 0; j < 8; ++j) idx[j] = nidx[j];
        p = np;
        have = nhave;
    }
    if (p < pe) {
        #pragma unroll
        for (int j = 0; j < 8; ++j) {
            int ei = p + j;
            uint4 vv = {0, 0, 0, 0};
            if (ei < pe) vv = *(const uint4*)(T + (size_t)csr[ei] * DIM + (q << 3));
            ACC8(vv);
        }
    }
    // self term handled by the half that owns the node's (L2-hot) row
    int selfhalf = (node < NHALF) ? 0 : 1;
    if (selfhalf == half) {
        uint4 vs = *(const uint4*)(T + (size_t)node * DIM + (q << 3));
        ACC8(vs);
    }
    __half* P = half ? P1 : P0;
    f16x8 hv;
    hv[0] = (_Float16)a0; hv[1] = (_Float16)a1;
    hv[2] = (_Float16)a2; hv[3] = (_Float16)a3;
    hv[4] = (_Float16)a4; hv[5] = (_Float16)a5;
    hv[6] = (_Float16)a6; hv[7] = (_Float16)a7;
    *(f16x8*)(P + (size_t)node * DIM + (q << 3)) = hv;
}

// ---------------- mlp: P0+P1 -> MFMA MLP -> next table; binned BN stats ----------------
__global__ __launch_bounds__(256) void mlp_kernel(const __half* __restrict__ P0,
                                                  const __half* __restrict__ P1,
                                                  const float* __restrict__ degf,
                                                  const __half* __restrict__ blob,
                                                  const float* __restrict__ cwf,
                                                  const float* __restrict__ bias_a,
                                                  const float* __restrict__ bias_b,
                                                  __half* __restrict__ outT,
                                                  float* __restrict__ sbins) {
    __shared__ __align__(16) _Float16 X[4][512];
    int tid = threadIdx.x;
    int wave = tid >> 6;
    int l = tid & 63;
    int d0 = l & 15, kg = l >> 4;
    int tile = blockIdx.x * 4 + wave;
    if (tile >= NTILES) return;
    int tb = tile * 16;

    f16x8 v0 = *(const f16x8*)(P0 + (size_t)(tb + d0) * DIM + kg * 8);
    f16x8 v1 = *(const f16x8*)(P1 + (size_t)(tb + d0) * DIM + kg * 8);
    f16x8 af = v0 + v1;
    f16x8 bA0 = *(const f16x8*)(blob + d0 * 32 + kg * 8);
    f16x8 bA1 = *(const f16x8*)(blob + (d0 + 16) * 32 + kg * 8);
    f16x8 bB0 = *(const f16x8*)(blob + 1024 + d0 * 32 + kg * 8);
    f16x8 bB1 = *(const f16x8*)(blob + 1024 + (d0 + 16) * 32 + kg * 8);
    f32x4 degv = *(const f32x4*)(degf + tb + kg * 4);
    float cw0 = cwf[d0], cw1 = cwf[d0 + 16];
    float ba0 = bias_a[d0], ba1 = bias_a[d0 + 16];
    float bb0 = bias_b[d0], bb1 = bias_b[d0 + 16];

    f32x4 c0 = {ba0, ba0, ba0, ba0};
    f32x4 c1 = {ba1, ba1, ba1, ba1};
    c0 = __builtin_amdgcn_mfma_f32_16x16x32_f16(af, bA0, c0, 0, 0, 0);
    c1 = __builtin_amdgcn_mfma_f32_16x16x32_f16(af, bA1, c1, 0, 0, 0);
    #pragma unroll
    for (int rr = 0; rr < 4; ++rr) {
        float w0 = fmaxf(c0[rr] + degv[rr] * cw0, 0.f);
        float w1 = fmaxf(c1[rr] + degv[rr] * cw1, 0.f);
        int row = kg * 4 + rr;
        X[wave][row * 32 + d0] = (_Float16)w0;
        X[wave][row * 32 + d0 + 16] = (_Float16)w1;
    }
    __builtin_amdgcn_wave_barrier();
    f16x8 af2 = *(f16x8*)&X[wave][d0 * 32 + kg * 8];
    __builtin_amdgcn_wave_barrier();

    f32x4 e0 = {bb0, bb0, bb0, bb0};
    f32x4 e1 = {bb1, bb1, bb1, bb1};
    e0 = __builtin_amdgcn_mfma_f32_16x16x32_f16(af2, bB0, e0, 0, 0, 0);
    e1 = __builtin_amdgcn_mfma_f32_16x16x32_f16(af2, bB1, e1, 0, 0, 0);
    float s0 = 0.f, ss0 = 0.f, s1 = 0.f, ss1 = 0.f;
    #pragma unroll
    for (int rr = 0; rr < 4; ++rr) {
        float y0 = fmaxf(e0[rr], 0.f);
        float y1 = fmaxf(e1[rr], 0.f);
        s0 += y0; ss0 += y0 * y0;
        s1 += y1; ss1 += y1 * y1;
        int row = kg * 4 + rr;
        X[wave][row * 32 + d0] = (_Float16)y0;
        X[wave][row * 32 + d0 + 16] = (_Float16)y1;
    }
    __builtin_amdgcn_wave_barrier();
    {
        int gg = l >> 2, c = l & 3;
        uint4 vv = *(uint4*)&X[wave][gg * 32 + c * 8];
        *(uint4*)(outT + (size_t)(tb + gg) * DIM + c * 8) = vv;
    }
    s0 += __shfl_xor(s0, 16); s0 += __shfl_xor(s0, 32);
    ss0 += __shfl_xor(ss0, 16); ss0 += __shfl_xor(ss0, 32);
    s1 += __shfl_xor(s1, 16); s1 += __shfl_xor(s1, 32);
    ss1 += __shfl_xor(ss1, 16); ss1 += __shfl_xor(ss1, 32);
    if (kg == 0) {
        float* sb = sbins + ((blockIdx.x * 4 + wave) & (SBINS - 1)) * 64;
        atomicAdd(&sb[d0], s0);
        atomicAdd(&sb[DIM + d0], ss0);
        atomicAdd(&sb[d0 + 16], s1);
        atomicAdd(&sb[DIM + d0 + 16], ss1);
    }
}

// ---------------- final BN + global_add_pool (run-length, batch sorted) ----------------
#define POOL_BLOCKS 512
__global__ __launch_bounds__(256) void bn_pool_kernel(const __half* __restrict__ h,
                                                      const float* __restrict__ sbins,
                                                      const float* __restrict__ gamma,
                                                      const float* __restrict__ beta,
                                                      const int* __restrict__ batch,
                                                      float* __restrict__ pooled) {
    __shared__ float st[64];
    int tid = threadIdx.x;
    if (tid < 64) {
        float s = 0.f;
        for (int b = 0; b < SBINS; ++b) s += sbins[b * 64 + tid];
        st[tid] = s;
    }
    __syncthreads();
    int lane = tid & 31;
    int group = tid >> 5;
    float mu = st[lane] * (1.f / N_NODES);
    float var = st[DIM + lane] * (1.f / N_NODES) - mu * mu;
    float inv = rsqrtf(var + BN_EPS);
    float a = gamma[lane] * inv;
    float c = beta[lane] - mu * a;
    const int ngroups = POOL_BLOCKS * 8;
    const int chunk = (N_NODES + ngroups - 1) / ngroups;
    int g = blockIdx.x * 8 + group;
    int start = g * chunk;
    if (start >= N_NODES) return;
    int end = start + chunk; if (end > N_NODES) end = N_NODES;
    int cur = batch[start];
    float s = 0.f;
    for (int node = start; node < end; ++node) {
        float v = __half2float(h[(size_t)node * DIM + lane]) * a + c;
        int bg = batch[node];
        if (bg != cur) {
            atomicAdd(&pooled[cur * DIM + lane], s);
            s = 0.f;
            cur = bg;
        }
        s += v;
    }
    atomicAdd(&pooled[cur * DIM + lane], s);
}

// ---------------- out = relu(pooled @ Wfc + bfc) ----------------
__global__ __launch_bounds__(256) void fc_kernel(const float* __restrict__ pooled,
                                                 const float* __restrict__ Wfc,
                                                 const float* __restrict__ bfc,
                                                 float* __restrict__ out) {
    __shared__ float Wl[DIM * OUT_DIM];
    for (int i = threadIdx.x; i < DIM * OUT_DIM; i += blockDim.x) Wl[i] = Wfc[i];
    __syncthreads();
    int idx = blockIdx.x * blockDim.x + threadIdx.x;
    int stride = gridDim.x * blockDim.x;
    for (; idx < N_GRAPHS * OUT_DIM; idx += stride) {
        int g = idx >> 7;
        int o = idx & 127;
        float acc = bfc[o];
        #pragma unroll
        for (int k = 0; k < DIM; ++k)
            acc += pooled[g * DIM + k] * Wl[k * OUT_DIM + o];
        out[idx] = fmaxf(acc, 0.f);
    }
}

extern "C" void kernel_launch(void* const* d_in, const int* in_sizes, int n_in,
                              void* d_out, int out_size, void* d_ws, size_t ws_size,
                              hipStream_t stream) {
    const float* x   = (const float*)d_in[0];
    const int* eidx  = (const int*)d_in[1];
    const int* src   = eidx;
    const int* dst   = eidx + N_EDGES;
    const int* batch = (const int*)d_in[2];
    const float* W1a = (const float*)d_in[3];
    const float* b1a = (const float*)d_in[4];
    const float* W1b = (const float*)d_in[5];
    const float* b1b = (const float*)d_in[6];
    const float* Wa  = (const float*)d_in[7];
    const float* ba  = (const float*)d_in[8];
    const float* Wb  = (const float*)d_in[9];
    const float* bb  = (const float*)d_in[10];
    const float* gamma = (const float*)d_in[11];
    const float* beta  = (const float*)d_in[12];
    const float* Wfc = (const float*)d_in[13];
    const float* bfc = (const float*)d_in[14];
    float* out = (float*)d_out;

    const size_t TSZ = (size_t)N_NODES * DIM;                // 3.2M halfs = 6.4MB
    __half* TA = (__half*)d_ws;                              // 6.4MB
    __half* TB = TA + TSZ;                                   // 6.4MB
    __half* P0 = TB + TSZ;                                   // 6.4MB
    __half* P1 = P0 + TSZ;                                   // 6.4MB
    float* degf   = (float*)(P1 + TSZ);                      // 400KB
    float* sbins  = degf + N_NODES;                          // 5 * SBINS * 64
    float* pooled = sbins + 5 * SBINS * 64;                  // 256KB
    float* cwf    = pooled + N_GRAPHS * DIM;                 // 5*32
    __half* blobs = (__half*)(cwf + 5 * 32);                 // 5*2048 halfs
    __half* blob1 = blobs + 5 * 2048;                        // 3072 halfs
    int* csr      = (int*)(blob1 + 6 * 512);                 // 12.8MB
    int* rowst    = csr + N_EDGES;                           // N_NODES+1
    int* rowmid   = rowst + N_NODES + 1;                     // N_NODES
    int* bcnt     = rowmid + N_NODES;
    int* bstart   = bcnt + 256;
    int* bcursor  = bstart + NB + 1;
    int* qcnt     = bcursor + 256;                           // NB*NSUB*BSIZE (packed) 1.6MB

    // aliases (dead before hosts' first use)
    int* bsrc            = (int*)TA;              // 12.8MB over TA+TB
    unsigned short* blow = (unsigned short*)P0;   // 6.4MB over P0
    int* qbase0          = (int*)P1;              // 1.6MB in P1
    int* qbase1          = qbase0 + NB * NSUB * BSIZE;  // 1.6MB in P1

    hipMemsetAsync(bcnt, 0, 256 * sizeof(int), stream);
    hipMemsetAsync(sbins, 0, 5 * SBINS * 64 * sizeof(float), stream);
    hipMemsetAsync(pooled, 0, N_GRAPHS * DIM * sizeof(float), stream);

    bucket_hist_kernel<<<1024, 256, 0, stream>>>(dst, bcnt);
    bucket_scan_kernel<<<1, 256, 0, stream>>>(bcnt, bstart, bcursor, rowst);
    bucket_scatter_kernel<<<(N_EDGES + CHUNK - 1) / CHUNK, 256, 0, stream>>>(src, dst, bcursor, bsrc, blow);
    node_count_kernel<<<NB * NSUB, 256, 0, stream>>>(bstart, bsrc, blow, qcnt);
    node_scan_kernel<<<NB, 256, 0, stream>>>(bstart, qcnt, qbase0, qbase1, rowst, rowmid);
    node_scatter_kernel<<<NB * NSUB, 256, 0, stream>>>(bstart, bsrc, blow, qbase0, qbase1, csr);

    deg_kernel<<<(N_NODES + 255) / 256, 256, 0, stream>>>(rowst, degf);
    prep_t1_kernel<<<1, 1024, 0, stream>>>(W1a, blob1);
    transform1_kernel<<<(NTILES + 3) / 4, 256, 0, stream>>>(x, blob1, TA);

    prep_id_kernel<<<1, 1024, 0, stream>>>(W1b, blobs, cwf);

    const __half* in = TA;
    __half* o = TB;

    // layer 1
    agg_pass_kernel<<<AGG_BLOCKS, 256, 0, stream>>>(in, rowst, rowmid, csr, P0, P1);
    mlp_kernel<<<(NTILES + 3) / 4, 256, 0, stream>>>(P0, P1, degf, blobs, cwf, b1a, b1b, o, sbins);
    { const __half* t = in; in = o; o = (__half*)t; }

    for (int i = 0; i < 4; ++i) {
        __half* blob_i = blobs + (i + 1) * 2048;
        float* cwf_i = cwf + (i + 1) * 32;
        prep_kernel<<<1, 1024, 0, stream>>>(sbins + i * SBINS * 64, gamma + i * DIM, beta + i * DIM,
                                            Wa + i * DIM * DIM, Wb + i * DIM * DIM, blob_i, cwf_i);
        agg_pass_kernel<<<AGG_BLOCKS, 256, 0, stream>>>(in, rowst, rowmid, csr, P0, P1);
        mlp_kernel<<<(NTILES + 3) / 4, 256, 0, stream>>>(P0, P1, degf, blob_i, cwf_i,
                                                         ba + i * DIM, bb + i * DIM, o,
                                                         sbins + (i + 1) * SBINS * 64);
        { const __half* t = in; in = o; o = (__half*)t; }
    }

    bn_pool_kernel<<<POOL_BLOCKS, 256, 0, stream>>>(in, sbins + 4 * SBINS * 64,
                                                    gamma + 4 * DIM, beta + 4 * DIM, batch, pooled);
    fc_kernel<<<1024, 256, 0, stream>>>(pooled, Wfc, bfc, out);
}

// Round 13
// 354.627 us; speedup vs baseline: 3.3720x; 1.0417x over previous
//
#include <hip/hip_runtime.h>
#include <hip/hip_fp16.h>

#define N_NODES 100000
#define N_GRAPHS 2048
#define N_EDGES 3200000
#define NHALF 50000
#define DIM 32
#define FEAT 78
#define OUT_DIM 128
#define BN_EPS 1e-5f

#define BSHIFT 9
#define BSIZE 512
#define NB ((N_NODES + BSIZE - 1) / BSIZE)   // 196
#define CHUNK 8192
#define NSUB 4
#define NR 4                                  // node-ranges per bucket (scatter)

#define NTILES (N_NODES / 16)          // 6250
#define SBINS 64
#define AGG_BLOCKS 3128

typedef _Float16 f16x8 __attribute__((ext_vector_type(8)));
typedef float f32x4 __attribute__((ext_vector_type(4)));

// ---------------- K1: coarse bucket histogram (int4-vectorized) ----------------
__global__ __launch_bounds__(256) void bucket_hist_kernel(const int* __restrict__ dst,
                                                          int* __restrict__ bcnt) {
    __shared__ int lh[256];
    int tid = threadIdx.x;
    lh[tid] = 0;
    __syncthreads();
    const int4* d4 = (const int4*)dst;
    const int n4 = N_EDGES / 4;
    int i = blockIdx.x * blockDim.x + tid;
    int stride = gridDim.x * blockDim.x;
    for (; i < n4; i += stride) {
        int4 v = d4[i];
        atomicAdd(&lh[v.x >> BSHIFT], 1);
        atomicAdd(&lh[v.y >> BSHIFT], 1);
        atomicAdd(&lh[v.z >> BSHIFT], 1);
        atomicAdd(&lh[v.w >> BSHIFT], 1);
    }
    __syncthreads();
    if (tid < NB && lh[tid])
        atomicAdd(&bcnt[tid], lh[tid]);
}

// ---------------- K2: scan over buckets ----------------
__global__ __launch_bounds__(256) void bucket_scan_kernel(const int* __restrict__ bcnt,
                                                          int* __restrict__ bstart,
                                                          int* __restrict__ bcursor,
                                                          int* __restrict__ rowst) {
    __shared__ int sc[256];
    int tid = threadIdx.x;
    int v = (tid < NB) ? bcnt[tid] : 0;
    sc[tid] = v;
    __syncthreads();
    for (int off = 1; off < 256; off <<= 1) {
        int nv = (tid >= off) ? sc[tid - off] : 0;
        __syncthreads();
        sc[tid] += nv;
        __syncthreads();
    }
    if (tid < NB) {
        int ex = sc[tid] - v;
        bstart[tid] = ex;
        bcursor[tid] = ex;
    }
    if (tid == 0) {
        bstart[NB] = N_EDGES;
        rowst[N_NODES] = N_EDGES;
    }
}

// ---------------- K3: multisplit scatter -> packed (nloc<<17 | src) per bucket ----------------
__global__ __launch_bounds__(256) void bucket_scatter_kernel(const int* __restrict__ src,
                                                             const int* __restrict__ dst,
                                                             int* __restrict__ bcursor,
                                                             int* __restrict__ epk) {
    __shared__ int lpk[CHUNK];
    __shared__ unsigned char lbkt[CHUNK];
    __shared__ int lhist[256];
    __shared__ int sc[256];
    __shared__ int lpre[256];
    __shared__ int gbase[256];
    __shared__ int lcur[256];
    int tid = threadIdx.x;
    int base = blockIdx.x * CHUNK;
    int n = N_EDGES - base; if (n > CHUNK) n = CHUNK;

    lhist[tid] = 0;
    __syncthreads();
    for (int i = tid; i < n; i += 256)
        atomicAdd(&lhist[dst[base + i] >> BSHIFT], 1);
    __syncthreads();
    int v = lhist[tid];
    sc[tid] = v;
    __syncthreads();
    for (int off = 1; off < 256; off <<= 1) {
        int nv = (tid >= off) ? sc[tid - off] : 0;
        __syncthreads();
        sc[tid] += nv;
        __syncthreads();
    }
    int ex = sc[tid] - v;
    lpre[tid] = ex;
    lcur[tid] = ex;
    if (tid < NB && v)
        gbase[tid] = atomicAdd(&bcursor[tid], v);
    __syncthreads();
    for (int i = tid; i < n; i += 256) {
        int d = dst[base + i];
        int s = src[base + i];
        int b = d >> BSHIFT;
        int pos = atomicAdd(&lcur[b], 1);
        lpk[pos] = ((d & (BSIZE - 1)) << 17) | s;
        lbkt[pos] = (unsigned char)b;
    }
    __syncthreads();
    for (int i = tid; i < n; i += 256) {
        int b = lbkt[i];
        int gpos = gbase[b] + (i - lpre[b]);
        epk[gpos] = lpk[i];
    }
}

// ---------------- K4a: per-(bucket,quarter) histogram, packed (tot<<16)|cnt_lo ----------------
__global__ __launch_bounds__(256) void node_count_kernel(const int* __restrict__ bstart,
                                                         const int* __restrict__ epk,
                                                         int* __restrict__ qcnt) {
    __shared__ int lcnt[BSIZE];
    int tid = threadIdx.x;
    int b = blockIdx.x / NSUB;
    int qt = blockIdx.x % NSUB;
    int ss = bstart[b], se = bstart[b + 1];
    int len = se - ss;
    int qs = ss + (int)(((long long)len * qt) / NSUB);
    int qe = ss + (int)(((long long)len * (qt + 1)) / NSUB);
    lcnt[tid] = 0; lcnt[tid + 256] = 0;
    __syncthreads();
    for (int i = qs + tid; i < qe; i += 256) {
        int pk = epk[i];
        int add = 0x10000 | (((pk & 0x1FFFF) < NHALF) ? 1 : 0);
        atomicAdd(&lcnt[pk >> 17], add);
    }
    __syncthreads();
    int* qc = qcnt + (size_t)blockIdx.x * BSIZE;
    qc[tid] = lcnt[tid];
    qc[tid + 256] = lcnt[tid + 256];
}

// ---------------- K4b: per-bucket scan -> rowst, rowmid, qbase0/1 ----------------
__global__ __launch_bounds__(256) void node_scan_kernel(const int* __restrict__ bstart,
                                                        const int* __restrict__ qcnt,
                                                        int* __restrict__ qbase0,
                                                        int* __restrict__ qbase1,
                                                        int* __restrict__ rowst,
                                                        int* __restrict__ rowmid) {
    __shared__ int sc[256];
    int tid = threadIdx.x;
    int b = blockIdx.x;
    int ss = bstart[b];
    const int* qc = qcnt + (size_t)b * NSUB * BSIZE;
    int j0 = 2 * tid, j1 = 2 * tid + 1;
    int pk0[NSUB], pk1[NSUB];
    int t0 = 0, t1 = 0, m0 = 0, m1 = 0;
    #pragma unroll
    for (int q = 0; q < NSUB; ++q) {
        pk0[q] = qc[q * BSIZE + j0];
        pk1[q] = qc[q * BSIZE + j1];
        t0 += pk0[q] >> 16; m0 += pk0[q] & 0xFFFF;
        t1 += pk1[q] >> 16; m1 += pk1[q] & 0xFFFF;
    }
    int s = t0 + t1;
    sc[tid] = s;
    __syncthreads();
    for (int off = 1; off < 256; off <<= 1) {
        int nv = (tid >= off) ? sc[tid - off] : 0;
        __syncthreads();
        sc[tid] += nv;
        __syncthreads();
    }
    int ex = sc[tid] - s;
    int B0 = ss + ex;
    int B1 = B0 + t0;
    int node_base = b << BSHIFT;
    if (node_base + j0 < N_NODES) { rowst[node_base + j0] = B0; rowmid[node_base + j0] = B0 + m0; }
    if (node_base + j1 < N_NODES) { rowst[node_base + j1] = B1; rowmid[node_base + j1] = B1 + m1; }
    int r0a = B0, r0b = B0 + m0;
    int r1a = B1, r1b = B1 + m1;
    #pragma unroll
    for (int q = 0; q < NSUB; ++q) {
        int c0 = pk0[q] & 0xFFFF, ct = pk0[q] >> 16;
        qbase0[((size_t)b * NSUB + q) * BSIZE + j0] = r0a; r0a += c0;
        qbase1[((size_t)b * NSUB + q) * BSIZE + j0] = r0b; r0b += ct - c0;
        int d0c = pk1[q] & 0xFFFF, dt = pk1[q] >> 16;
        qbase0[((size_t)b * NSUB + q) * BSIZE + j1] = r1a; r1a += d0c;
        qbase1[((size_t)b * NSUB + q) * BSIZE + j1] = r1b; r1b += dt - d0c;
    }
}

// ---------------- K4c: node-range-split scatter (exclusive output lines) -> csr ----------------
// Block (b, r) owns nodes [r*128,(r+1)*128) of bucket b: sweeps the whole bucket's
// packed edges, keeps its nodes, writes into its exclusive contiguous csr range.
__global__ __launch_bounds__(256) void node_scatter_kernel(const int* __restrict__ bstart,
                                                           const int* __restrict__ epk,
                                                           const int* __restrict__ qbase0,
                                                           const int* __restrict__ qbase1,
                                                           int* __restrict__ csr) {
    __shared__ int lcur[2 * NSUB * 128];
    int tid = threadIdx.x;
    int b = blockIdx.x / NR;
    int r = blockIdx.x % NR;
    for (int j = tid; j < NSUB * 128; j += 256) {
        int q = j >> 7, n = j & 127;
        lcur[j] = qbase0[((size_t)b * NSUB + q) * BSIZE + r * 128 + n];
        lcur[NSUB * 128 + j] = qbase1[((size_t)b * NSUB + q) * BSIZE + r * 128 + n];
    }
    __syncthreads();
    int ss = bstart[b], se = bstart[b + 1];
    int len = se - ss;
    #pragma unroll
    for (int q = 0; q < NSUB; ++q) {
        int qs = ss + (int)(((long long)len * q) / NSUB);
        int qe = ss + (int)(((long long)len * (q + 1)) / NSUB);
        for (int i = qs + tid; i < qe; i += 256) {
            int pk = epk[i];
            int nloc = pk >> 17;
            if ((nloc >> 7) == r) {
                int s = pk & 0x1FFFF;
                int h = (s >= NHALF) ? NSUB * 128 : 0;
                int pos = atomicAdd(&lcur[h + (q << 7) + (nloc & 127)], 1);
                csr[pos] = s;
            }
        }
    }
}

// ---------------- deg+1 as float ----------------
__global__ __launch_bounds__(256) void deg_kernel(const int* __restrict__ rowst,
                                                  float* __restrict__ degf) {
    int i = blockIdx.x * blockDim.x + threadIdx.x;
    if (i < N_NODES)
        degf[i] = (float)(rowst[i + 1] - rowst[i] + 1);
}

// ---------------- prep_t1: W1a (78x32, zero-pad K->96) -> 6 B-fragments f16 ----------------
__global__ __launch_bounds__(1024) void prep_t1_kernel(const float* __restrict__ W1a,
                                                       __half* __restrict__ blob1) {
    int tid = threadIdx.x;
    for (int idx = tid; idx < 6 * 512; idx += 1024) {
        int e = idx & 7;
        int l = (idx >> 3) & 63;
        int f = idx >> 9;
        int kc = f >> 1, ct = f & 1;
        int k = kc * 32 + (l >> 4) * 8 + e;
        int col = ct * 16 + (l & 15);
        float v = (k < FEAT) ? W1a[k * DIM + col] : 0.f;
        blob1[idx] = __float2half(v);
    }
}

// ---------------- transform1: MFMA x @ W1a -> table T [node][32] ----------------
__global__ __launch_bounds__(256) void transform1_kernel(const float* __restrict__ x,
                                                         const __half* __restrict__ blob1,
                                                         __half* __restrict__ T) {
    __shared__ __align__(16) _Float16 X[4][512];
    int tid = threadIdx.x;
    int wave = tid >> 6;
    int l = tid & 63;
    int d0 = l & 15, kg = l >> 4;
    int tile = blockIdx.x * 4 + wave;
    if (tile >= NTILES) return;
    int tb = tile * 16;
    const float* xr = x + (size_t)(tb + d0) * FEAT;

    f16x8 af0, af1, af2;
    #pragma unroll
    for (int j = 0; j < 4; ++j) {
        int k0 = kg * 8 + 2 * j;
        float2 v0 = *(const float2*)(xr + k0);
        float2 v1 = *(const float2*)(xr + 32 + k0);
        af0[2 * j] = (_Float16)v0.x; af0[2 * j + 1] = (_Float16)v0.y;
        af1[2 * j] = (_Float16)v1.x; af1[2 * j + 1] = (_Float16)v1.y;
        int k2 = 64 + k0;
        float2 v2 = {0.f, 0.f};
        if (k2 < FEAT) v2 = *(const float2*)(xr + k2);
        af2[2 * j] = (_Float16)v2.x; af2[2 * j + 1] = (_Float16)v2.y;
    }
    f16x8 b0 = *(const f16x8*)(blob1 + (0 * 64 + l) * 8);
    f16x8 b1 = *(const f16x8*)(blob1 + (1 * 64 + l) * 8);
    f16x8 b2 = *(const f16x8*)(blob1 + (2 * 64 + l) * 8);
    f16x8 b3 = *(const f16x8*)(blob1 + (3 * 64 + l) * 8);
    f16x8 b4 = *(const f16x8*)(blob1 + (4 * 64 + l) * 8);
    f16x8 b5 = *(const f16x8*)(blob1 + (5 * 64 + l) * 8);

    f32x4 c0 = {0.f, 0.f, 0.f, 0.f};
    f32x4 c1 = {0.f, 0.f, 0.f, 0.f};
    c0 = __builtin_amdgcn_mfma_f32_16x16x32_f16(af0, b0, c0, 0, 0, 0);
    c1 = __builtin_amdgcn_mfma_f32_16x16x32_f16(af0, b1, c1, 0, 0, 0);
    c0 = __builtin_amdgcn_mfma_f32_16x16x32_f16(af1, b2, c0, 0, 0, 0);
    c1 = __builtin_amdgcn_mfma_f32_16x16x32_f16(af1, b3, c1, 0, 0, 0);
    c0 = __builtin_amdgcn_mfma_f32_16x16x32_f16(af2, b4, c0, 0, 0, 0);
    c1 = __builtin_amdgcn_mfma_f32_16x16x32_f16(af2, b5, c1, 0, 0, 0);

    #pragma unroll
    for (int rr = 0; rr < 4; ++rr) {
        int row = kg * 4 + rr;
        X[wave][row * 32 + d0] = (_Float16)c0[rr];
        X[wave][row * 32 + d0 + 16] = (_Float16)c1[rr];
    }
    __builtin_amdgcn_wave_barrier();
    int gg = l >> 2, cq = l & 3;
    uint4 vv = *(uint4*)&X[wave][gg * 32 + cq * 8];
    *(uint4*)(T + (size_t)(tb + gg) * DIM + cq * 8) = vv;
}

// ---------------- prep: reduce stat bins + BN-fold, weights in fragment layout ----------------
__global__ __launch_bounds__(1024) void prep_kernel(const float* __restrict__ sbins,
                                                    const float* __restrict__ gamma,
                                                    const float* __restrict__ beta,
                                                    const float* __restrict__ Wa,
                                                    const float* __restrict__ Wb,
                                                    __half* __restrict__ blob,
                                                    float* __restrict__ cwf) {
    __shared__ float st[64];
    __shared__ float a[DIM], c[DIM];
    int tid = threadIdx.x;
    if (tid < 64) {
        float s = 0.f;
        for (int b = 0; b < SBINS; ++b) s += sbins[b * 64 + tid];
        st[tid] = s;
    }
    __syncthreads();
    if (tid < DIM) {
        float mu = st[tid] * (1.f / N_NODES);
        float var = st[DIM + tid] * (1.f / N_NODES) - mu * mu;
        float av = gamma[tid] * rsqrtf(var + BN_EPS);
        a[tid] = av;
        c[tid] = beta[tid] - mu * av;
    }
    __syncthreads();
    int d = tid >> 5, k = tid & 31;
    blob[d * 32 + k] = __float2half(a[k] * Wa[k * 32 + d]);
    blob[1024 + d * 32 + k] = __float2half(Wb[k * 32 + d]);
    if (tid < DIM) {
        float s = 0.f;
        for (int kk = 0; kk < DIM; ++kk)
            s += c[kk] * Wa[kk * 32 + tid];
        cwf[tid] = s;
    }
}

__global__ __launch_bounds__(1024) void prep_id_kernel(const float* __restrict__ W1b,
                                                       __half* __restrict__ blob,
                                                       float* __restrict__ cwf) {
    int tid = threadIdx.x;
    int d = tid >> 5, k = tid & 31;
    blob[d * 32 + k] = __float2half((d == k) ? 1.f : 0.f);
    blob[1024 + d * 32 + k] = __float2half(W1b[k * 32 + d]);
    if (tid < DIM) cwf[tid] = 0.f;
}

#define ACC8(v) do { const __half2* hp_ = (const __half2*)&(v); float2 f_; \
  f_ = __half22float2(hp_[0]); a0 += f_.x; a1 += f_.y; \
  f_ = __half22float2(hp_[1]); a2 += f_.x; a3 += f_.y; \
  f_ = __half22float2(hp_[2]); a4 += f_.x; a5 += f_.y; \
  f_ = __half22float2(hp_[3]); a6 += f_.x; a7 += f_.y; } while (0)

// ---------------- agg_pass: src-range-partitioned gather, XCD-split, full 64B rows ----------
__global__ __launch_bounds__(256) void agg_pass_kernel(const __half* __restrict__ T,
                                                       const int* __restrict__ rowst,
                                                       const int* __restrict__ rowmid,
                                                       const int* __restrict__ csr,
                                                       __half* __restrict__ P0,
                                                       __half* __restrict__ P1) {
    int b = blockIdx.x;
    int half = (b >> 2) & 1;
    int idx_in_half = (b >> 3) * 4 + (b & 3);
    int tid = threadIdx.x;
    int wave = tid >> 6;
    int l = tid & 63;
    int g = l >> 2, q = l & 3;
    int tile = idx_in_half * 4 + wave;
    if (tile >= NTILES) return;
    int node = tile * 16 + g;
    int ps, pe;
    if (half == 0) { ps = rowst[node]; pe = rowmid[node]; }
    else           { ps = rowmid[node]; pe = rowst[node + 1]; }
    float a0 = 0.f, a1 = 0.f, a2 = 0.f, a3 = 0.f,
          a4 = 0.f, a5 = 0.f, a6 = 0.f, a7 = 0.f;
    int p = ps;
    int idx[8];
    bool have = (p + 8 <= pe);
    if (have) {
        #pragma unroll
        for (int j = 0; j < 8; ++j) idx[j] = csr[p + j];
    }
    while (have) {
        uint4 v[8];
        #pragma unroll
        for (int j = 0; j < 8; ++j)
            v[j] = *(const uint4*)(T + (size_t)idx[j] * DIM + (q << 3));
        int np = p + 8;
        bool nhave = (np + 8 <= pe);
        int nidx[8];
        if (nhave) {
            #pragma unroll
            for (int j = 0; j < 8; ++j) nidx[j] = csr[np + j];
        }
        #pragma unroll
        for (int j = 0; j < 8; ++j) ACC8(v[j]);
        #pragma unroll
        for (int j = 0; j < 8; ++j) idx[j] = nidx[j];
        p = np;
        have = nhave;
    }
    if (p < pe) {
        #pragma unroll
        for (int j = 0; j < 8; ++j) {
            int ei = p + j;
            uint4 vv = {0, 0, 0, 0};
            if (ei < pe) vv = *(const uint4*)(T + (size_t)csr[ei] * DIM + (q << 3));
            ACC8(vv);
        }
    }
    int selfhalf = (node < NHALF) ? 0 : 1;
    if (selfhalf == half) {
        uint4 vs = *(const uint4*)(T + (size_t)node * DIM + (q << 3));
        ACC8(vs);
    }
    __half* P = half ? P1 : P0;
    f16x8 hv;
    hv[0] = (_Float16)a0; hv[1] = (_Float16)a1;
    hv[2] = (_Float16)a2; hv[3] = (_Float16)a3;
    hv[4] = (_Float16)a4; hv[5] = (_Float16)a5;
    hv[6] = (_Float16)a6; hv[7] = (_Float16)a7;
    *(f16x8*)(P + (size_t)node * DIM + (q << 3)) = hv;
}

// ---------------- mlp: P0+P1 -> MFMA MLP -> next table; binned BN stats ----------------
__global__ __launch_bounds__(256) void mlp_kernel(const __half* __restrict__ P0,
                                                  const __half* __restrict__ P1,
                                                  const float* __restrict__ degf,
                                                  const __half* __restrict__ blob,
                                                  const float* __restrict__ cwf,
                                                  const float* __restrict__ bias_a,
                                                  const float* __restrict__ bias_b,
                                                  __half* __restrict__ outT,
                                                  float* __restrict__ sbins) {
    __shared__ __align__(16) _Float16 X[4][512];
    int tid = threadIdx.x;
    int wave = tid >> 6;
    int l = tid & 63;
    int d0 = l & 15, kg = l >> 4;
    int tile = blockIdx.x * 4 + wave;
    if (tile >= NTILES) return;
    int tb = tile * 16;

    f16x8 v0 = *(const f16x8*)(P0 + (size_t)(tb + d0) * DIM + kg * 8);
    f16x8 v1 = *(const f16x8*)(P1 + (size_t)(tb + d0) * DIM + kg * 8);
    f16x8 af = v0 + v1;
    f16x8 bA0 = *(const f16x8*)(blob + d0 * 32 + kg * 8);
    f16x8 bA1 = *(const f16x8*)(blob + (d0 + 16) * 32 + kg * 8);
    f16x8 bB0 = *(const f16x8*)(blob + 1024 + d0 * 32 + kg * 8);
    f16x8 bB1 = *(const f16x8*)(blob + 1024 + (d0 + 16) * 32 + kg * 8);
    f32x4 degv = *(const f32x4*)(degf + tb + kg * 4);
    float cw0 = cwf[d0], cw1 = cwf[d0 + 16];
    float ba0 = bias_a[d0], ba1 = bias_a[d0 + 16];
    float bb0 = bias_b[d0], bb1 = bias_b[d0 + 16];

    f32x4 c0 = {ba0, ba0, ba0, ba0};
    f32x4 c1 = {ba1, ba1, ba1, ba1};
    c0 = __builtin_amdgcn_mfma_f32_16x16x32_f16(af, bA0, c0, 0, 0, 0);
    c1 = __builtin_amdgcn_mfma_f32_16x16x32_f16(af, bA1, c1, 0, 0, 0);
    #pragma unroll
    for (int rr = 0; rr < 4; ++rr) {
        float w0 = fmaxf(c0[rr] + degv[rr] * cw0, 0.f);
        float w1 = fmaxf(c1[rr] + degv[rr] * cw1, 0.f);
        int row = kg * 4 + rr;
        X[wave][row * 32 + d0] = (_Float16)w0;
        X[wave][row * 32 + d0 + 16] = (_Float16)w1;
    }
    __builtin_amdgcn_wave_barrier();
    f16x8 af2 = *(f16x8*)&X[wave][d0 * 32 + kg * 8];
    __builtin_amdgcn_wave_barrier();

    f32x4 e0 = {bb0, bb0, bb0, bb0};
    f32x4 e1 = {bb1, bb1, bb1, bb1};
    e0 = __builtin_amdgcn_mfma_f32_16x16x32_f16(af2, bB0, e0, 0, 0, 0);
    e1 = __builtin_amdgcn_mfma_f32_16x16x32_f16(af2, bB1, e1, 0, 0, 0);
    float s0 = 0.f, ss0 = 0.f, s1 = 0.f, ss1 = 0.f;
    #pragma unroll
    for (int rr = 0; rr < 4; ++rr) {
        float y0 = fmaxf(e0[rr], 0.f);
        float y1 = fmaxf(e1[rr], 0.f);
        s0 += y0; ss0 += y0 * y0;
        s1 += y1; ss1 += y1 * y1;
        int row = kg * 4 + rr;
        X[wave][row * 32 + d0] = (_Float16)y0;
        X[wave][row * 32 + d0 + 16] = (_Float16)y1;
    }
    __builtin_amdgcn_wave_barrier();
    {
        int gg = l >> 2, c = l & 3;
        uint4 vv = *(uint4*)&X[wave][gg * 32 + c * 8];
        *(uint4*)(outT + (size_t)(tb + gg) * DIM + c * 8) = vv;
    }
    s0 += __shfl_xor(s0, 16); s0 += __shfl_xor(s0, 32);
    ss0 += __shfl_xor(ss0, 16); ss0 += __shfl_xor(ss0, 32);
    s1 += __shfl_xor(s1, 16); s1 += __shfl_xor(s1, 32);
    ss1 += __shfl_xor(ss1, 16); ss1 += __shfl_xor(ss1, 32);
    if (kg == 0) {
        float* sb = sbins + ((blockIdx.x * 4 + wave) & (SBINS - 1)) * 64;
        atomicAdd(&sb[d0], s0);
        atomicAdd(&sb[DIM + d0], ss0);
        atomicAdd(&sb[d0 + 16], s1);
        atomicAdd(&sb[DIM + d0 + 16], ss1);
    }
}

// ---------------- final BN + global_add_pool (run-length, batch sorted) ----------------
#define POOL_BLOCKS 512
__global__ __launch_bounds__(256) void bn_pool_kernel(const __half* __restrict__ h,
                                                      const float* __restrict__ sbins,
                                                      const float* __restrict__ gamma,
                                                      const float* __restrict__ beta,
                                                      const int* __restrict__ batch,
                                                      float* __restrict__ pooled) {
    __shared__ float st[64];
    int tid = threadIdx.x;
    if (tid < 64) {
        float s = 0.f;
        for (int b = 0; b < SBINS; ++b) s += sbins[b * 64 + tid];
        st[tid] = s;
    }
    __syncthreads();
    int lane = tid & 31;
    int group = tid >> 5;
    float mu = st[lane] * (1.f / N_NODES);
    float var = st[DIM + lane] * (1.f / N_NODES) - mu * mu;
    float inv = rsqrtf(var + BN_EPS);
    float a = gamma[lane] * inv;
    float c = beta[lane] - mu * a;
    const int ngroups = POOL_BLOCKS * 8;
    const int chunk = (N_NODES + ngroups - 1) / ngroups;
    int g = blockIdx.x * 8 + group;
    int start = g * chunk;
    if (start >= N_NODES) return;
    int end = start + chunk; if (end > N_NODES) end = N_NODES;
    int cur = batch[start];
    float s = 0.f;
    for (int node = start; node < end; ++node) {
        float v = __half2float(h[(size_t)node * DIM + lane]) * a + c;
        int bg = batch[node];
        if (bg != cur) {
            atomicAdd(&pooled[cur * DIM + lane], s);
            s = 0.f;
            cur = bg;
        }
        s += v;
    }
    atomicAdd(&pooled[cur * DIM + lane], s);
}

// ---------------- out = relu(pooled @ Wfc + bfc) ----------------
__global__ __launch_bounds__(256) void fc_kernel(const float* __restrict__ pooled,
                                                 const float* __restrict__ Wfc,
                                                 const float* __restrict__ bfc,
                                                 float* __restrict__ out) {
    __shared__ float Wl[DIM * OUT_DIM];
    for (int i = threadIdx.x; i < DIM * OUT_DIM; i += blockDim.x) Wl[i] = Wfc[i];
    __syncthreads();
    int idx = blockIdx.x * blockDim.x + threadIdx.x;
    int stride = gridDim.x * blockDim.x;
    for (; idx < N_GRAPHS * OUT_DIM; idx += stride) {
        int g = idx >> 7;
        int o = idx & 127;
        float acc = bfc[o];
        #pragma unroll
        for (int k = 0; k < DIM; ++k)
            acc += pooled[g * DIM + k] * Wl[k * OUT_DIM + o];
        out[idx] = fmaxf(acc, 0.f);
    }
}

extern "C" void kernel_launch(void* const* d_in, const int* in_sizes, int n_in,
                              void* d_out, int out_size, void* d_ws, size_t ws_size,
                              hipStream_t stream) {
    const float* x   = (const float*)d_in[0];
    const int* eidx  = (const int*)d_in[1];
    const int* src   = eidx;
    const int* dst   = eidx + N_EDGES;
    const int* batch = (const int*)d_in[2];
    const float* W1a = (const float*)d_in[3];
    const float* b1a = (const float*)d_in[4];
    const float* W1b = (const float*)d_in[5];
    const float* b1b = (const float*)d_in[6];
    const float* Wa  = (const float*)d_in[7];
    const float* ba  = (const float*)d_in[8];
    const float* Wb  = (const float*)d_in[9];
    const float* bb  = (const float*)d_in[10];
    const float* gamma = (const float*)d_in[11];
    const float* beta  = (const float*)d_in[12];
    const float* Wfc = (const float*)d_in[13];
    const float* bfc = (const float*)d_in[14];
    float* out = (float*)d_out;

    const size_t TSZ = (size_t)N_NODES * DIM;                // 3.2M halfs = 6.4MB
    __half* TA = (__half*)d_ws;                              // 6.4MB
    __half* TB = TA + TSZ;                                   // 6.4MB
    __half* P0 = TB + TSZ;                                   // 6.4MB
    __half* P1 = P0 + TSZ;                                   // 6.4MB
    float* degf   = (float*)(P1 + TSZ);                      // 400KB
    float* sbins  = degf + N_NODES;                          // 5 * SBINS * 64
    float* pooled = sbins + 5 * SBINS * 64;                  // 256KB
    float* cwf    = pooled + N_GRAPHS * DIM;                 // 5*32
    __half* blobs = (__half*)(cwf + 5 * 32);                 // 5*2048 halfs
    __half* blob1 = blobs + 5 * 2048;                        // 3072 halfs
    int* csr      = (int*)(blob1 + 6 * 512);                 // 12.8MB
    int* rowst    = csr + N_EDGES;                           // N_NODES+1
    int* rowmid   = rowst + N_NODES + 1;                     // N_NODES
    int* bcnt     = rowmid + N_NODES;
    int* bstart   = bcnt + 256;
    int* bcursor  = bstart + NB + 1;
    int* qcnt     = bcursor + 256;                           // NB*NSUB*BSIZE (packed)

    // aliases (dead before hosts' first use)
    int* epk             = (int*)TA;              // 12.8MB packed edges over TA+TB
    int* qbase0          = (int*)P1;              // 1.6MB in P1
    int* qbase1          = qbase0 + NB * NSUB * BSIZE;  // 1.6MB in P1

    hipMemsetAsync(bcnt, 0, 256 * sizeof(int), stream);
    hipMemsetAsync(sbins, 0, 5 * SBINS * 64 * sizeof(float), stream);
    hipMemsetAsync(pooled, 0, N_GRAPHS * DIM * sizeof(float), stream);

    bucket_hist_kernel<<<1024, 256, 0, stream>>>(dst, bcnt);
    bucket_scan_kernel<<<1, 256, 0, stream>>>(bcnt, bstart, bcursor, rowst);
    bucket_scatter_kernel<<<(N_EDGES + CHUNK - 1) / CHUNK, 256, 0, stream>>>(src, dst, bcursor, epk);
    node_count_kernel<<<NB * NSUB, 256, 0, stream>>>(bstart, epk, qcnt);
    node_scan_kernel<<<NB, 256, 0, stream>>>(bstart, qcnt, qbase0, qbase1, rowst, rowmid);
    node_scatter_kernel<<<NB * NR, 256, 0, stream>>>(bstart, epk, qbase0, qbase1, csr);

    deg_kernel<<<(N_NODES + 255) / 256, 256, 0, stream>>>(rowst, degf);
    prep_t1_kernel<<<1, 1024, 0, stream>>>(W1a, blob1);
    transform1_kernel<<<(NTILES + 3) / 4, 256, 0, stream>>>(x, blob1, TA);

    prep_id_kernel<<<1, 1024, 0, stream>>>(W1b, blobs, cwf);

    const __half* in = TA;
    __half* o = TB;

    // layer 1
    agg_pass_kernel<<<AGG_BLOCKS, 256, 0, stream>>>(in, rowst, rowmid, csr, P0, P1);
    mlp_kernel<<<(NTILES + 3) / 4, 256, 0, stream>>>(P0, P1, degf, blobs, cwf, b1a, b1b, o, sbins);
    { const __half* t = in; in = o; o = (__half*)t; }

    for (int i = 0; i < 4; ++i) {
        __half* blob_i = blobs + (i + 1) * 2048;
        float* cwf_i = cwf + (i + 1) * 32;
        prep_kernel<<<1, 1024, 0, stream>>>(sbins + i * SBINS * 64, gamma + i * DIM, beta + i * DIM,
                                            Wa + i * DIM * DIM, Wb + i * DIM * DIM, blob_i, cwf_i);
        agg_pass_kernel<<<AGG_BLOCKS, 256, 0, stream>>>(in, rowst, rowmid, csr, P0, P1);
        mlp_kernel<<<(NTILES + 3) / 4, 256, 0, stream>>>(P0, P1, degf, blob_i, cwf_i,
                                                         ba + i * DIM, bb + i * DIM, o,
                                                         sbins + (i + 1) * SBINS * 64);
        { const __half* t = in; in = o; o = (__half*)t; }
    }

    bn_pool_kernel<<<POOL_BLOCKS, 256, 0, stream>>>(in, sbins + 4 * SBINS * 64,
                                                    gamma + 4 * DIM, beta + 4 * DIM, batch, pooled);
    fc_kernel<<<1024, 256, 0, stream>>>(pooled, Wfc, bfc, out);
}

// Round 14
// 352.956 us; speedup vs baseline: 3.3880x; 1.0047x over previous
//
#include <hip/hip_runtime.h>
#include <hip/hip_fp16.h>

#define N_NODES 100000
#define N_GRAPHS 2048
#define N_EDGES 3200000
#define NHALF 50000
#define DIM 32
#define FEAT 78
#define OUT_DIM 128
#define BN_EPS 1e-5f

#define BSHIFT 9
#define BSIZE 512
#define NB ((N_NODES + BSIZE - 1) / BSIZE)   // 196
#define CHUNK 4096
#define NSUB 4
#define NR 4                                  // node-ranges per bucket (scatter)

#define NTILES (N_NODES / 16)          // 6250
#define SBINS 64
#define AGG_BLOCKS 3128

typedef _Float16 f16x8 __attribute__((ext_vector_type(8)));
typedef float f32x4 __attribute__((ext_vector_type(4)));

// ---------------- K1: coarse bucket histogram (int4-vectorized) ----------------
__global__ __launch_bounds__(256) void bucket_hist_kernel(const int* __restrict__ dst,
                                                          int* __restrict__ bcnt) {
    __shared__ int lh[256];
    int tid = threadIdx.x;
    lh[tid] = 0;
    __syncthreads();
    const int4* d4 = (const int4*)dst;
    const int n4 = N_EDGES / 4;
    int i = blockIdx.x * blockDim.x + tid;
    int stride = gridDim.x * blockDim.x;
    for (; i < n4; i += stride) {
        int4 v = d4[i];
        atomicAdd(&lh[v.x >> BSHIFT], 1);
        atomicAdd(&lh[v.y >> BSHIFT], 1);
        atomicAdd(&lh[v.z >> BSHIFT], 1);
        atomicAdd(&lh[v.w >> BSHIFT], 1);
    }
    __syncthreads();
    if (tid < NB && lh[tid])
        atomicAdd(&bcnt[tid], lh[tid]);
}

// ---------------- K2: scan over buckets ----------------
__global__ __launch_bounds__(256) void bucket_scan_kernel(const int* __restrict__ bcnt,
                                                          int* __restrict__ bstart,
                                                          int* __restrict__ bcursor,
                                                          int* __restrict__ rowst) {
    __shared__ int sc[256];
    int tid = threadIdx.x;
    int v = (tid < NB) ? bcnt[tid] : 0;
    sc[tid] = v;
    __syncthreads();
    for (int off = 1; off < 256; off <<= 1) {
        int nv = (tid >= off) ? sc[tid - off] : 0;
        __syncthreads();
        sc[tid] += nv;
        __syncthreads();
    }
    if (tid < NB) {
        int ex = sc[tid] - v;
        bstart[tid] = ex;
        bcursor[tid] = ex;
    }
    if (tid == 0) {
        bstart[NB] = N_EDGES;
        rowst[N_NODES] = N_EDGES;
    }
}

// ---------------- K3: multisplit scatter -> packed (nloc<<17 | src) per bucket ----------------
__global__ __launch_bounds__(256) void bucket_scatter_kernel(const int* __restrict__ src,
                                                             const int* __restrict__ dst,
                                                             int* __restrict__ bcursor,
                                                             int* __restrict__ epk) {
    __shared__ int lpk[CHUNK];
    __shared__ unsigned char lbkt[CHUNK];
    __shared__ int lhist[256];
    __shared__ int sc[256];
    __shared__ int lpre[256];
    __shared__ int gbase[256];
    __shared__ int lcur[256];
    int tid = threadIdx.x;
    int base = blockIdx.x * CHUNK;
    int n = N_EDGES - base; if (n > CHUNK) n = CHUNK;

    lhist[tid] = 0;
    __syncthreads();
    for (int i = tid; i < n; i += 256)
        atomicAdd(&lhist[dst[base + i] >> BSHIFT], 1);
    __syncthreads();
    int v = lhist[tid];
    sc[tid] = v;
    __syncthreads();
    for (int off = 1; off < 256; off <<= 1) {
        int nv = (tid >= off) ? sc[tid - off] : 0;
        __syncthreads();
        sc[tid] += nv;
        __syncthreads();
    }
    int ex = sc[tid] - v;
    lpre[tid] = ex;
    lcur[tid] = ex;
    if (tid < NB && v)
        gbase[tid] = atomicAdd(&bcursor[tid], v);
    __syncthreads();
    for (int i = tid; i < n; i += 256) {
        int d = dst[base + i];
        int s = src[base + i];
        int b = d >> BSHIFT;
        int pos = atomicAdd(&lcur[b], 1);
        lpk[pos] = ((d & (BSIZE - 1)) << 17) | s;
        lbkt[pos] = (unsigned char)b;
    }
    __syncthreads();
    for (int i = tid; i < n; i += 256) {
        int b = lbkt[i];
        int gpos = gbase[b] + (i - lpre[b]);
        epk[gpos] = lpk[i];
    }
}

// ---------------- K4a: per-(bucket,quarter) histogram, packed (tot<<16)|cnt_lo ----------------
__global__ __launch_bounds__(256) void node_count_kernel(const int* __restrict__ bstart,
                                                         const int* __restrict__ epk,
                                                         int* __restrict__ qcnt) {
    __shared__ int lcnt[BSIZE];
    int tid = threadIdx.x;
    int b = blockIdx.x / NSUB;
    int qt = blockIdx.x % NSUB;
    int ss = bstart[b], se = bstart[b + 1];
    int len = se - ss;
    int qs = ss + (int)(((long long)len * qt) / NSUB);
    int qe = ss + (int)(((long long)len * (qt + 1)) / NSUB);
    lcnt[tid] = 0; lcnt[tid + 256] = 0;
    __syncthreads();
    for (int i = qs + tid; i < qe; i += 256) {
        int pk = epk[i];
        int add = 0x10000 | (((pk & 0x1FFFF) < NHALF) ? 1 : 0);
        atomicAdd(&lcnt[pk >> 17], add);
    }
    __syncthreads();
    int* qc = qcnt + (size_t)blockIdx.x * BSIZE;
    qc[tid] = lcnt[tid];
    qc[tid + 256] = lcnt[tid + 256];
}

// ---------------- K4b: per-bucket scan -> rowst, rowmid, degf, qbase0/1 ----------------
__global__ __launch_bounds__(256) void node_scan_kernel(const int* __restrict__ bstart,
                                                        const int* __restrict__ qcnt,
                                                        int* __restrict__ qbase0,
                                                        int* __restrict__ qbase1,
                                                        int* __restrict__ rowst,
                                                        int* __restrict__ rowmid,
                                                        float* __restrict__ degf) {
    __shared__ int sc[256];
    int tid = threadIdx.x;
    int b = blockIdx.x;
    int ss = bstart[b];
    const int* qc = qcnt + (size_t)b * NSUB * BSIZE;
    int j0 = 2 * tid, j1 = 2 * tid + 1;
    int pk0[NSUB], pk1[NSUB];
    int t0 = 0, t1 = 0, m0 = 0, m1 = 0;
    #pragma unroll
    for (int q = 0; q < NSUB; ++q) {
        pk0[q] = qc[q * BSIZE + j0];
        pk1[q] = qc[q * BSIZE + j1];
        t0 += pk0[q] >> 16; m0 += pk0[q] & 0xFFFF;
        t1 += pk1[q] >> 16; m1 += pk1[q] & 0xFFFF;
    }
    int s = t0 + t1;
    sc[tid] = s;
    __syncthreads();
    for (int off = 1; off < 256; off <<= 1) {
        int nv = (tid >= off) ? sc[tid - off] : 0;
        __syncthreads();
        sc[tid] += nv;
        __syncthreads();
    }
    int ex = sc[tid] - s;
    int B0 = ss + ex;
    int B1 = B0 + t0;
    int node_base = b << BSHIFT;
    if (node_base + j0 < N_NODES) {
        rowst[node_base + j0] = B0; rowmid[node_base + j0] = B0 + m0;
        degf[node_base + j0] = (float)(t0 + 1);
    }
    if (node_base + j1 < N_NODES) {
        rowst[node_base + j1] = B1; rowmid[node_base + j1] = B1 + m1;
        degf[node_base + j1] = (float)(t1 + 1);
    }
    int r0a = B0, r0b = B0 + m0;
    int r1a = B1, r1b = B1 + m1;
    #pragma unroll
    for (int q = 0; q < NSUB; ++q) {
        int c0 = pk0[q] & 0xFFFF, ct = pk0[q] >> 16;
        qbase0[((size_t)b * NSUB + q) * BSIZE + j0] = r0a; r0a += c0;
        qbase1[((size_t)b * NSUB + q) * BSIZE + j0] = r0b; r0b += ct - c0;
        int d0c = pk1[q] & 0xFFFF, dt = pk1[q] >> 16;
        qbase0[((size_t)b * NSUB + q) * BSIZE + j1] = r1a; r1a += d0c;
        qbase1[((size_t)b * NSUB + q) * BSIZE + j1] = r1b; r1b += dt - d0c;
    }
}

// ---------------- K4c: node-range-split scatter (exclusive output lines) -> csr ----------------
__global__ __launch_bounds__(256) void node_scatter_kernel(const int* __restrict__ bstart,
                                                           const int* __restrict__ epk,
                                                           const int* __restrict__ qbase0,
                                                           const int* __restrict__ qbase1,
                                                           int* __restrict__ csr) {
    __shared__ int lcur[2 * NSUB * 128];
    int tid = threadIdx.x;
    int b = blockIdx.x / NR;
    int r = blockIdx.x % NR;
    for (int j = tid; j < NSUB * 128; j += 256) {
        int q = j >> 7, n = j & 127;
        lcur[j] = qbase0[((size_t)b * NSUB + q) * BSIZE + r * 128 + n];
        lcur[NSUB * 128 + j] = qbase1[((size_t)b * NSUB + q) * BSIZE + r * 128 + n];
    }
    __syncthreads();
    int ss = bstart[b], se = bstart[b + 1];
    int len = se - ss;
    #pragma unroll
    for (int q = 0; q < NSUB; ++q) {
        int qs = ss + (int)(((long long)len * q) / NSUB);
        int qe = ss + (int)(((long long)len * (q + 1)) / NSUB);
        for (int i = qs + tid; i < qe; i += 256) {
            int pk = epk[i];
            int nloc = pk >> 17;
            if ((nloc >> 7) == r) {
                int s = pk & 0x1FFFF;
                int h = (s >= NHALF) ? NSUB * 128 : 0;
                int pos = atomicAdd(&lcur[h + (q << 7) + (nloc & 127)], 1);
                csr[pos] = s;
            }
        }
    }
}

// ---------------- prep0: W1a fragments (K pad 96) + identity blob + cwf=0 ----------------
__global__ __launch_bounds__(1024) void prep0_kernel(const float* __restrict__ W1a,
                                                     const float* __restrict__ W1b,
                                                     __half* __restrict__ blob1,
                                                     __half* __restrict__ blob,
                                                     float* __restrict__ cwf) {
    int tid = threadIdx.x;
    for (int idx = tid; idx < 6 * 512; idx += 1024) {
        int e = idx & 7;
        int l = (idx >> 3) & 63;
        int f = idx >> 9;
        int kc = f >> 1, ct = f & 1;
        int k = kc * 32 + (l >> 4) * 8 + e;
        int col = ct * 16 + (l & 15);
        float v = (k < FEAT) ? W1a[k * DIM + col] : 0.f;
        blob1[idx] = __float2half(v);
    }
    int d = tid >> 5, k = tid & 31;
    blob[d * 32 + k] = __float2half((d == k) ? 1.f : 0.f);
    blob[1024 + d * 32 + k] = __float2half(W1b[k * 32 + d]);
    if (tid < DIM) cwf[tid] = 0.f;
}

// ---------------- transform1: MFMA x @ W1a -> table T [node][32] ----------------
__global__ __launch_bounds__(256) void transform1_kernel(const float* __restrict__ x,
                                                         const __half* __restrict__ blob1,
                                                         __half* __restrict__ T) {
    __shared__ __align__(16) _Float16 X[4][512];
    int tid = threadIdx.x;
    int wave = tid >> 6;
    int l = tid & 63;
    int d0 = l & 15, kg = l >> 4;
    int tile = blockIdx.x * 4 + wave;
    if (tile >= NTILES) return;
    int tb = tile * 16;
    const float* xr = x + (size_t)(tb + d0) * FEAT;

    f16x8 af0, af1, af2;
    #pragma unroll
    for (int j = 0; j < 4; ++j) {
        int k0 = kg * 8 + 2 * j;
        float2 v0 = *(const float2*)(xr + k0);
        float2 v1 = *(const float2*)(xr + 32 + k0);
        af0[2 * j] = (_Float16)v0.x; af0[2 * j + 1] = (_Float16)v0.y;
        af1[2 * j] = (_Float16)v1.x; af1[2 * j + 1] = (_Float16)v1.y;
        int k2 = 64 + k0;
        float2 v2 = {0.f, 0.f};
        if (k2 < FEAT) v2 = *(const float2*)(xr + k2);
        af2[2 * j] = (_Float16)v2.x; af2[2 * j + 1] = (_Float16)v2.y;
    }
    f16x8 b0 = *(const f16x8*)(blob1 + (0 * 64 + l) * 8);
    f16x8 b1 = *(const f16x8*)(blob1 + (1 * 64 + l) * 8);
    f16x8 b2 = *(const f16x8*)(blob1 + (2 * 64 + l) * 8);
    f16x8 b3 = *(const f16x8*)(blob1 + (3 * 64 + l) * 8);
    f16x8 b4 = *(const f16x8*)(blob1 + (4 * 64 + l) * 8);
    f16x8 b5 = *(const f16x8*)(blob1 + (5 * 64 + l) * 8);

    f32x4 c0 = {0.f, 0.f, 0.f, 0.f};
    f32x4 c1 = {0.f, 0.f, 0.f, 0.f};
    c0 = __builtin_amdgcn_mfma_f32_16x16x32_f16(af0, b0, c0, 0, 0, 0);
    c1 = __builtin_amdgcn_mfma_f32_16x16x32_f16(af0, b1, c1, 0, 0, 0);
    c0 = __builtin_amdgcn_mfma_f32_16x16x32_f16(af1, b2, c0, 0, 0, 0);
    c1 = __builtin_amdgcn_mfma_f32_16x16x32_f16(af1, b3, c1, 0, 0, 0);
    c0 = __builtin_amdgcn_mfma_f32_16x16x32_f16(af2, b4, c0, 0, 0, 0);
    c1 = __builtin_amdgcn_mfma_f32_16x16x32_f16(af2, b5, c1, 0, 0, 0);

    #pragma unroll
    for (int rr = 0; rr < 4; ++rr) {
        int row = kg * 4 + rr;
        X[wave][row * 32 + d0] = (_Float16)c0[rr];
        X[wave][row * 32 + d0 + 16] = (_Float16)c1[rr];
    }
    __builtin_amdgcn_wave_barrier();
    int gg = l >> 2, cq = l & 3;
    uint4 vv = *(uint4*)&X[wave][gg * 32 + cq * 8];
    *(uint4*)(T + (size_t)(tb + gg) * DIM + cq * 8) = vv;
}

// ---------------- prep: reduce stat bins + BN-fold, weights in fragment layout ----------------
__global__ __launch_bounds__(1024) void prep_kernel(const float* __restrict__ sbins,
                                                    const float* __restrict__ gamma,
                                                    const float* __restrict__ beta,
                                                    const float* __restrict__ Wa,
                                                    const float* __restrict__ Wb,
                                                    __half* __restrict__ blob,
                                                    float* __restrict__ cwf) {
    __shared__ float st[64];
    __shared__ float a[DIM], c[DIM];
    int tid = threadIdx.x;
    if (tid < 64) {
        float s = 0.f;
        for (int b = 0; b < SBINS; ++b) s += sbins[b * 64 + tid];
        st[tid] = s;
    }
    __syncthreads();
    if (tid < DIM) {
        float mu = st[tid] * (1.f / N_NODES);
        float var = st[DIM + tid] * (1.f / N_NODES) - mu * mu;
        float av = gamma[tid] * rsqrtf(var + BN_EPS);
        a[tid] = av;
        c[tid] = beta[tid] - mu * av;
    }
    __syncthreads();
    int d = tid >> 5, k = tid & 31;
    blob[d * 32 + k] = __float2half(a[k] * Wa[k * 32 + d]);
    blob[1024 + d * 32 + k] = __float2half(Wb[k * 32 + d]);
    if (tid < DIM) {
        float s = 0.f;
        for (int kk = 0; kk < DIM; ++kk)
            s += c[kk] * Wa[kk * 32 + tid];
        cwf[tid] = s;
    }
}

#define ACC8(v) do { const __half2* hp_ = (const __half2*)&(v); float2 f_; \
  f_ = __half22float2(hp_[0]); a0 += f_.x; a1 += f_.y; \
  f_ = __half22float2(hp_[1]); a2 += f_.x; a3 += f_.y; \
  f_ = __half22float2(hp_[2]); a4 += f_.x; a5 += f_.y; \
  f_ = __half22float2(hp_[3]); a6 += f_.x; a7 += f_.y; } while (0)

// ---------------- agg_pass: src-range-partitioned gather, XCD-split, full 64B rows ----------
__global__ __launch_bounds__(256) void agg_pass_kernel(const __half* __restrict__ T,
                                                       const int* __restrict__ rowst,
                                                       const int* __restrict__ rowmid,
                                                       const int* __restrict__ csr,
                                                       __half* __restrict__ P0,
                                                       __half* __restrict__ P1) {
    int b = blockIdx.x;
    int half = (b >> 2) & 1;
    int idx_in_half = (b >> 3) * 4 + (b & 3);
    int tid = threadIdx.x;
    int wave = tid >> 6;
    int l = tid & 63;
    int g = l >> 2, q = l & 3;
    int tile = idx_in_half * 4 + wave;
    if (tile >= NTILES) return;
    int node = tile * 16 + g;
    int ps, pe;
    if (half == 0) { ps = rowst[node]; pe = rowmid[node]; }
    else           { ps = rowmid[node]; pe = rowst[node + 1]; }
    float a0 = 0.f, a1 = 0.f, a2 = 0.f, a3 = 0.f,
          a4 = 0.f, a5 = 0.f, a6 = 0.f, a7 = 0.f;
    int p = ps;
    int idx[8];
    bool have = (p + 8 <= pe);
    if (have) {
        #pragma unroll
        for (int j = 0; j < 8; ++j) idx[j] = csr[p + j];
    }
    while (have) {
        uint4 v[8];
        #pragma unroll
        for (int j = 0; j < 8; ++j)
            v[j] = *(const uint4*)(T + (size_t)idx[j] * DIM + (q << 3));
        int np = p + 8;
        bool nhave = (np + 8 <= pe);
        int nidx[8];
        if (nhave) {
            #pragma unroll
            for (int j = 0; j < 8; ++j) nidx[j] = csr[np + j];
        }
        #pragma unroll
        for (int j = 0; j < 8; ++j) ACC8(v[j]);
        #pragma unroll
        for (int j = 0; j < 8; ++j) idx[j] = nidx[j];
        p = np;
        have = nhave;
    }
    if (p < pe) {
        #pragma unroll
        for (int j = 0; j < 8; ++j) {
            int ei = p + j;
            uint4 vv = {0, 0, 0, 0};
            if (ei < pe) vv = *(const uint4*)(T + (size_t)csr[ei] * DIM + (q << 3));
            ACC8(vv);
        }
    }
    int selfhalf = (node < NHALF) ? 0 : 1;
    if (selfhalf == half) {
        uint4 vs = *(const uint4*)(T + (size_t)node * DIM + (q << 3));
        ACC8(vs);
    }
    __half* P = half ? P1 : P0;
    f16x8 hv;
    hv[0] = (_Float16)a0; hv[1] = (_Float16)a1;
    hv[2] = (_Float16)a2; hv[3] = (_Float16)a3;
    hv[4] = (_Float16)a4; hv[5] = (_Float16)a5;
    hv[6] = (_Float16)a6; hv[7] = (_Float16)a7;
    *(f16x8*)(P + (size_t)node * DIM + (q << 3)) = hv;
}

// ---------------- mlp: P0+P1 -> MFMA MLP -> next table; binned BN stats ----------------
__global__ __launch_bounds__(256) void mlp_kernel(const __half* __restrict__ P0,
                                                  const __half* __restrict__ P1,
                                                  const float* __restrict__ degf,
                                                  const __half* __restrict__ blob,
                                                  const float* __restrict__ cwf,
                                                  const float* __restrict__ bias_a,
                                                  const float* __restrict__ bias_b,
                                                  __half* __restrict__ outT,
                                                  float* __restrict__ sbins) {
    __shared__ __align__(16) _Float16 X[4][512];
    int tid = threadIdx.x;
    int wave = tid >> 6;
    int l = tid & 63;
    int d0 = l & 15, kg = l >> 4;
    int tile = blockIdx.x * 4 + wave;
    if (tile >= NTILES) return;
    int tb = tile * 16;

    f16x8 v0 = *(const f16x8*)(P0 + (size_t)(tb + d0) * DIM + kg * 8);
    f16x8 v1 = *(const f16x8*)(P1 + (size_t)(tb + d0) * DIM + kg * 8);
    f16x8 af = v0 + v1;
    f16x8 bA0 = *(const f16x8*)(blob + d0 * 32 + kg * 8);
    f16x8 bA1 = *(const f16x8*)(blob + (d0 + 16) * 32 + kg * 8);
    f16x8 bB0 = *(const f16x8*)(blob + 1024 + d0 * 32 + kg * 8);
    f16x8 bB1 = *(const f16x8*)(blob + 1024 + (d0 + 16) * 32 + kg * 8);
    f32x4 degv = *(const f32x4*)(degf + tb + kg * 4);
    float cw0 = cwf[d0], cw1 = cwf[d0 + 16];
    float ba0 = bias_a[d0], ba1 = bias_a[d0 + 16];
    float bb0 = bias_b[d0], bb1 = bias_b[d0 + 16];

    f32x4 c0 = {ba0, ba0, ba0, ba0};
    f32x4 c1 = {ba1, ba1, ba1, ba1};
    c0 = __builtin_amdgcn_mfma_f32_16x16x32_f16(af, bA0, c0, 0, 0, 0);
    c1 = __builtin_amdgcn_mfma_f32_16x16x32_f16(af, bA1, c1, 0, 0, 0);
    #pragma unroll
    for (int rr = 0; rr < 4; ++rr) {
        float w0 = fmaxf(c0[rr] + degv[rr] * cw0, 0.f);
        float w1 = fmaxf(c1[rr] + degv[rr] * cw1, 0.f);
        int row = kg * 4 + rr;
        X[wave][row * 32 + d0] = (_Float16)w0;
        X[wave][row * 32 + d0 + 16] = (_Float16)w1;
    }
    __builtin_amdgcn_wave_barrier();
    f16x8 af2 = *(f16x8*)&X[wave][d0 * 32 + kg * 8];
    __builtin_amdgcn_wave_barrier();

    f32x4 e0 = {bb0, bb0, bb0, bb0};
    f32x4 e1 = {bb1, bb1, bb1, bb1};
    e0 = __builtin_amdgcn_mfma_f32_16x16x32_f16(af2, bB0, e0, 0, 0, 0);
    e1 = __builtin_amdgcn_mfma_f32_16x16x32_f16(af2, bB1, e1, 0, 0, 0);
    float s0 = 0.f, ss0 = 0.f, s1 = 0.f, ss1 = 0.f;
    #pragma unroll
    for (int rr = 0; rr < 4; ++rr) {
        float y0 = fmaxf(e0[rr], 0.f);
        float y1 = fmaxf(e1[rr], 0.f);
        s0 += y0; ss0 += y0 * y0;
        s1 += y1; ss1 += y1 * y1;
        int row = kg * 4 + rr;
        X[wave][row * 32 + d0] = (_Float16)y0;
        X[wave][row * 32 + d0 + 16] = (_Float16)y1;
    }
    __builtin_amdgcn_wave_barrier();
    {
        int gg = l >> 2, c = l & 3;
        uint4 vv = *(uint4*)&X[wave][gg * 32 + c * 8];
        *(uint4*)(outT + (size_t)(tb + gg) * DIM + c * 8) = vv;
    }
    s0 += __shfl_xor(s0, 16); s0 += __shfl_xor(s0, 32);
    ss0 += __shfl_xor(ss0, 16); ss0 += __shfl_xor(ss0, 32);
    s1 += __shfl_xor(s1, 16); s1 += __shfl_xor(s1, 32);
    ss1 += __shfl_xor(ss1, 16); ss1 += __shfl_xor(ss1, 32);
    if (kg == 0) {
        float* sb = sbins + ((blockIdx.x * 4 + wave) & (SBINS - 1)) * 64;
        atomicAdd(&sb[d0], s0);
        atomicAdd(&sb[DIM + d0], ss0);
        atomicAdd(&sb[d0 + 16], s1);
        atomicAdd(&sb[DIM + d0 + 16], ss1);
    }
}

// ---------------- final BN + global_add_pool (run-length, batch sorted) ----------------
#define POOL_BLOCKS 512
__global__ __launch_bounds__(256) void bn_pool_kernel(const __half* __restrict__ h,
                                                      const float* __restrict__ sbins,
                                                      const float* __restrict__ gamma,
                                                      const float* __restrict__ beta,
                                                      const int* __restrict__ batch,
                                                      float* __restrict__ pooled) {
    __shared__ float st[64];
    int tid = threadIdx.x;
    if (tid < 64) {
        float s = 0.f;
        for (int b = 0; b < SBINS; ++b) s += sbins[b * 64 + tid];
        st[tid] = s;
    }
    __syncthreads();
    int lane = tid & 31;
    int group = tid >> 5;
    float mu = st[lane] * (1.f / N_NODES);
    float var = st[DIM + lane] * (1.f / N_NODES) - mu * mu;
    float inv = rsqrtf(var + BN_EPS);
    float a = gamma[lane] * inv;
    float c = beta[lane] - mu * a;
    const int ngroups = POOL_BLOCKS * 8;
    const int chunk = (N_NODES + ngroups - 1) / ngroups;
    int g = blockIdx.x * 8 + group;
    int start = g * chunk;
    if (start >= N_NODES) return;
    int end = start + chunk; if (end > N_NODES) end = N_NODES;
    int cur = batch[start];
    float s = 0.f;
    for (int node = start; node < end; ++node) {
        float v = __half2float(h[(size_t)node * DIM + lane]) * a + c;
        int bg = batch[node];
        if (bg != cur) {
            atomicAdd(&pooled[cur * DIM + lane], s);
            s = 0.f;
            cur = bg;
        }
        s += v;
    }
    atomicAdd(&pooled[cur * DIM + lane], s);
}

// ---------------- out = relu(pooled @ Wfc + bfc) ----------------
__global__ __launch_bounds__(256) void fc_kernel(const float* __restrict__ pooled,
                                                 const float* __restrict__ Wfc,
                                                 const float* __restrict__ bfc,
                                                 float* __restrict__ out) {
    __shared__ float Wl[DIM * OUT_DIM];
    for (int i = threadIdx.x; i < DIM * OUT_DIM; i += blockDim.x) Wl[i] = Wfc[i];
    __syncthreads();
    int idx = blockIdx.x * blockDim.x + threadIdx.x;
    int stride = gridDim.x * blockDim.x;
    for (; idx < N_GRAPHS * OUT_DIM; idx += stride) {
        int g = idx >> 7;
        int o = idx & 127;
        float acc = bfc[o];
        #pragma unroll
        for (int k = 0; k < DIM; ++k)
            acc += pooled[g * DIM + k] * Wl[k * OUT_DIM + o];
        out[idx] = fmaxf(acc, 0.f);
    }
}

extern "C" void kernel_launch(void* const* d_in, const int* in_sizes, int n_in,
                              void* d_out, int out_size, void* d_ws, size_t ws_size,
                              hipStream_t stream) {
    const float* x   = (const float*)d_in[0];
    const int* eidx  = (const int*)d_in[1];
    const int* src   = eidx;
    const int* dst   = eidx + N_EDGES;
    const int* batch = (const int*)d_in[2];
    const float* W1a = (const float*)d_in[3];
    const float* b1a = (const float*)d_in[4];
    const float* W1b = (const float*)d_in[5];
    const float* b1b = (const float*)d_in[6];
    const float* Wa  = (const float*)d_in[7];
    const float* ba  = (const float*)d_in[8];
    const float* Wb  = (const float*)d_in[9];
    const float* bb  = (const float*)d_in[10];
    const float* gamma = (const float*)d_in[11];
    const float* beta  = (const float*)d_in[12];
    const float* Wfc = (const float*)d_in[13];
    const float* bfc = (const float*)d_in[14];
    float* out = (float*)d_out;

    const size_t TSZ = (size_t)N_NODES * DIM;                // 3.2M halfs = 6.4MB
    __half* TA = (__half*)d_ws;                              // 6.4MB
    __half* TB = TA + TSZ;                                   // 6.4MB
    __half* P0 = TB + TSZ;                                   // 6.4MB
    __half* P1 = P0 + TSZ;                                   // 6.4MB
    float* degf   = (float*)(P1 + TSZ);                      // 400KB
    float* sbins  = degf + N_NODES;                          // 5 * SBINS * 64
    float* pooled = sbins + 5 * SBINS * 64;                  // 256KB (contiguous after sbins)
    float* cwf    = pooled + N_GRAPHS * DIM;                 // 5*32
    __half* blobs = (__half*)(cwf + 5 * 32);                 // 5*2048 halfs
    __half* blob1 = blobs + 5 * 2048;                        // 3072 halfs
    int* csr      = (int*)(blob1 + 6 * 512);                 // 12.8MB
    int* rowst    = csr + N_EDGES;                           // N_NODES+1
    int* rowmid   = rowst + N_NODES + 1;                     // N_NODES
    int* bcnt     = rowmid + N_NODES;
    int* bstart   = bcnt + 256;
    int* bcursor  = bstart + NB + 1;
    int* qcnt     = bcursor + 256;                           // NB*NSUB*BSIZE (packed)

    // aliases (dead before hosts' first use)
    int* epk             = (int*)TA;              // 12.8MB packed edges over TA+TB
    int* qbase0          = (int*)P1;              // 1.6MB in P1
    int* qbase1          = qbase0 + NB * NSUB * BSIZE;  // 1.6MB in P1

    hipMemsetAsync(bcnt, 0, 256 * sizeof(int), stream);
    hipMemsetAsync(sbins, 0, (5 * SBINS * 64 + N_GRAPHS * DIM) * sizeof(float), stream);

    bucket_hist_kernel<<<1024, 256, 0, stream>>>(dst, bcnt);
    bucket_scan_kernel<<<1, 256, 0, stream>>>(bcnt, bstart, bcursor, rowst);
    bucket_scatter_kernel<<<(N_EDGES + CHUNK - 1) / CHUNK, 256, 0, stream>>>(src, dst, bcursor, epk);
    node_count_kernel<<<NB * NSUB, 256, 0, stream>>>(bstart, epk, qcnt);
    node_scan_kernel<<<NB, 256, 0, stream>>>(bstart, qcnt, qbase0, qbase1, rowst, rowmid, degf);
    node_scatter_kernel<<<NB * NR, 256, 0, stream>>>(bstart, epk, qbase0, qbase1, csr);

    prep0_kernel<<<1, 1024, 0, stream>>>(W1a, W1b, blob1, blobs, cwf);
    transform1_kernel<<<(NTILES + 3) / 4, 256, 0, stream>>>(x, blob1, TA);

    const __half* in = TA;
    __half* o = TB;

    // layer 1
    agg_pass_kernel<<<AGG_BLOCKS, 256, 0, stream>>>(in, rowst, rowmid, csr, P0, P1);
    mlp_kernel<<<(NTILES + 3) / 4, 256, 0, stream>>>(P0, P1, degf, blobs, cwf, b1a, b1b, o, sbins);
    { const __half* t = in; in = o; o = (__half*)t; }

    for (int i = 0; i < 4; ++i) {
        __half* blob_i = blobs + (i + 1) * 2048;
        float* cwf_i = cwf + (i + 1) * 32;
        prep_kernel<<<1, 1024, 0, stream>>>(sbins + i * SBINS * 64, gamma + i * DIM, beta + i * DIM,
                                            Wa + i * DIM * DIM, Wb + i * DIM * DIM, blob_i, cwf_i);
        agg_pass_kernel<<<AGG_BLOCKS, 256, 0, stream>>>(in, rowst, rowmid, csr, P0, P1);
        mlp_kernel<<<(NTILES + 3) / 4, 256, 0, stream>>>(P0, P1, degf, blob_i, cwf_i,
                                                         ba + i * DIM, bb + i * DIM, o,
                                                         sbins + (i + 1) * SBINS * 64);
        { const __half* t = in; in = o; o = (__half*)t; }
    }

    bn_pool_kernel<<<POOL_BLOCKS, 256, 0, stream>>>(in, sbins + 4 * SBINS * 64,
                                                    gamma + 4 * DIM, beta + 4 * DIM, batch, pooled);
    fc_kernel<<<1024, 256, 0, stream>>>(pooled, Wfc, bfc, out);
}